// Round 1
// baseline (421.761 us; speedup 1.0000x reference)
//
#include <hip/hip_runtime.h>
#include <math.h>

// Problem constants
#define BATCH 8
#define C1C 256
#define C2C 256
#define CC 128
#define NPIX 1024   // 32*32
#define NH 8        // heads
#define HDD 16      // head dim

// ---------------------------------------------------------------------------
// Generic batched GEMM: Y[b] (M x N) = W (M x K) @ X[b] (K x N) (+bias) (+res)
// Tile 64x64, K-chunk 16, 256 threads, 4x4 micro-tile per thread.
// ---------------------------------------------------------------------------
template<bool HAS_BIAS, bool HAS_RES>
__global__ __launch_bounds__(256) void gemm_kernel(
    const float* __restrict__ W, const float* __restrict__ X,
    const float* __restrict__ bias, const float* __restrict__ res,
    float* __restrict__ Y, int M, int Nn, int K, long sX, long sY, long sR) {
  __shared__ float Ws[16][68];
  __shared__ float Xs[16][68];
  const int b = blockIdx.z;
  const float* Xb = X + (long)b * sX;
  float* Yb = Y + (long)b * sY;
  const int m0 = blockIdx.y * 64, n0 = blockIdx.x * 64;
  const int tid = threadIdx.x;
  const int tx = tid & 15, ty = tid >> 4;
  float acc[4][4] = {};
  for (int k0 = 0; k0 < K; k0 += 16) {
    {
      int r = tid >> 2;
      int c4 = (tid & 3) * 4;
      const float4 wv = *(const float4*)(W + (long)(m0 + r) * K + k0 + c4);
      Ws[c4 + 0][r] = wv.x; Ws[c4 + 1][r] = wv.y;
      Ws[c4 + 2][r] = wv.z; Ws[c4 + 3][r] = wv.w;
    }
    {
      int r = tid >> 4;
      int cR = (tid & 15) * 4;
      const float4 xv = *(const float4*)(Xb + (long)(k0 + r) * Nn + n0 + cR);
      *(float4*)&Xs[r][cR] = xv;
    }
    __syncthreads();
#pragma unroll
    for (int kk = 0; kk < 16; kk++) {
      float a[4], bx[4];
#pragma unroll
      for (int i = 0; i < 4; i++) a[i] = Ws[kk][ty * 4 + i];
#pragma unroll
      for (int j = 0; j < 4; j++) bx[j] = Xs[kk][tx * 4 + j];
#pragma unroll
      for (int i = 0; i < 4; i++)
#pragma unroll
        for (int j = 0; j < 4; j++) acc[i][j] += a[i] * bx[j];
    }
    __syncthreads();
  }
#pragma unroll
  for (int i = 0; i < 4; i++) {
    int m = m0 + ty * 4 + i;
    float bv = HAS_BIAS ? bias[m] : 0.f;
#pragma unroll
    for (int j = 0; j < 4; j++) {
      int n = n0 + tx * 4 + j;
      float v = acc[i][j] + bv;
      if (HAS_RES) v += res[(long)b * sR + (long)m * Nn + n];
      Yb[(long)m * Nn + n] = v;
    }
  }
}

// ---------------------------------------------------------------------------
// FFT magnitude pooling: pooled[b,c] = mean |rfft2(y1[b,c], ortho)| over 32x17
// Also m1[b,c] = mean(y1[b,c]).  One block per (b,c) image.
// ---------------------------------------------------------------------------
__global__ __launch_bounds__(256) void fftpool_kernel(
    const float* __restrict__ yc, float* __restrict__ pooled, float* __restrict__ m1) {
  const int bc = blockIdx.x;
  const int b = bc >> 7, cx = bc & 127;
  const float* img = yc + ((long)b * 384 + 128 + cx) * NPIX;
  __shared__ float im[1024];
  __shared__ float Gr[32][17], Gi[32][17];
  __shared__ float cs[32], sn[32];
  __shared__ float red[256];
  const int t = threadIdx.x;
  if (t < 32) {
    float ang = -0.19634954084936207f * (float)t;  // -2*pi*t/32
    __sincosf(ang, &sn[t], &cs[t]);
  }
  float lsum = 0.f;
  for (int i = t; i < 1024; i += 256) { float v = img[i]; im[i] = v; lsum += v; }
  red[t] = lsum;
  __syncthreads();
  for (int s = 128; s > 0; s >>= 1) {
    if (t < s) red[t] += red[t + s];
    __syncthreads();
  }
  if (t == 0) m1[bc] = red[0] * (1.f / 1024.f);
  // stage 1: along w
  for (int i = t; i < 544; i += 256) {
    int h = i / 17, v = i % 17;
    float ar = 0.f, ai = 0.f;
    for (int w2 = 0; w2 < 32; w2++) {
      int k = (v * w2) & 31;
      float x = im[h * 32 + w2];
      ar += x * cs[k]; ai += x * sn[k];
    }
    Gr[h][v] = ar; Gi[h][v] = ai;
  }
  __syncthreads();
  // stage 2: along h, accumulate |X|
  float asum = 0.f;
  for (int i = t; i < 544; i += 256) {
    int u = i / 17, v = i % 17;
    float xr = 0.f, xi = 0.f;
    for (int h = 0; h < 32; h++) {
      int k = (u * h) & 31;
      float gr = Gr[h][v], gi = Gi[h][v];
      xr += gr * cs[k] - gi * sn[k];
      xi += gr * sn[k] + gi * cs[k];
    }
    asum += sqrtf(xr * xr + xi * xi);
  }
  red[t] = asum;
  __syncthreads();
  for (int s = 128; s > 0; s >>= 1) {
    if (t < s) red[t] += red[t + s];
    __syncthreads();
  }
  if (t == 0) pooled[bc] = red[0] * (1.f / (32.f * 544.f));
}

// ---------------------------------------------------------------------------
// Gates: fw/ca MLPs -> g = fw*ca; p_route -> alpha.  One block per batch.
// ---------------------------------------------------------------------------
__global__ __launch_bounds__(128) void gates_kernel(
    const float* __restrict__ pooled, const float* __restrict__ m1,
    const float* __restrict__ fm_w1, const float* __restrict__ fm_w2,
    const float* __restrict__ ca_w1, const float* __restrict__ ca_w2,
    const float* __restrict__ rt_w, const float* __restrict__ rt_b,
    float* __restrict__ g, float* __restrict__ alpha) {
  const int b = blockIdx.x, t = threadIdx.x;
  __shared__ float h1[8], fwv[128], xsm[128], h2[8];
  const float* pb = pooled + b * 128;
  const float* mb = m1 + b * 128;
  if (t < 8) {
    float s = 0.f;
    for (int c = 0; c < 128; c++) s += pb[c] * fm_w1[t * 128 + c];
    h1[t] = fmaxf(s, 0.f);
  }
  __syncthreads();
  {
    float s = 0.f;
    for (int r = 0; r < 8; r++) s += h1[r] * fm_w2[t * 8 + r];
    float fw = 1.f / (1.f + __expf(-s));
    fwv[t] = fw; xsm[t] = fw * mb[t];
  }
  __syncthreads();
  if (t < 8) {
    float s = 0.f;
    for (int c = 0; c < 128; c++) s += xsm[c] * ca_w1[t * 128 + c];
    h2[t] = fmaxf(s, 0.f);
  }
  __syncthreads();
  {
    float s = 0.f;
    for (int r = 0; r < 8; r++) s += h2[r] * ca_w2[t * 8 + r];
    float ca = 1.f / (1.f + __expf(-s));
    g[b * 128 + t] = fwv[t] * ca;
  }
  if (t == 0) {
    float s = 0.f;
    for (int c = 0; c < 128; c++) s += mb[c] * rt_w[c];
    s += rt_b[0];
    alpha[b] = 1.f / (1.f + __expf(-s));
  }
}

// ---------------------------------------------------------------------------
// Variance of k and v head vectors (ddof=1). One thread per (b,h,n).
// ---------------------------------------------------------------------------
__global__ __launch_bounds__(256) void var_kernel(
    const float* __restrict__ qkvb, float* __restrict__ var_k, float* __restrict__ var_v) {
  long idx = (long)blockIdx.x * 256 + threadIdx.x;  // 65536 total
  int n = idx & 1023;
  long bh = idx >> 10;
  int b = (int)(bh >> 3), h = (int)(bh & 7);
  const float* kb = qkvb + ((long)b * 384 + 128 + h * 16) * NPIX + n;
  const float* vb = qkvb + ((long)b * 384 + 256 + h * 16) * NPIX + n;
  float xk[16], xv[16], sk = 0.f, sv = 0.f;
#pragma unroll
  for (int d = 0; d < 16; d++) {
    xk[d] = kb[(long)d * NPIX]; sk += xk[d];
    xv[d] = vb[(long)d * NPIX]; sv += xv[d];
  }
  float mk = sk * (1.f / 16.f), mv = sv * (1.f / 16.f);
  float vk_ = 0.f, vv_ = 0.f;
#pragma unroll
  for (int d = 0; d < 16; d++) {
    float a = xk[d] - mk; vk_ += a * a;
    float c = xv[d] - mv; vv_ += c * c;
  }
  var_k[idx] = vk_ * (1.f / 15.f);
  var_v[idx] = vv_ * (1.f / 15.f);
}

__global__ __launch_bounds__(256) void maxvk_kernel(
    const float* __restrict__ var_k, float* __restrict__ maxvk) {
  const int bh = blockIdx.x;
  __shared__ float red[256];
  float m = 0.f;
  for (int i = threadIdx.x; i < NPIX; i += 256) m = fmaxf(m, var_k[(long)bh * NPIX + i]);
  red[threadIdx.x] = m;
  __syncthreads();
  for (int s = 128; s > 0; s >>= 1) {
    if (threadIdx.x < s) red[threadIdx.x] = fmaxf(red[threadIdx.x], red[threadIdx.x + s]);
    __syncthreads();
  }
  if (threadIdx.x == 0) maxvk[bh] = red[0];
}

// ---------------------------------------------------------------------------
// Stat attention: to[b,h,n,:] = sum_m softmax_m(cn*vk[m]) * v[b,h,m,:]
// cn = var_v[b,h,n]/4 >= 0; global max(var_k) gives exact stable softmax.
// Block: (bh, n-chunk of 256). v streamed through LDS in chunks of 256 rows.
// ---------------------------------------------------------------------------
__global__ __launch_bounds__(256) void stat_attn_kernel(
    const float* __restrict__ qkvb, const float* __restrict__ var_k,
    const float* __restrict__ var_v, const float* __restrict__ maxvk,
    float* __restrict__ to_cn) {
  const int bh = blockIdx.x;
  const int b = bh >> 3, h = bh & 7;
  const int n = blockIdx.y * 256 + threadIdx.x;
  __shared__ float vk[NPIX];
  __shared__ float vs[256][17];
  const float* vbase = qkvb + ((long)b * 384 + 256 + h * 16) * NPIX;
  for (int i = threadIdx.x; i < NPIX; i += 256) vk[i] = var_k[(long)bh * NPIX + i];
  const float cn = var_v[(long)bh * NPIX + n] * 0.25f;
  const float mv = maxvk[bh];
  float denom = 0.f;
  float acc[16];
#pragma unroll
  for (int d = 0; d < 16; d++) acc[d] = 0.f;
  for (int m0 = 0; m0 < NPIX; m0 += 256) {
    __syncthreads();
    for (int i = threadIdx.x; i < 256 * 16; i += 256) {
      int d = i >> 8, mm = i & 255;
      vs[mm][d] = vbase[(long)d * NPIX + m0 + mm];
    }
    __syncthreads();
    for (int mm = 0; mm < 256; mm++) {
      float w = __expf(cn * (vk[m0 + mm] - mv));
      denom += w;
#pragma unroll
      for (int d = 0; d < 16; d++) acc[d] += w * vs[mm][d];
    }
  }
  float inv = 1.f / denom;
#pragma unroll
  for (int d = 0; d < 16; d++)
    to_cn[((long)b * CC + h * 16 + d) * NPIX + n] = acc[d] * inv;
}

// ---------------------------------------------------------------------------
// Bit-pack signs of q/k spatial projections. Wave per (b,n); ballot packs 64.
// bit=1 <=> val>0 (+1), bit=0 <=> -1.
// ---------------------------------------------------------------------------
__global__ __launch_bounds__(256) void pack_kernel(
    const float* __restrict__ qv, const float* __restrict__ kv,
    unsigned long long* __restrict__ qbits, unsigned long long* __restrict__ kbits) {
  const int wave = threadIdx.x >> 6, lane = threadIdx.x & 63;
  const long p = (long)blockIdx.x * 4 + wave;  // 0..8191
  const int b = (int)(p >> 10), n = (int)(p & 1023);
  const float* qb_ = qv + (long)b * 128 * NPIX + n;
  const float* kb_ = kv + (long)b * 128 * NPIX + n;
  unsigned long long q0 = __ballot(qb_[(long)lane * NPIX] > 0.f);
  unsigned long long q1 = __ballot(qb_[(long)(64 + lane) * NPIX] > 0.f);
  unsigned long long k0 = __ballot(kb_[(long)lane * NPIX] > 0.f);
  unsigned long long k1 = __ballot(kb_[(long)(64 + lane) * NPIX] > 0.f);
  if (lane == 0) {
    qbits[p * 2] = q0; qbits[p * 2 + 1] = q1;
    kbits[p * 2] = k0; kbits[p * 2 + 1] = k1;
  }
}

// ---------------------------------------------------------------------------
// Row softmax stats for binary attention: max and 1/sum of exp(S/sqrt(128)).
// S[n,m] = 128 - 2*popcount(q[n]^k[m]).  Block: 256 rows of one batch.
// ---------------------------------------------------------------------------
__global__ __launch_bounds__(256) void rowstats_kernel(
    const unsigned long long* __restrict__ qbits, const unsigned long long* __restrict__ kbits,
    float* __restrict__ rmax, float* __restrict__ rinvd) {
  const int b = blockIdx.x >> 2;
  const int n0 = (blockIdx.x & 3) * 256;
  __shared__ unsigned long long kb[1024][2];
  for (int i = threadIdx.x; i < 1024; i += 256) {
    kb[i][0] = kbits[((long)b * 1024 + i) * 2];
    kb[i][1] = kbits[((long)b * 1024 + i) * 2 + 1];
  }
  __syncthreads();
  const int n = n0 + threadIdx.x;
  const unsigned long long q0 = qbits[((long)b * 1024 + n) * 2];
  const unsigned long long q1 = qbits[((long)b * 1024 + n) * 2 + 1];
  int smax = -1000;
  for (int m = 0; m < 1024; m++) {
    int ham = __popcll(kb[m][0] ^ q0) + __popcll(kb[m][1] ^ q1);
    smax = max(smax, 128 - 2 * ham);
  }
  const float fs = 0.08838834764831845f;  // 1/sqrt(128)
  float mx = smax * fs, den = 0.f;
  for (int m = 0; m < 1024; m++) {
    int ham = __popcll(kb[m][0] ^ q0) + __popcll(kb[m][1] ^ q1);
    den += __expf((float)(128 - 2 * ham) * fs - mx);
  }
  rmax[(long)b * 1024 + n] = mx;
  rinvd[(long)b * 1024 + n] = 1.f / den;
}

// ---------------------------------------------------------------------------
// ob[b,c,n] = sum_m a2[n,m] * vv[b,c,m].  Block: 32 n  x 128 c, m chunks of 64.
// ---------------------------------------------------------------------------
__global__ __launch_bounds__(256) void ob_kernel(
    const unsigned long long* __restrict__ qbits, const unsigned long long* __restrict__ kbits,
    const float* __restrict__ vv, const float* __restrict__ rmax,
    const float* __restrict__ rinvd, float* __restrict__ ob) {
  const int b = blockIdx.y;
  const int n0 = blockIdx.x * 32;
  __shared__ float vvs[128][65];
  __shared__ float ws[32][64];
  __shared__ unsigned long long qs[32][2];
  __shared__ float rm[32], rd[32];
  if (threadIdx.x < 32) {
    int n = n0 + threadIdx.x;
    qs[threadIdx.x][0] = qbits[((long)b * 1024 + n) * 2];
    qs[threadIdx.x][1] = qbits[((long)b * 1024 + n) * 2 + 1];
    rm[threadIdx.x] = rmax[(long)b * 1024 + n];
    rd[threadIdx.x] = rinvd[(long)b * 1024 + n];
  }
  const int c = threadIdx.x & 127, half = threadIdx.x >> 7;
  const float fs = 0.08838834764831845f;
  float acc[16];
#pragma unroll
  for (int t = 0; t < 16; t++) acc[t] = 0.f;
  for (int m0 = 0; m0 < 1024; m0 += 64) {
    __syncthreads();
    for (int i = threadIdx.x; i < 128 * 64; i += 256) {
      int cc = i >> 6, mm = i & 63;
      vvs[cc][mm] = vv[((long)b * 128 + cc) * NPIX + m0 + mm];
    }
    for (int i = threadIdx.x; i < 32 * 64; i += 256) {
      int ni = i >> 6, mj = i & 63;
      unsigned long long k0 = kbits[((long)b * 1024 + m0 + mj) * 2];
      unsigned long long k1 = kbits[((long)b * 1024 + m0 + mj) * 2 + 1];
      int ham = __popcll(qs[ni][0] ^ k0) + __popcll(qs[ni][1] ^ k1);
      ws[ni][mj] = __expf((float)(128 - 2 * ham) * fs - rm[ni]) * rd[ni];
    }
    __syncthreads();
    for (int mj = 0; mj < 64; mj++) {
      float v = vvs[c][mj];
#pragma unroll
      for (int t = 0; t < 16; t++) acc[t] += ws[half * 16 + t][mj] * v;
    }
  }
#pragma unroll
  for (int t = 0; t < 16; t++)
    ob[((long)b * 128 + c) * NPIX + n0 + half * 16 + t] = acc[t];
}

// ---------------------------------------------------------------------------
// Depthwise 3x3 conv (SAME, zero pad). One block per (b,c).
// ---------------------------------------------------------------------------
__global__ __launch_bounds__(256) void dwconv_kernel(
    const float* __restrict__ yc, const float* __restrict__ dw_w,
    const float* __restrict__ dw_b, float* __restrict__ xl) {
  const int bc = blockIdx.x;
  const int b = bc >> 7, cx = bc & 127;
  const float* img = yc + ((long)b * 384 + 128 + cx) * NPIX;
  float w[9];
#pragma unroll
  for (int i = 0; i < 9; i++) w[i] = dw_w[cx * 9 + i];
  const float bias = dw_b[cx];
  for (int i = threadIdx.x; i < 1024; i += 256) {
    int h = i >> 5, wx = i & 31;
    float s = bias;
#pragma unroll
    for (int ky = 0; ky < 3; ky++) {
      int hh = h + ky - 1;
      if (hh < 0 || hh > 31) continue;
#pragma unroll
      for (int kx = 0; kx < 3; kx++) {
        int ww2 = wx + kx - 1;
        if (ww2 < 0 || ww2 > 31) continue;
        s += img[hh * 32 + ww2] * w[ky * 3 + kx];
      }
    }
    xl[(long)bc * NPIX + i] = s;
  }
}

// ---------------------------------------------------------------------------
// Combine: yc[b,256+c,n] += g*y1 + (1-a)*xl + a*obp
// ---------------------------------------------------------------------------
__global__ __launch_bounds__(256) void combine_kernel(
    float* __restrict__ yc, const float* __restrict__ xl, const float* __restrict__ obp,
    const float* __restrict__ g, const float* __restrict__ alpha) {
  long i = (long)blockIdx.x * 256 + threadIdx.x;  // B*128*1024
  int n = (int)(i & 1023);
  long bc = i >> 10;
  int b = (int)(bc >> 7), cx = (int)(bc & 127);
  float a = alpha[b];
  float y1v = yc[((long)b * 384 + 128 + cx) * NPIX + n];
  long oidx = ((long)b * 384 + 256 + cx) * NPIX + n;
  yc[oidx] = yc[oidx] + g[bc] * y1v + (1.f - a) * xl[i] + a * obp[i];
}

// ---------------------------------------------------------------------------
extern "C" void kernel_launch(void* const* d_in, const int* in_sizes, int n_in,
                              void* d_out, int out_size, void* d_ws, size_t ws_size,
                              hipStream_t stream) {
  const float* x = (const float*)d_in[0];
  const float* cv1_w = (const float*)d_in[1];
  const float* cv1_b = (const float*)d_in[2];
  const float* fm_w1 = (const float*)d_in[3];
  const float* fm_w2 = (const float*)d_in[4];
  const float* ca_w1 = (const float*)d_in[5];
  const float* ca_w2 = (const float*)d_in[6];
  const float* qkv_w = (const float*)d_in[7];
  const float* tproj_w = (const float*)d_in[8];
  const float* tproj_b = (const float*)d_in[9];
  const float* dw_w = (const float*)d_in[10];
  const float* dw_b = (const float*)d_in[11];
  const float* rt_w = (const float*)d_in[12];
  const float* rt_b = (const float*)d_in[13];
  const float* q_w = (const float*)d_in[14];
  const float* k_w = (const float*)d_in[15];
  const float* v_w = (const float*)d_in[16];
  const float* sproj_w = (const float*)d_in[17];
  const float* sproj_b = (const float*)d_in[18];
  const float* cv2_w = (const float*)d_in[19];
  const float* cv2_b = (const float*)d_in[20];
  float* out = (float*)d_out;

  char* wsp = (char*)d_ws;
  size_t off = 0;
  auto alloc = [&](size_t bytes) {
    void* p = wsp + off;
    off += (bytes + 255) & ~(size_t)255;
    return p;
  };
  float* yc = (float*)alloc(8UL * 384 * 1024 * 4);
  float* qkvb = (float*)alloc(8UL * 384 * 1024 * 4);
  float* to_cn = (float*)alloc(8UL * 128 * 1024 * 4);
  float* qv = (float*)alloc(8UL * 128 * 1024 * 4);
  float* kv = (float*)alloc(8UL * 128 * 1024 * 4);
  float* vvb = (float*)alloc(8UL * 128 * 1024 * 4);
  float* var_k = (float*)alloc(8UL * 8 * 1024 * 4);
  float* var_v = (float*)alloc(8UL * 8 * 1024 * 4);
  float* maxvk = (float*)alloc(64 * 4);
  float* pooled = (float*)alloc(1024 * 4);
  float* m1 = (float*)alloc(1024 * 4);
  float* g = (float*)alloc(1024 * 4);
  float* alpha = (float*)alloc(8 * 4);
  unsigned long long* qbits = (unsigned long long*)alloc(8192UL * 2 * 8);
  unsigned long long* kbits = (unsigned long long*)alloc(8192UL * 2 * 8);
  float* rmax = (float*)alloc(8192 * 4);
  float* rinvd = (float*)alloc(8192 * 4);
  float* obv = qv;    // alias: qv dead after pack
  float* obp = kv;    // alias: kv dead after pack
  float* xl = to_cn;  // alias: to_cn dead after tproj
  if (off > ws_size) return;

  dim3 blk(256);
  // 1. cv1: yc[:,0:256,:] = cv1_w @ x + cv1_b
  gemm_kernel<true, false><<<dim3(16, 4, 8), blk, 0, stream>>>(
      cv1_w, x, cv1_b, nullptr, yc, 256, 1024, 256, 256L * 1024, 384L * 1024, 0);
  // 2. FFT pooling + channel means
  fftpool_kernel<<<dim3(1024), blk, 0, stream>>>(yc, pooled, m1);
  // 3. gates
  gates_kernel<<<dim3(8), dim3(128), 0, stream>>>(pooled, m1, fm_w1, fm_w2,
                                                  ca_w1, ca_w2, rt_w, rt_b, g, alpha);
  // 4. qkv projection
  gemm_kernel<false, false><<<dim3(16, 6, 8), blk, 0, stream>>>(
      qkv_w, yc + 128 * 1024, nullptr, nullptr, qkvb, 384, 1024, 128,
      384L * 1024, 384L * 1024, 0);
  // 5-6. variances + max
  var_kernel<<<dim3(256), blk, 0, stream>>>(qkvb, var_k, var_v);
  maxvk_kernel<<<dim3(64), blk, 0, stream>>>(var_k, maxvk);
  // 7. stat attention
  stat_attn_kernel<<<dim3(64, 4), blk, 0, stream>>>(qkvb, var_k, var_v, maxvk, to_cn);
  // 8. tproj -> yc[:,256:384,:] (stat_out)
  gemm_kernel<true, false><<<dim3(16, 2, 8), blk, 0, stream>>>(
      tproj_w, to_cn, tproj_b, nullptr, yc + 256 * 1024, 128, 1024, 128,
      128L * 1024, 384L * 1024, 0);
  // 9. spatial q/k/v projections
  gemm_kernel<false, false><<<dim3(16, 2, 8), blk, 0, stream>>>(
      q_w, yc + 128 * 1024, nullptr, nullptr, qv, 128, 1024, 128,
      384L * 1024, 128L * 1024, 0);
  gemm_kernel<false, false><<<dim3(16, 2, 8), blk, 0, stream>>>(
      k_w, yc + 128 * 1024, nullptr, nullptr, kv, 128, 1024, 128,
      384L * 1024, 128L * 1024, 0);
  gemm_kernel<false, false><<<dim3(16, 2, 8), blk, 0, stream>>>(
      v_w, yc + 128 * 1024, nullptr, nullptr, vvb, 128, 1024, 128,
      384L * 1024, 128L * 1024, 0);
  // 10. sign pack
  pack_kernel<<<dim3(2048), blk, 0, stream>>>(qv, kv, qbits, kbits);
  // 11. row softmax stats
  rowstats_kernel<<<dim3(32), blk, 0, stream>>>(qbits, kbits, rmax, rinvd);
  // 12. ob = vv @ a2^T
  ob_kernel<<<dim3(32, 8), blk, 0, stream>>>(qbits, kbits, vvb, rmax, rinvd, obv);
  // 13. sproj
  gemm_kernel<true, false><<<dim3(16, 2, 8), blk, 0, stream>>>(
      sproj_w, obv, sproj_b, nullptr, obp, 128, 1024, 128,
      128L * 1024, 128L * 1024, 0);
  // 14. depthwise conv
  dwconv_kernel<<<dim3(1024), blk, 0, stream>>>(yc, dw_w, dw_b, xl);
  // 15. combine freq + spat into yc attn region
  combine_kernel<<<dim3(4096), blk, 0, stream>>>(yc, xl, obp, g, alpha);
  // 16. cv2 + residual
  gemm_kernel<true, true><<<dim3(16, 4, 8), blk, 0, stream>>>(
      cv2_w, yc, cv2_b, x, out, 256, 1024, 384, 384L * 1024, 256L * 1024,
      256L * 1024);
}

// Round 2
// 356.604 us; speedup vs baseline: 1.1827x; 1.1827x over previous
//
#include <hip/hip_runtime.h>
#include <math.h>

// Problem constants
#define BATCH 8
#define C1C 256
#define C2C 256
#define CC 128
#define NPIX 1024   // 32*32
#define NH 8        // heads
#define HDD 16      // head dim

// ---------------------------------------------------------------------------
// Generic batched GEMM: Y[b] (M x N) = W (M x K) @ X[b] (K x N) (+bias) (+res)
// Tile 64x64, K-chunk 16, 256 threads, 4x4 micro-tile per thread.
// ---------------------------------------------------------------------------
template<bool HAS_BIAS, bool HAS_RES>
__global__ __launch_bounds__(256) void gemm_kernel(
    const float* __restrict__ W, const float* __restrict__ X,
    const float* __restrict__ bias, const float* __restrict__ res,
    float* __restrict__ Y, int M, int Nn, int K, long sX, long sY, long sR) {
  __shared__ float Ws[16][68];
  __shared__ float Xs[16][68];
  const int b = blockIdx.z;
  const float* Xb = X + (long)b * sX;
  float* Yb = Y + (long)b * sY;
  const int m0 = blockIdx.y * 64, n0 = blockIdx.x * 64;
  const int tid = threadIdx.x;
  const int tx = tid & 15, ty = tid >> 4;
  float acc[4][4] = {};
  for (int k0 = 0; k0 < K; k0 += 16) {
    {
      int r = tid >> 2;
      int c4 = (tid & 3) * 4;
      const float4 wv = *(const float4*)(W + (long)(m0 + r) * K + k0 + c4);
      Ws[c4 + 0][r] = wv.x; Ws[c4 + 1][r] = wv.y;
      Ws[c4 + 2][r] = wv.z; Ws[c4 + 3][r] = wv.w;
    }
    {
      int r = tid >> 4;
      int cR = (tid & 15) * 4;
      const float4 xv = *(const float4*)(Xb + (long)(k0 + r) * Nn + n0 + cR);
      *(float4*)&Xs[r][cR] = xv;
    }
    __syncthreads();
#pragma unroll
    for (int kk = 0; kk < 16; kk++) {
      float a[4], bx[4];
#pragma unroll
      for (int i = 0; i < 4; i++) a[i] = Ws[kk][ty * 4 + i];
#pragma unroll
      for (int j = 0; j < 4; j++) bx[j] = Xs[kk][tx * 4 + j];
#pragma unroll
      for (int i = 0; i < 4; i++)
#pragma unroll
        for (int j = 0; j < 4; j++) acc[i][j] += a[i] * bx[j];
    }
    __syncthreads();
  }
#pragma unroll
  for (int i = 0; i < 4; i++) {
    int m = m0 + ty * 4 + i;
    float bv = HAS_BIAS ? bias[m] : 0.f;
#pragma unroll
    for (int j = 0; j < 4; j++) {
      int n = n0 + tx * 4 + j;
      float v = acc[i][j] + bv;
      if (HAS_RES) v += res[(long)b * sR + (long)m * Nn + n];
      Yb[(long)m * Nn + n] = v;
    }
  }
}

// ---------------------------------------------------------------------------
// FFT magnitude pooling: pooled[b,c] = mean |rfft2(y1[b,c], ortho)| over 32x17
// Also m1[b,c] = mean(y1[b,c]).  One block per (b,c) image.
// ---------------------------------------------------------------------------
__global__ __launch_bounds__(256) void fftpool_kernel(
    const float* __restrict__ yc, float* __restrict__ pooled, float* __restrict__ m1) {
  const int bc = blockIdx.x;
  const int b = bc >> 7, cx = bc & 127;
  const float* img = yc + ((long)b * 384 + 128 + cx) * NPIX;
  __shared__ float im[1024];
  __shared__ float Gr[32][17], Gi[32][17];
  __shared__ float cs[32], sn[32];
  __shared__ float red[256];
  const int t = threadIdx.x;
  if (t < 32) {
    float ang = -0.19634954084936207f * (float)t;  // -2*pi*t/32
    __sincosf(ang, &sn[t], &cs[t]);
  }
  float lsum = 0.f;
  for (int i = t; i < 1024; i += 256) { float v = img[i]; im[i] = v; lsum += v; }
  red[t] = lsum;
  __syncthreads();
  for (int s = 128; s > 0; s >>= 1) {
    if (t < s) red[t] += red[t + s];
    __syncthreads();
  }
  if (t == 0) m1[bc] = red[0] * (1.f / 1024.f);
  // stage 1: along w
  for (int i = t; i < 544; i += 256) {
    int h = i / 17, v = i % 17;
    float ar = 0.f, ai = 0.f;
    for (int w2 = 0; w2 < 32; w2++) {
      int k = (v * w2) & 31;
      float x = im[h * 32 + w2];
      ar += x * cs[k]; ai += x * sn[k];
    }
    Gr[h][v] = ar; Gi[h][v] = ai;
  }
  __syncthreads();
  // stage 2: along h, accumulate |X|
  float asum = 0.f;
  for (int i = t; i < 544; i += 256) {
    int u = i / 17, v = i % 17;
    float xr = 0.f, xi = 0.f;
    for (int h = 0; h < 32; h++) {
      int k = (u * h) & 31;
      float gr = Gr[h][v], gi = Gi[h][v];
      xr += gr * cs[k] - gi * sn[k];
      xi += gr * sn[k] + gi * cs[k];
    }
    asum += sqrtf(xr * xr + xi * xi);
  }
  red[t] = asum;
  __syncthreads();
  for (int s = 128; s > 0; s >>= 1) {
    if (t < s) red[t] += red[t + s];
    __syncthreads();
  }
  if (t == 0) pooled[bc] = red[0] * (1.f / (32.f * 544.f));
}

// ---------------------------------------------------------------------------
// Gates: fw/ca MLPs -> g = fw*ca; p_route -> alpha.  One block per batch.
// ---------------------------------------------------------------------------
__global__ __launch_bounds__(128) void gates_kernel(
    const float* __restrict__ pooled, const float* __restrict__ m1,
    const float* __restrict__ fm_w1, const float* __restrict__ fm_w2,
    const float* __restrict__ ca_w1, const float* __restrict__ ca_w2,
    const float* __restrict__ rt_w, const float* __restrict__ rt_b,
    float* __restrict__ g, float* __restrict__ alpha) {
  const int b = blockIdx.x, t = threadIdx.x;
  __shared__ float h1[8], fwv[128], xsm[128], h2[8];
  const float* pb = pooled + b * 128;
  const float* mb = m1 + b * 128;
  if (t < 8) {
    float s = 0.f;
    for (int c = 0; c < 128; c++) s += pb[c] * fm_w1[t * 128 + c];
    h1[t] = fmaxf(s, 0.f);
  }
  __syncthreads();
  {
    float s = 0.f;
    for (int r = 0; r < 8; r++) s += h1[r] * fm_w2[t * 8 + r];
    float fw = 1.f / (1.f + __expf(-s));
    fwv[t] = fw; xsm[t] = fw * mb[t];
  }
  __syncthreads();
  if (t < 8) {
    float s = 0.f;
    for (int c = 0; c < 128; c++) s += xsm[c] * ca_w1[t * 128 + c];
    h2[t] = fmaxf(s, 0.f);
  }
  __syncthreads();
  {
    float s = 0.f;
    for (int r = 0; r < 8; r++) s += h2[r] * ca_w2[t * 8 + r];
    float ca = 1.f / (1.f + __expf(-s));
    g[b * 128 + t] = fwv[t] * ca;
  }
  if (t == 0) {
    float s = 0.f;
    for (int c = 0; c < 128; c++) s += mb[c] * rt_w[c];
    s += rt_b[0];
    alpha[b] = 1.f / (1.f + __expf(-s));
  }
}

// ---------------------------------------------------------------------------
// Variance of k and v head vectors (ddof=1). One thread per (b,h,n).
// ---------------------------------------------------------------------------
__global__ __launch_bounds__(256) void var_kernel(
    const float* __restrict__ qkvb, float* __restrict__ var_k, float* __restrict__ var_v) {
  long idx = (long)blockIdx.x * 256 + threadIdx.x;  // 65536 total
  int n = idx & 1023;
  long bh = idx >> 10;
  int b = (int)(bh >> 3), h = (int)(bh & 7);
  const float* kb = qkvb + ((long)b * 384 + 128 + h * 16) * NPIX + n;
  const float* vb = qkvb + ((long)b * 384 + 256 + h * 16) * NPIX + n;
  float xk[16], xv[16], sk = 0.f, sv = 0.f;
#pragma unroll
  for (int d = 0; d < 16; d++) {
    xk[d] = kb[(long)d * NPIX]; sk += xk[d];
    xv[d] = vb[(long)d * NPIX]; sv += xv[d];
  }
  float mk = sk * (1.f / 16.f), mv = sv * (1.f / 16.f);
  float vk_ = 0.f, vv_ = 0.f;
#pragma unroll
  for (int d = 0; d < 16; d++) {
    float a = xk[d] - mk; vk_ += a * a;
    float c = xv[d] - mv; vv_ += c * c;
  }
  var_k[idx] = vk_ * (1.f / 15.f);
  var_v[idx] = vv_ * (1.f / 15.f);
}

__global__ __launch_bounds__(256) void maxvk_kernel(
    const float* __restrict__ var_k, float* __restrict__ maxvk) {
  const int bh = blockIdx.x;
  __shared__ float red[256];
  float m = 0.f;
  for (int i = threadIdx.x; i < NPIX; i += 256) m = fmaxf(m, var_k[(long)bh * NPIX + i]);
  red[threadIdx.x] = m;
  __syncthreads();
  for (int s = 128; s > 0; s >>= 1) {
    if (threadIdx.x < s) red[threadIdx.x] = fmaxf(red[threadIdx.x], red[threadIdx.x + s]);
    __syncthreads();
  }
  if (threadIdx.x == 0) maxvk[bh] = red[0];
}

// ---------------------------------------------------------------------------
// Stat attention: to[b,h,n,:] = sum_m softmax_m(cn*vk[m]) * v[b,h,m,:]
// cn = var_v[b,h,n]/4 >= 0; global max(var_k) gives exact stable softmax.
// Block: (bh, n-chunk of 256). v streamed through LDS in chunks of 256 rows.
// ---------------------------------------------------------------------------
__global__ __launch_bounds__(256) void stat_attn_kernel(
    const float* __restrict__ qkvb, const float* __restrict__ var_k,
    const float* __restrict__ var_v, const float* __restrict__ maxvk,
    float* __restrict__ to_cn) {
  const int bh = blockIdx.x;
  const int b = bh >> 3, h = bh & 7;
  const int n = blockIdx.y * 256 + threadIdx.x;
  __shared__ float vk[NPIX];
  __shared__ float vs[256][17];
  const float* vbase = qkvb + ((long)b * 384 + 256 + h * 16) * NPIX;
  for (int i = threadIdx.x; i < NPIX; i += 256) vk[i] = var_k[(long)bh * NPIX + i];
  const float cn = var_v[(long)bh * NPIX + n] * 0.25f;
  const float mv = maxvk[bh];
  float denom = 0.f;
  float acc[16];
#pragma unroll
  for (int d = 0; d < 16; d++) acc[d] = 0.f;
  for (int m0 = 0; m0 < NPIX; m0 += 256) {
    __syncthreads();
    for (int i = threadIdx.x; i < 256 * 16; i += 256) {
      int d = i >> 8, mm = i & 255;
      vs[mm][d] = vbase[(long)d * NPIX + m0 + mm];
    }
    __syncthreads();
    for (int mm = 0; mm < 256; mm++) {
      float w = __expf(cn * (vk[m0 + mm] - mv));
      denom += w;
#pragma unroll
      for (int d = 0; d < 16; d++) acc[d] += w * vs[mm][d];
    }
  }
  float inv = 1.f / denom;
#pragma unroll
  for (int d = 0; d < 16; d++)
    to_cn[((long)b * CC + h * 16 + d) * NPIX + n] = acc[d] * inv;
}

// ---------------------------------------------------------------------------
// Bit-pack signs of q/k spatial projections. Wave per (b,n); ballot packs 64.
// bit=1 <=> val>0 (+1), bit=0 <=> -1.
// ---------------------------------------------------------------------------
__global__ __launch_bounds__(256) void pack_kernel(
    const float* __restrict__ qv, const float* __restrict__ kv,
    unsigned long long* __restrict__ qbits, unsigned long long* __restrict__ kbits) {
  const int wave = threadIdx.x >> 6, lane = threadIdx.x & 63;
  const long p = (long)blockIdx.x * 4 + wave;  // 0..8191
  const int b = (int)(p >> 10), n = (int)(p & 1023);
  const float* qb_ = qv + (long)b * 128 * NPIX + n;
  const float* kb_ = kv + (long)b * 128 * NPIX + n;
  unsigned long long q0 = __ballot(qb_[(long)lane * NPIX] > 0.f);
  unsigned long long q1 = __ballot(qb_[(long)(64 + lane) * NPIX] > 0.f);
  unsigned long long k0 = __ballot(kb_[(long)lane * NPIX] > 0.f);
  unsigned long long k1 = __ballot(kb_[(long)(64 + lane) * NPIX] > 0.f);
  if (lane == 0) {
    qbits[p * 2] = q0; qbits[p * 2 + 1] = q1;
    kbits[p * 2] = k0; kbits[p * 2 + 1] = k1;
  }
}

// ---------------------------------------------------------------------------
// Binary-attn softmax denominators. Scores (128-2*ham)/sqrt(128) lie in
// [-11.32, 11.32] so exp() is fp32-safe WITHOUT max subtraction:
// rinvd[b,n] = 1 / sum_m exp(s(n,m)).  One pass, k-bits in LDS.
// ---------------------------------------------------------------------------
__global__ __launch_bounds__(256) void denom_kernel(
    const unsigned long long* __restrict__ qbits,
    const unsigned long long* __restrict__ kbits, float* __restrict__ rinvd) {
  const int b = blockIdx.y;
  const int n = blockIdx.x * 256 + threadIdx.x;
  __shared__ unsigned long long kb[1024][2];
  for (int i = threadIdx.x; i < 1024; i += 256) {
    kb[i][0] = kbits[((long)b * 1024 + i) * 2];
    kb[i][1] = kbits[((long)b * 1024 + i) * 2 + 1];
  }
  __syncthreads();
  const unsigned long long q0 = qbits[((long)b * 1024 + n) * 2];
  const unsigned long long q1 = qbits[((long)b * 1024 + n) * 2 + 1];
  const float fs = 0.08838834764831845f;  // 1/sqrt(128)
  float den = 0.f;
  for (int m = 0; m < 1024; m++) {
    int ham = __popcll(kb[m][0] ^ q0) + __popcll(kb[m][1] ^ q1);
    den += __expf((float)(128 - 2 * ham) * fs);
  }
  rinvd[(long)b * 1024 + n] = 1.f / den;
}

// ---------------------------------------------------------------------------
// Fused binary-attention GEMM: ob[b,c,n] = sum_m vv[b,c,m] * a2t[b,m,n]
// where a2t[m,n] = exp((128-2*popc(q[n]^k[m]))/sqrt(128)) * rinvd[n] is
// synthesized on the fly into the LDS X-tile (no 32MB materialization).
// 64x64 tile, K-chunk 16, 4x4 micro-tile. Grid (16, 2, 8).
// ---------------------------------------------------------------------------
__global__ __launch_bounds__(256) void obgemm_kernel(
    const float* __restrict__ vv, const unsigned long long* __restrict__ qbits,
    const unsigned long long* __restrict__ kbits, const float* __restrict__ rinvd,
    float* __restrict__ ob) {
  const int b = blockIdx.z;
  const int c0 = blockIdx.y * 64, n0 = blockIdx.x * 64;
  __shared__ float Ws[16][68];
  __shared__ float Xs[16][68];
  __shared__ unsigned long long qn[64][2];
  __shared__ float rd[64];
  const int tid = threadIdx.x;
  if (tid < 64) {
    qn[tid][0] = qbits[((long)b * 1024 + n0 + tid) * 2];
    qn[tid][1] = qbits[((long)b * 1024 + n0 + tid) * 2 + 1];
    rd[tid] = rinvd[(long)b * 1024 + n0 + tid];
  }
  __syncthreads();
  const int tx = tid & 15, ty = tid >> 4;
  const float fs = 0.08838834764831845f;
  float acc[4][4] = {};
  for (int k0 = 0; k0 < 1024; k0 += 16) {
    {
      int r = tid >> 2, c4 = (tid & 3) * 4;
      const float4 wv = *(const float4*)(vv + ((long)b * 128 + c0 + r) * 1024 + k0 + c4);
      Ws[c4 + 0][r] = wv.x; Ws[c4 + 1][r] = wv.y;
      Ws[c4 + 2][r] = wv.z; Ws[c4 + 3][r] = wv.w;
    }
    {
      int kr = tid >> 4, nc = (tid & 15) * 4;
      unsigned long long kb0 = kbits[((long)b * 1024 + k0 + kr) * 2];
      unsigned long long kb1 = kbits[((long)b * 1024 + k0 + kr) * 2 + 1];
#pragma unroll
      for (int j = 0; j < 4; j++) {
        int ham = __popcll(qn[nc + j][0] ^ kb0) + __popcll(qn[nc + j][1] ^ kb1);
        Xs[kr][nc + j] = __expf((float)(128 - 2 * ham) * fs) * rd[nc + j];
      }
    }
    __syncthreads();
#pragma unroll
    for (int kk = 0; kk < 16; kk++) {
      float a[4], bx[4];
#pragma unroll
      for (int i = 0; i < 4; i++) a[i] = Ws[kk][ty * 4 + i];
#pragma unroll
      for (int j = 0; j < 4; j++) bx[j] = Xs[kk][tx * 4 + j];
#pragma unroll
      for (int i = 0; i < 4; i++)
#pragma unroll
        for (int j = 0; j < 4; j++) acc[i][j] += a[i] * bx[j];
    }
    __syncthreads();
  }
#pragma unroll
  for (int i = 0; i < 4; i++)
#pragma unroll
    for (int j = 0; j < 4; j++)
      ob[((long)b * 128 + c0 + ty * 4 + i) * 1024 + n0 + tx * 4 + j] = acc[i][j];
}

// ---------------------------------------------------------------------------
// Depthwise 3x3 conv (SAME, zero pad). One block per (b,c).
// ---------------------------------------------------------------------------
__global__ __launch_bounds__(256) void dwconv_kernel(
    const float* __restrict__ yc, const float* __restrict__ dw_w,
    const float* __restrict__ dw_b, float* __restrict__ xl) {
  const int bc = blockIdx.x;
  const int b = bc >> 7, cx = bc & 127;
  const float* img = yc + ((long)b * 384 + 128 + cx) * NPIX;
  float w[9];
#pragma unroll
  for (int i = 0; i < 9; i++) w[i] = dw_w[cx * 9 + i];
  const float bias = dw_b[cx];
  for (int i = threadIdx.x; i < 1024; i += 256) {
    int h = i >> 5, wx = i & 31;
    float s = bias;
#pragma unroll
    for (int ky = 0; ky < 3; ky++) {
      int hh = h + ky - 1;
      if (hh < 0 || hh > 31) continue;
#pragma unroll
      for (int kx = 0; kx < 3; kx++) {
        int ww2 = wx + kx - 1;
        if (ww2 < 0 || ww2 > 31) continue;
        s += img[hh * 32 + ww2] * w[ky * 3 + kx];
      }
    }
    xl[(long)bc * NPIX + i] = s;
  }
}

// ---------------------------------------------------------------------------
// Combine: yc[b,256+c,n] += g*y1 + (1-a)*xl + a*obp
// ---------------------------------------------------------------------------
__global__ __launch_bounds__(256) void combine_kernel(
    float* __restrict__ yc, const float* __restrict__ xl, const float* __restrict__ obp,
    const float* __restrict__ g, const float* __restrict__ alpha) {
  long i = (long)blockIdx.x * 256 + threadIdx.x;  // B*128*1024
  int n = (int)(i & 1023);
  long bc = i >> 10;
  int b = (int)(bc >> 7), cx = (int)(bc & 127);
  float a = alpha[b];
  float y1v = yc[((long)b * 384 + 128 + cx) * NPIX + n];
  long oidx = ((long)b * 384 + 256 + cx) * NPIX + n;
  yc[oidx] = yc[oidx] + g[bc] * y1v + (1.f - a) * xl[i] + a * obp[i];
}

// ---------------------------------------------------------------------------
extern "C" void kernel_launch(void* const* d_in, const int* in_sizes, int n_in,
                              void* d_out, int out_size, void* d_ws, size_t ws_size,
                              hipStream_t stream) {
  const float* x = (const float*)d_in[0];
  const float* cv1_w = (const float*)d_in[1];
  const float* cv1_b = (const float*)d_in[2];
  const float* fm_w1 = (const float*)d_in[3];
  const float* fm_w2 = (const float*)d_in[4];
  const float* ca_w1 = (const float*)d_in[5];
  const float* ca_w2 = (const float*)d_in[6];
  const float* qkv_w = (const float*)d_in[7];
  const float* tproj_w = (const float*)d_in[8];
  const float* tproj_b = (const float*)d_in[9];
  const float* dw_w = (const float*)d_in[10];
  const float* dw_b = (const float*)d_in[11];
  const float* rt_w = (const float*)d_in[12];
  const float* rt_b = (const float*)d_in[13];
  const float* q_w = (const float*)d_in[14];
  const float* k_w = (const float*)d_in[15];
  const float* v_w = (const float*)d_in[16];
  const float* sproj_w = (const float*)d_in[17];
  const float* sproj_b = (const float*)d_in[18];
  const float* cv2_w = (const float*)d_in[19];
  const float* cv2_b = (const float*)d_in[20];
  float* out = (float*)d_out;

  char* wsp = (char*)d_ws;
  size_t off = 0;
  auto alloc = [&](size_t bytes) {
    void* p = wsp + off;
    off += (bytes + 255) & ~(size_t)255;
    return p;
  };
  float* yc = (float*)alloc(8UL * 384 * 1024 * 4);
  float* qkvb = (float*)alloc(8UL * 384 * 1024 * 4);
  float* to_cn = (float*)alloc(8UL * 128 * 1024 * 4);
  float* qv = (float*)alloc(8UL * 128 * 1024 * 4);
  float* kv = (float*)alloc(8UL * 128 * 1024 * 4);
  float* vvb = (float*)alloc(8UL * 128 * 1024 * 4);
  float* var_k = (float*)alloc(8UL * 8 * 1024 * 4);
  float* var_v = (float*)alloc(8UL * 8 * 1024 * 4);
  float* maxvk = (float*)alloc(64 * 4);
  float* pooled = (float*)alloc(1024 * 4);
  float* m1 = (float*)alloc(1024 * 4);
  float* g = (float*)alloc(1024 * 4);
  float* alpha = (float*)alloc(8 * 4);
  unsigned long long* qbits = (unsigned long long*)alloc(8192UL * 2 * 8);
  unsigned long long* kbits = (unsigned long long*)alloc(8192UL * 2 * 8);
  float* rinvd = (float*)alloc(8192 * 4);
  float* obv = qv;    // alias: qv dead after pack
  float* obp = kv;    // alias: kv dead after pack
  float* xl = to_cn;  // alias: to_cn dead after tproj
  if (off > ws_size) return;

  dim3 blk(256);
  // 1. cv1: yc[:,0:256,:] = cv1_w @ x + cv1_b
  gemm_kernel<true, false><<<dim3(16, 4, 8), blk, 0, stream>>>(
      cv1_w, x, cv1_b, nullptr, yc, 256, 1024, 256, 256L * 1024, 384L * 1024, 0);
  // 2. FFT pooling + channel means
  fftpool_kernel<<<dim3(1024), blk, 0, stream>>>(yc, pooled, m1);
  // 3. gates
  gates_kernel<<<dim3(8), dim3(128), 0, stream>>>(pooled, m1, fm_w1, fm_w2,
                                                  ca_w1, ca_w2, rt_w, rt_b, g, alpha);
  // 4. qkv projection
  gemm_kernel<false, false><<<dim3(16, 6, 8), blk, 0, stream>>>(
      qkv_w, yc + 128 * 1024, nullptr, nullptr, qkvb, 384, 1024, 128,
      384L * 1024, 384L * 1024, 0);
  // 5-6. variances + max
  var_kernel<<<dim3(256), blk, 0, stream>>>(qkvb, var_k, var_v);
  maxvk_kernel<<<dim3(64), blk, 0, stream>>>(var_k, maxvk);
  // 7. stat attention
  stat_attn_kernel<<<dim3(64, 4), blk, 0, stream>>>(qkvb, var_k, var_v, maxvk, to_cn);
  // 8. tproj -> yc[:,256:384,:] (stat_out)
  gemm_kernel<true, false><<<dim3(16, 2, 8), blk, 0, stream>>>(
      tproj_w, to_cn, tproj_b, nullptr, yc + 256 * 1024, 128, 1024, 128,
      128L * 1024, 384L * 1024, 0);
  // 9. spatial q/k/v projections
  gemm_kernel<false, false><<<dim3(16, 2, 8), blk, 0, stream>>>(
      q_w, yc + 128 * 1024, nullptr, nullptr, qv, 128, 1024, 128,
      384L * 1024, 128L * 1024, 0);
  gemm_kernel<false, false><<<dim3(16, 2, 8), blk, 0, stream>>>(
      k_w, yc + 128 * 1024, nullptr, nullptr, kv, 128, 1024, 128,
      384L * 1024, 128L * 1024, 0);
  gemm_kernel<false, false><<<dim3(16, 2, 8), blk, 0, stream>>>(
      v_w, yc + 128 * 1024, nullptr, nullptr, vvb, 128, 1024, 128,
      384L * 1024, 128L * 1024, 0);
  // 10. sign pack
  pack_kernel<<<dim3(2048), blk, 0, stream>>>(qv, kv, qbits, kbits);
  // 11. softmax denominators (no max needed: |score| <= 11.32)
  denom_kernel<<<dim3(4, 8), blk, 0, stream>>>(qbits, kbits, rinvd);
  // 12. fused a2-gen + GEMM: ob = vv @ a2^T
  obgemm_kernel<<<dim3(16, 2, 8), blk, 0, stream>>>(vvb, qbits, kbits, rinvd, obv);
  // 13. sproj
  gemm_kernel<true, false><<<dim3(16, 2, 8), blk, 0, stream>>>(
      sproj_w, obv, sproj_b, nullptr, obp, 128, 1024, 128,
      128L * 1024, 128L * 1024, 0);
  // 14. depthwise conv
  dwconv_kernel<<<dim3(1024), blk, 0, stream>>>(yc, dw_w, dw_b, xl);
  // 15. combine freq + spat into yc attn region
  combine_kernel<<<dim3(4096), blk, 0, stream>>>(yc, xl, obp, g, alpha);
  // 16. cv2 + residual
  gemm_kernel<true, true><<<dim3(16, 4, 8), blk, 0, stream>>>(
      cv2_w, yc, cv2_b, x, out, 256, 1024, 384, 384L * 1024, 256L * 1024,
      256L * 1024);
}

// Round 6
// 285.237 us; speedup vs baseline: 1.4786x; 1.2502x over previous
//
#include <hip/hip_runtime.h>
#include <math.h>

// Problem constants
#define BATCH 8
#define C1C 256
#define C2C 256
#define CC 128
#define NPIX 1024   // 32*32
#define NH 8        // heads
#define HDD 16      // head dim

// ---------------------------------------------------------------------------
// Generic batched GEMM: Y[b] (M x N) = W (M x K) @ X[b] (K x N) (+bias) (+res)
// Tile 64x64, K-chunk 16, 256 threads, 4x4 micro-tile per thread.
// ---------------------------------------------------------------------------
template<bool HAS_BIAS, bool HAS_RES>
__global__ __launch_bounds__(256) void gemm_kernel(
    const float* __restrict__ W, const float* __restrict__ X,
    const float* __restrict__ bias, const float* __restrict__ res,
    float* __restrict__ Y, int M, int Nn, int K, long sX, long sY, long sR) {
  __shared__ float Ws[16][68];
  __shared__ float Xs[16][68];
  const int b = blockIdx.z;
  const float* Xb = X + (long)b * sX;
  float* Yb = Y + (long)b * sY;
  const int m0 = blockIdx.y * 64, n0 = blockIdx.x * 64;
  const int tid = threadIdx.x;
  const int tx = tid & 15, ty = tid >> 4;
  float acc[4][4] = {};
  for (int k0 = 0; k0 < K; k0 += 16) {
    {
      int r = tid >> 2;
      int c4 = (tid & 3) * 4;
      const float4 wv = *(const float4*)(W + (long)(m0 + r) * K + k0 + c4);
      Ws[c4 + 0][r] = wv.x; Ws[c4 + 1][r] = wv.y;
      Ws[c4 + 2][r] = wv.z; Ws[c4 + 3][r] = wv.w;
    }
    {
      int r = tid >> 4;
      int cR = (tid & 15) * 4;
      const float4 xv = *(const float4*)(Xb + (long)(k0 + r) * Nn + n0 + cR);
      *(float4*)&Xs[r][cR] = xv;
    }
    __syncthreads();
#pragma unroll
    for (int kk = 0; kk < 16; kk++) {
      float a[4], bx[4];
#pragma unroll
      for (int i = 0; i < 4; i++) a[i] = Ws[kk][ty * 4 + i];
#pragma unroll
      for (int j = 0; j < 4; j++) bx[j] = Xs[kk][tx * 4 + j];
#pragma unroll
      for (int i = 0; i < 4; i++)
#pragma unroll
        for (int j = 0; j < 4; j++) acc[i][j] += a[i] * bx[j];
    }
    __syncthreads();
  }
#pragma unroll
  for (int i = 0; i < 4; i++) {
    int m = m0 + ty * 4 + i;
    float bv = HAS_BIAS ? bias[m] : 0.f;
#pragma unroll
    for (int j = 0; j < 4; j++) {
      int n = n0 + tx * 4 + j;
      float v = acc[i][j] + bv;
      if (HAS_RES) v += res[(long)b * sR + (long)m * Nn + n];
      Yb[(long)m * Nn + n] = v;
    }
  }
}

// ---------------------------------------------------------------------------
// Concatenate spatial q/k/v weights into one [384][128] matrix (replaces
// hipMemcpyAsync D2D to avoid any graph-capture risk).
// ---------------------------------------------------------------------------
__global__ __launch_bounds__(256) void fuse_w_kernel(
    const float* __restrict__ q_w, const float* __restrict__ k_w,
    const float* __restrict__ v_w, float* __restrict__ skv_w) {
  int i = blockIdx.x * 256 + threadIdx.x;  // 0 .. 3*16384-1
  int which = i >> 14, r = i & 16383;
  float v = (which == 0) ? q_w[r] : (which == 1) ? k_w[r] : v_w[r];
  skv_w[i] = v;
}

// ---------------------------------------------------------------------------
// FFT magnitude pooling: pooled[b,c] = mean |rfft2(y1[b,c], ortho)| over 32x17
// Also m1[b,c] = mean(y1[b,c]).  One block per (b,c) image.
// ---------------------------------------------------------------------------
__global__ __launch_bounds__(256) void fftpool_kernel(
    const float* __restrict__ yc, float* __restrict__ pooled, float* __restrict__ m1) {
  const int bc = blockIdx.x;
  const int b = bc >> 7, cx = bc & 127;
  const float* img = yc + ((long)b * 384 + 128 + cx) * NPIX;
  __shared__ float im[1024];
  __shared__ float Gr[32][17], Gi[32][17];
  __shared__ float cs[32], sn[32];
  __shared__ float red[256];
  const int t = threadIdx.x;
  if (t < 32) {
    float ang = -0.19634954084936207f * (float)t;  // -2*pi*t/32
    __sincosf(ang, &sn[t], &cs[t]);
  }
  float lsum = 0.f;
  for (int i = t; i < 1024; i += 256) { float v = img[i]; im[i] = v; lsum += v; }
  red[t] = lsum;
  __syncthreads();
  for (int s = 128; s > 0; s >>= 1) {
    if (t < s) red[t] += red[t + s];
    __syncthreads();
  }
  if (t == 0) m1[bc] = red[0] * (1.f / 1024.f);
  // stage 1: along w
  for (int i = t; i < 544; i += 256) {
    int h = i / 17, v = i % 17;
    float ar = 0.f, ai = 0.f;
    for (int w2 = 0; w2 < 32; w2++) {
      int k = (v * w2) & 31;
      float x = im[h * 32 + w2];
      ar += x * cs[k]; ai += x * sn[k];
    }
    Gr[h][v] = ar; Gi[h][v] = ai;
  }
  __syncthreads();
  // stage 2: along h, accumulate |X|
  float asum = 0.f;
  for (int i = t; i < 544; i += 256) {
    int u = i / 17, v = i % 17;
    float xr = 0.f, xi = 0.f;
    for (int h = 0; h < 32; h++) {
      int k = (u * h) & 31;
      float gr = Gr[h][v], gi = Gi[h][v];
      xr += gr * cs[k] - gi * sn[k];
      xi += gr * sn[k] + gi * cs[k];
    }
    asum += sqrtf(xr * xr + xi * xi);
  }
  red[t] = asum;
  __syncthreads();
  for (int s = 128; s > 0; s >>= 1) {
    if (t < s) red[t] += red[t + s];
    __syncthreads();
  }
  if (t == 0) pooled[bc] = red[0] * (1.f / (32.f * 544.f));
}

// ---------------------------------------------------------------------------
// Gates: fw/ca MLPs -> g = fw*ca; p_route -> alpha.  One block per batch.
// ---------------------------------------------------------------------------
__global__ __launch_bounds__(128) void gates_kernel(
    const float* __restrict__ pooled, const float* __restrict__ m1,
    const float* __restrict__ fm_w1, const float* __restrict__ fm_w2,
    const float* __restrict__ ca_w1, const float* __restrict__ ca_w2,
    const float* __restrict__ rt_w, const float* __restrict__ rt_b,
    float* __restrict__ g, float* __restrict__ alpha) {
  const int b = blockIdx.x, t = threadIdx.x;
  __shared__ float h1[8], fwv[128], xsm[128], h2[8];
  const float* pb = pooled + b * 128;
  const float* mb = m1 + b * 128;
  if (t < 8) {
    float s = 0.f;
    for (int c = 0; c < 128; c++) s += pb[c] * fm_w1[t * 128 + c];
    h1[t] = fmaxf(s, 0.f);
  }
  __syncthreads();
  {
    float s = 0.f;
    for (int r = 0; r < 8; r++) s += h1[r] * fm_w2[t * 8 + r];
    float fw = 1.f / (1.f + __expf(-s));
    fwv[t] = fw; xsm[t] = fw * mb[t];
  }
  __syncthreads();
  if (t < 8) {
    float s = 0.f;
    for (int c = 0; c < 128; c++) s += xsm[c] * ca_w1[t * 128 + c];
    h2[t] = fmaxf(s, 0.f);
  }
  __syncthreads();
  {
    float s = 0.f;
    for (int r = 0; r < 8; r++) s += h2[r] * ca_w2[t * 8 + r];
    float ca = 1.f / (1.f + __expf(-s));
    g[b * 128 + t] = fwv[t] * ca;
  }
  if (t == 0) {
    float s = 0.f;
    for (int c = 0; c < 128; c++) s += mb[c] * rt_w[c];
    s += rt_b[0];
    alpha[b] = 1.f / (1.f + __expf(-s));
  }
}

// ---------------------------------------------------------------------------
// Variance of k and v head vectors (ddof=1) + per-bh max(var_k).
// One block per bh; thread handles 4 n's.
// ---------------------------------------------------------------------------
__global__ __launch_bounds__(256) void varmax_kernel(
    const float* __restrict__ qkvb, float* __restrict__ var_k,
    float* __restrict__ var_v, float* __restrict__ maxvk) {
  const int bh = blockIdx.x;
  const int b = bh >> 3, h = bh & 7;
  __shared__ float red[256];
  const float* kb = qkvb + ((long)b * 384 + 128 + h * 16) * NPIX;
  const float* vb = qkvb + ((long)b * 384 + 256 + h * 16) * NPIX;
  float mx = 0.f;
  for (int j = 0; j < 4; j++) {
    int n = threadIdx.x + j * 256;
    float xk[16], xv[16], sk = 0.f, sv = 0.f;
#pragma unroll
    for (int d = 0; d < 16; d++) {
      xk[d] = kb[(long)d * NPIX + n]; sk += xk[d];
      xv[d] = vb[(long)d * NPIX + n]; sv += xv[d];
    }
    float mk = sk * (1.f / 16.f), mv = sv * (1.f / 16.f);
    float vk_ = 0.f, vv_ = 0.f;
#pragma unroll
    for (int d = 0; d < 16; d++) {
      float a = xk[d] - mk; vk_ += a * a;
      float c = xv[d] - mv; vv_ += c * c;
    }
    vk_ *= (1.f / 15.f); vv_ *= (1.f / 15.f);
    var_k[(long)bh * NPIX + n] = vk_;
    var_v[(long)bh * NPIX + n] = vv_;
    mx = fmaxf(mx, vk_);
  }
  red[threadIdx.x] = mx;
  __syncthreads();
  for (int s = 128; s > 0; s >>= 1) {
    if (threadIdx.x < s) red[threadIdx.x] = fmaxf(red[threadIdx.x], red[threadIdx.x + s]);
    __syncthreads();
  }
  if (threadIdx.x == 0) maxvk[bh] = red[0];
}

// ---------------------------------------------------------------------------
// Stat attention: to[b,h,n,:] = sum_m softmax_m(cn*vk[m]) * v[b,h,m,:]
// Grid (64 bh, 8 n-chunks of 128); thread = (n, d-half of 8).
// Inner loop per m: 1 vk broadcast + exp + 2 ds_read_b128 + 8 FMA.
// ---------------------------------------------------------------------------
__global__ __launch_bounds__(256) void stat_attn_kernel(
    const float* __restrict__ qkvb, const float* __restrict__ var_k,
    const float* __restrict__ var_v, const float* __restrict__ maxvk,
    float* __restrict__ to_cn) {
  const int bh = blockIdx.x;
  const int b = bh >> 3, h = bh & 7;
  const int tid = threadIdx.x;
  const int nl = tid & 127, dh = tid >> 7;
  const int n = blockIdx.y * 128 + nl;
  __shared__ float vk[NPIX];
  __shared__ float vs[256][20];  // 80B rows: 16B-aligned for b128 reads
  const float* vbase = qkvb + ((long)b * 384 + 256 + h * 16) * NPIX;
  for (int i = tid; i < NPIX; i += 256) vk[i] = var_k[(long)bh * NPIX + i];
  const float cn = var_v[(long)bh * NPIX + n] * 0.25f;
  const float mv = maxvk[bh];
  float denom = 0.f;
  float acc[8];
#pragma unroll
  for (int j = 0; j < 8; j++) acc[j] = 0.f;
  for (int m0 = 0; m0 < NPIX; m0 += 256) {
    __syncthreads();
    // stage V chunk: pass p loads row d=p coalesced, writes column d of vs
#pragma unroll
    for (int p = 0; p < 16; p++) vs[tid][p] = vbase[(long)p * NPIX + m0 + tid];
    __syncthreads();
#pragma unroll 4
    for (int mm = 0; mm < 256; mm++) {
      float w = __expf(cn * (vk[m0 + mm] - mv));
      denom += w;
      const float4 vA = *(const float4*)&vs[mm][dh * 8];
      const float4 vB = *(const float4*)&vs[mm][dh * 8 + 4];
      acc[0] += w * vA.x; acc[1] += w * vA.y; acc[2] += w * vA.z; acc[3] += w * vA.w;
      acc[4] += w * vB.x; acc[5] += w * vB.y; acc[6] += w * vB.z; acc[7] += w * vB.w;
    }
  }
  float inv = 1.f / denom;
#pragma unroll
  for (int j = 0; j < 8; j++)
    to_cn[((long)b * CC + h * 16 + dh * 8 + j) * NPIX + n] = acc[j] * inv;
}

// ---------------------------------------------------------------------------
// Bit-pack signs of fused spatial q/k projections (sqkv rows 0-127 = q,
// 128-255 = k). Wave per (b,n); ballot packs 64.
// ---------------------------------------------------------------------------
__global__ __launch_bounds__(256) void pack_kernel(
    const float* __restrict__ sqkv,
    unsigned long long* __restrict__ qbits, unsigned long long* __restrict__ kbits) {
  const int wave = threadIdx.x >> 6, lane = threadIdx.x & 63;
  const long p = (long)blockIdx.x * 4 + wave;  // 0..8191
  const int b = (int)(p >> 10), n = (int)(p & 1023);
  const float* base = sqkv + (long)b * 384 * NPIX + n;
  unsigned long long q0 = __ballot(base[(long)lane * NPIX] > 0.f);
  unsigned long long q1 = __ballot(base[(long)(64 + lane) * NPIX] > 0.f);
  unsigned long long k0 = __ballot(base[(long)(128 + lane) * NPIX] > 0.f);
  unsigned long long k1 = __ballot(base[(long)(192 + lane) * NPIX] > 0.f);
  if (lane == 0) {
    qbits[p * 2] = q0; qbits[p * 2 + 1] = q1;
    kbits[p * 2] = k0; kbits[p * 2 + 1] = k1;
  }
}

// ---------------------------------------------------------------------------
// Fused binary-attention GEMM with in-kernel softmax denominators:
// ob[b,c,n] = (sum_m vv[b,c,m] * w[m,n]) / (sum_m w[m,n]),
// w[m,n] = exp((128-2*popc(q[n]^k[m]))/sqrt(128)) synthesized on the fly.
// Scores bounded by ±11.32 so exp is fp32-safe unnormalized.
// vv = sqkv rows 256..383 (b-stride 384*1024).
// ---------------------------------------------------------------------------
__global__ __launch_bounds__(256) void obgemm_kernel(
    const float* __restrict__ vv, const unsigned long long* __restrict__ qbits,
    const unsigned long long* __restrict__ kbits, float* __restrict__ ob) {
  const int b = blockIdx.z;
  const int c0 = blockIdx.y * 64, n0 = blockIdx.x * 64;
  __shared__ float Ws[16][68];
  __shared__ float Xs[16][68];
  __shared__ float psum[16][68];
  __shared__ unsigned long long qn[64][2];
  __shared__ float rd[64];
  const int tid = threadIdx.x;
  if (tid < 64) {
    qn[tid][0] = qbits[((long)b * 1024 + n0 + tid) * 2];
    qn[tid][1] = qbits[((long)b * 1024 + n0 + tid) * 2 + 1];
  }
  __syncthreads();
  const int tx = tid & 15, ty = tid >> 4;
  const float fs = 0.08838834764831845f;
  float acc[4][4] = {};
  float pcs[4] = {};
  for (int k0 = 0; k0 < 1024; k0 += 16) {
    {
      int r = tid >> 2, c4 = (tid & 3) * 4;
      const float4 wv = *(const float4*)(vv + ((long)b * 384 + c0 + r) * 1024 + k0 + c4);
      Ws[c4 + 0][r] = wv.x; Ws[c4 + 1][r] = wv.y;
      Ws[c4 + 2][r] = wv.z; Ws[c4 + 3][r] = wv.w;
    }
    {
      int kr = tid >> 4, nc = (tid & 15) * 4;
      unsigned long long kb0 = kbits[((long)b * 1024 + k0 + kr) * 2];
      unsigned long long kb1 = kbits[((long)b * 1024 + k0 + kr) * 2 + 1];
#pragma unroll
      for (int j = 0; j < 4; j++) {
        int ham = __popcll(qn[nc + j][0] ^ kb0) + __popcll(qn[nc + j][1] ^ kb1);
        float w = __expf((float)(128 - 2 * ham) * fs);
        Xs[kr][nc + j] = w;
        pcs[j] += w;
      }
    }
    __syncthreads();
#pragma unroll
    for (int kk = 0; kk < 16; kk++) {
      float a[4], bx[4];
#pragma unroll
      for (int i = 0; i < 4; i++) a[i] = Ws[kk][ty * 4 + i];
#pragma unroll
      for (int j = 0; j < 4; j++) bx[j] = Xs[kk][tx * 4 + j];
#pragma unroll
      for (int i = 0; i < 4; i++)
#pragma unroll
        for (int j = 0; j < 4; j++) acc[i][j] += a[i] * bx[j];
    }
    __syncthreads();
  }
  // denominators: reduce per-thread column partials (kr slices cover all m)
  {
    int kr = tid >> 4, nc = (tid & 15) * 4;
#pragma unroll
    for (int j = 0; j < 4; j++) psum[kr][nc + j] = pcs[j];
  }
  __syncthreads();
  if (tid < 64) {
    float d = 0.f;
#pragma unroll
    for (int r = 0; r < 16; r++) d += psum[r][tid];
    rd[tid] = 1.f / d;
  }
  __syncthreads();
#pragma unroll
  for (int i = 0; i < 4; i++)
#pragma unroll
    for (int j = 0; j < 4; j++)
      ob[((long)b * 128 + c0 + ty * 4 + i) * 1024 + n0 + tx * 4 + j] =
          acc[i][j] * rd[tx * 4 + j];
}

// ---------------------------------------------------------------------------
// Depthwise 3x3 conv (SAME, zero pad). One block per (b,c).
// ---------------------------------------------------------------------------
__global__ __launch_bounds__(256) void dwconv_kernel(
    const float* __restrict__ yc, const float* __restrict__ dw_w,
    const float* __restrict__ dw_b, float* __restrict__ xl) {
  const int bc = blockIdx.x;
  const int b = bc >> 7, cx = bc & 127;
  const float* img = yc + ((long)b * 384 + 128 + cx) * NPIX;
  float w[9];
#pragma unroll
  for (int i = 0; i < 9; i++) w[i] = dw_w[cx * 9 + i];
  const float bias = dw_b[cx];
  for (int i = threadIdx.x; i < 1024; i += 256) {
    int h = i >> 5, wx = i & 31;
    float s = bias;
#pragma unroll
    for (int ky = 0; ky < 3; ky++) {
      int hh = h + ky - 1;
      if (hh < 0 || hh > 31) continue;
#pragma unroll
      for (int kx = 0; kx < 3; kx++) {
        int ww2 = wx + kx - 1;
        if (ww2 < 0 || ww2 > 31) continue;
        s += img[hh * 32 + ww2] * w[ky * 3 + kx];
      }
    }
    xl[(long)bc * NPIX + i] = s;
  }
}

// ---------------------------------------------------------------------------
// Combine: yc[b,256+c,n] += g*y1 + (1-a)*xl + a*obp
// ---------------------------------------------------------------------------
__global__ __launch_bounds__(256) void combine_kernel(
    float* __restrict__ yc, const float* __restrict__ xl, const float* __restrict__ obp,
    const float* __restrict__ g, const float* __restrict__ alpha) {
  long i = (long)blockIdx.x * 256 + threadIdx.x;  // B*128*1024
  int n = (int)(i & 1023);
  long bc = i >> 10;
  int b = (int)(bc >> 7), cx = (int)(bc & 127);
  float a = alpha[b];
  float y1v = yc[((long)b * 384 + 128 + cx) * NPIX + n];
  long oidx = ((long)b * 384 + 256 + cx) * NPIX + n;
  yc[oidx] = yc[oidx] + g[bc] * y1v + (1.f - a) * xl[i] + a * obp[i];
}

// ---------------------------------------------------------------------------
extern "C" void kernel_launch(void* const* d_in, const int* in_sizes, int n_in,
                              void* d_out, int out_size, void* d_ws, size_t ws_size,
                              hipStream_t stream) {
  const float* x = (const float*)d_in[0];
  const float* cv1_w = (const float*)d_in[1];
  const float* cv1_b = (const float*)d_in[2];
  const float* fm_w1 = (const float*)d_in[3];
  const float* fm_w2 = (const float*)d_in[4];
  const float* ca_w1 = (const float*)d_in[5];
  const float* ca_w2 = (const float*)d_in[6];
  const float* qkv_w = (const float*)d_in[7];
  const float* tproj_w = (const float*)d_in[8];
  const float* tproj_b = (const float*)d_in[9];
  const float* dw_w = (const float*)d_in[10];
  const float* dw_b = (const float*)d_in[11];
  const float* rt_w = (const float*)d_in[12];
  const float* rt_b = (const float*)d_in[13];
  const float* q_w = (const float*)d_in[14];
  const float* k_w = (const float*)d_in[15];
  const float* v_w = (const float*)d_in[16];
  const float* sproj_w = (const float*)d_in[17];
  const float* sproj_b = (const float*)d_in[18];
  const float* cv2_w = (const float*)d_in[19];
  const float* cv2_b = (const float*)d_in[20];
  float* out = (float*)d_out;

  char* wsp = (char*)d_ws;
  size_t off = 0;
  auto alloc = [&](size_t bytes) {
    void* p = wsp + off;
    off += (bytes + 255) & ~(size_t)255;
    return p;
  };
  float* yc = (float*)alloc(8UL * 384 * 1024 * 4);
  float* qkvb = (float*)alloc(8UL * 384 * 1024 * 4);
  float* to_cn = (float*)alloc(8UL * 128 * 1024 * 4);
  float* sqkv = (float*)alloc(8UL * 384 * 1024 * 4);
  float* skv_w = (float*)alloc(384UL * 128 * 4);
  float* var_k = (float*)alloc(8UL * 8 * 1024 * 4);
  float* var_v = (float*)alloc(8UL * 8 * 1024 * 4);
  float* maxvk = (float*)alloc(64 * 4);
  float* pooled = (float*)alloc(1024 * 4);
  float* m1 = (float*)alloc(1024 * 4);
  float* g = (float*)alloc(1024 * 4);
  float* alpha = (float*)alloc(8 * 4);
  unsigned long long* qbits = (unsigned long long*)alloc(8192UL * 2 * 8);
  unsigned long long* kbits = (unsigned long long*)alloc(8192UL * 2 * 8);
  // aliases into qkvb (dead after stat_attn):
  float* obv = qkvb;                    // [8][128][1024]
  float* obp = qkvb + 8L * 128 * 1024;  // [8][128][1024]
  float* xl = to_cn;                    // dead after tproj
  if (off > ws_size) return;

  dim3 blk(256);
  // 0. fuse spatial q/k/v weights into one [384][128] matrix
  fuse_w_kernel<<<dim3(192), blk, 0, stream>>>(q_w, k_w, v_w, skv_w);
  // 1. cv1: yc[:,0:256,:] = cv1_w @ x + cv1_b
  gemm_kernel<true, false><<<dim3(16, 4, 8), blk, 0, stream>>>(
      cv1_w, x, cv1_b, nullptr, yc, 256, 1024, 256, 256L * 1024, 384L * 1024, 0);
  // 2. FFT pooling + channel means
  fftpool_kernel<<<dim3(1024), blk, 0, stream>>>(yc, pooled, m1);
  // 3. gates
  gates_kernel<<<dim3(8), dim3(128), 0, stream>>>(pooled, m1, fm_w1, fm_w2,
                                                  ca_w1, ca_w2, rt_w, rt_b, g, alpha);
  // 4. qkv projection (stat attention)
  gemm_kernel<false, false><<<dim3(16, 6, 8), blk, 0, stream>>>(
      qkv_w, yc + 128 * 1024, nullptr, nullptr, qkvb, 384, 1024, 128,
      384L * 1024, 384L * 1024, 0);
  // 5. variances + per-bh max
  varmax_kernel<<<dim3(64), blk, 0, stream>>>(qkvb, var_k, var_v, maxvk);
  // 6. stat attention
  stat_attn_kernel<<<dim3(64, 8), blk, 0, stream>>>(qkvb, var_k, var_v, maxvk, to_cn);
  // 7. tproj -> yc[:,256:384,:] (stat_out)
  gemm_kernel<true, false><<<dim3(16, 2, 8), blk, 0, stream>>>(
      tproj_w, to_cn, tproj_b, nullptr, yc + 256 * 1024, 128, 1024, 128,
      128L * 1024, 384L * 1024, 0);
  // 8. fused spatial q/k/v projection
  gemm_kernel<false, false><<<dim3(16, 6, 8), blk, 0, stream>>>(
      skv_w, yc + 128 * 1024, nullptr, nullptr, sqkv, 384, 1024, 128,
      384L * 1024, 384L * 1024, 0);
  // 9. sign pack
  pack_kernel<<<dim3(2048), blk, 0, stream>>>(sqkv, qbits, kbits);
  // 10. fused a2-gen + denom + GEMM: ob = (vv @ w) / colsum(w)
  obgemm_kernel<<<dim3(16, 2, 8), blk, 0, stream>>>(sqkv, qbits, kbits, obv);
  // 11. sproj
  gemm_kernel<true, false><<<dim3(16, 2, 8), blk, 0, stream>>>(
      sproj_w, obv, sproj_b, nullptr, obp, 128, 1024, 128,
      128L * 1024, 128L * 1024, 0);
  // 12. depthwise conv
  dwconv_kernel<<<dim3(1024), blk, 0, stream>>>(yc, dw_w, dw_b, xl);
  // 13. combine freq + spat into yc attn region
  combine_kernel<<<dim3(4096), blk, 0, stream>>>(yc, xl, obp, g, alpha);
  // 14. cv2 + residual
  gemm_kernel<true, true><<<dim3(16, 4, 8), blk, 0, stream>>>(
      cv2_w, yc, cv2_b, x, out, 256, 1024, 384, 384L * 1024, 256L * 1024,
      256L * 1024);
}

// Round 7
// 275.526 us; speedup vs baseline: 1.5307x; 1.0352x over previous
//
#include <hip/hip_runtime.h>
#include <math.h>

// Problem constants
#define BATCH 8
#define C1C 256
#define C2C 256
#define CC 128
#define NPIX 1024   // 32*32
#define NH 8        // heads
#define HDD 16      // head dim

// ---------------------------------------------------------------------------
// Generic batched GEMM: Y[b] (M x N) = W (M x K) @ X[b] (K x N) (+bias) (+res)
// Tile 64x64, K-chunk 16, 256 threads, 4x4 micro-tile per thread.
// ---------------------------------------------------------------------------
template<bool HAS_BIAS, bool HAS_RES>
__global__ __launch_bounds__(256) void gemm_kernel(
    const float* __restrict__ W, const float* __restrict__ X,
    const float* __restrict__ bias, const float* __restrict__ res,
    float* __restrict__ Y, int M, int Nn, int K, long sX, long sY, long sR) {
  __shared__ float Ws[16][68];
  __shared__ float Xs[16][68];
  const int b = blockIdx.z;
  const float* Xb = X + (long)b * sX;
  float* Yb = Y + (long)b * sY;
  const int m0 = blockIdx.y * 64, n0 = blockIdx.x * 64;
  const int tid = threadIdx.x;
  const int tx = tid & 15, ty = tid >> 4;
  float acc[4][4] = {};
  for (int k0 = 0; k0 < K; k0 += 16) {
    {
      int r = tid >> 2;
      int c4 = (tid & 3) * 4;
      const float4 wv = *(const float4*)(W + (long)(m0 + r) * K + k0 + c4);
      Ws[c4 + 0][r] = wv.x; Ws[c4 + 1][r] = wv.y;
      Ws[c4 + 2][r] = wv.z; Ws[c4 + 3][r] = wv.w;
    }
    {
      int r = tid >> 4;
      int cR = (tid & 15) * 4;
      const float4 xv = *(const float4*)(Xb + (long)(k0 + r) * Nn + n0 + cR);
      *(float4*)&Xs[r][cR] = xv;
    }
    __syncthreads();
#pragma unroll
    for (int kk = 0; kk < 16; kk++) {
      float a[4], bx[4];
#pragma unroll
      for (int i = 0; i < 4; i++) a[i] = Ws[kk][ty * 4 + i];
#pragma unroll
      for (int j = 0; j < 4; j++) bx[j] = Xs[kk][tx * 4 + j];
#pragma unroll
      for (int i = 0; i < 4; i++)
#pragma unroll
        for (int j = 0; j < 4; j++) acc[i][j] += a[i] * bx[j];
    }
    __syncthreads();
  }
#pragma unroll
  for (int i = 0; i < 4; i++) {
    int m = m0 + ty * 4 + i;
    float bv = HAS_BIAS ? bias[m] : 0.f;
#pragma unroll
    for (int j = 0; j < 4; j++) {
      int n = n0 + tx * 4 + j;
      float v = acc[i][j] + bv;
      if (HAS_RES) v += res[(long)b * sR + (long)m * Nn + n];
      Yb[(long)m * Nn + n] = v;
    }
  }
}

// ---------------------------------------------------------------------------
// Concatenate spatial q/k/v weights into one [384][128] matrix.
// ---------------------------------------------------------------------------
__global__ __launch_bounds__(256) void fuse_w_kernel(
    const float* __restrict__ q_w, const float* __restrict__ k_w,
    const float* __restrict__ v_w, float* __restrict__ skv_w) {
  int i = blockIdx.x * 256 + threadIdx.x;  // 0 .. 3*16384-1
  int which = i >> 14, r = i & 16383;
  float v = (which == 0) ? q_w[r] : (which == 1) ? k_w[r] : v_w[r];
  skv_w[i] = v;
}

// ---------------------------------------------------------------------------
// FFT magnitude pooling: pooled[b,c] = mean |rfft2(y1[b,c], ortho)| over 32x17
// Also m1[b,c] = mean(y1[b,c]).  One block per (b,c) image.
// ---------------------------------------------------------------------------
__global__ __launch_bounds__(256) void fftpool_kernel(
    const float* __restrict__ yc, float* __restrict__ pooled, float* __restrict__ m1) {
  const int bc = blockIdx.x;
  const int b = bc >> 7, cx = bc & 127;
  const float* img = yc + ((long)b * 384 + 128 + cx) * NPIX;
  __shared__ float im[1024];
  __shared__ float Gr[32][17], Gi[32][17];
  __shared__ float cs[32], sn[32];
  __shared__ float red[256];
  const int t = threadIdx.x;
  if (t < 32) {
    float ang = -0.19634954084936207f * (float)t;  // -2*pi*t/32
    __sincosf(ang, &sn[t], &cs[t]);
  }
  float lsum = 0.f;
  for (int i = t; i < 1024; i += 256) { float v = img[i]; im[i] = v; lsum += v; }
  red[t] = lsum;
  __syncthreads();
  for (int s = 128; s > 0; s >>= 1) {
    if (t < s) red[t] += red[t + s];
    __syncthreads();
  }
  if (t == 0) m1[bc] = red[0] * (1.f / 1024.f);
  // stage 1: along w
  for (int i = t; i < 544; i += 256) {
    int h = i / 17, v = i % 17;
    float ar = 0.f, ai = 0.f;
    for (int w2 = 0; w2 < 32; w2++) {
      int k = (v * w2) & 31;
      float x = im[h * 32 + w2];
      ar += x * cs[k]; ai += x * sn[k];
    }
    Gr[h][v] = ar; Gi[h][v] = ai;
  }
  __syncthreads();
  // stage 2: along h, accumulate |X|
  float asum = 0.f;
  for (int i = t; i < 544; i += 256) {
    int u = i / 17, v = i % 17;
    float xr = 0.f, xi = 0.f;
    for (int h = 0; h < 32; h++) {
      int k = (u * h) & 31;
      float gr = Gr[h][v], gi = Gi[h][v];
      xr += gr * cs[k] - gi * sn[k];
      xi += gr * sn[k] + gi * cs[k];
    }
    asum += sqrtf(xr * xr + xi * xi);
  }
  red[t] = asum;
  __syncthreads();
  for (int s = 128; s > 0; s >>= 1) {
    if (t < s) red[t] += red[t + s];
    __syncthreads();
  }
  if (t == 0) pooled[bc] = red[0] * (1.f / (32.f * 544.f));
}

// ---------------------------------------------------------------------------
// Gates: fw/ca MLPs -> g = fw*ca; p_route -> alpha.  One block per batch.
// ---------------------------------------------------------------------------
__global__ __launch_bounds__(128) void gates_kernel(
    const float* __restrict__ pooled, const float* __restrict__ m1,
    const float* __restrict__ fm_w1, const float* __restrict__ fm_w2,
    const float* __restrict__ ca_w1, const float* __restrict__ ca_w2,
    const float* __restrict__ rt_w, const float* __restrict__ rt_b,
    float* __restrict__ g, float* __restrict__ alpha) {
  const int b = blockIdx.x, t = threadIdx.x;
  __shared__ float h1[8], fwv[128], xsm[128], h2[8];
  const float* pb = pooled + b * 128;
  const float* mb = m1 + b * 128;
  if (t < 8) {
    float s = 0.f;
    for (int c = 0; c < 128; c++) s += pb[c] * fm_w1[t * 128 + c];
    h1[t] = fmaxf(s, 0.f);
  }
  __syncthreads();
  {
    float s = 0.f;
    for (int r = 0; r < 8; r++) s += h1[r] * fm_w2[t * 8 + r];
    float fw = 1.f / (1.f + __expf(-s));
    fwv[t] = fw; xsm[t] = fw * mb[t];
  }
  __syncthreads();
  if (t < 8) {
    float s = 0.f;
    for (int c = 0; c < 128; c++) s += xsm[c] * ca_w1[t * 128 + c];
    h2[t] = fmaxf(s, 0.f);
  }
  __syncthreads();
  {
    float s = 0.f;
    for (int r = 0; r < 8; r++) s += h2[r] * ca_w2[t * 8 + r];
    float ca = 1.f / (1.f + __expf(-s));
    g[b * 128 + t] = fwv[t] * ca;
  }
  if (t == 0) {
    float s = 0.f;
    for (int c = 0; c < 128; c++) s += mb[c] * rt_w[c];
    s += rt_b[0];
    alpha[b] = 1.f / (1.f + __expf(-s));
  }
}

// ---------------------------------------------------------------------------
// Variance of k and v head vectors (ddof=1) + per-bh max(var_k).
// ---------------------------------------------------------------------------
__global__ __launch_bounds__(256) void varmax_kernel(
    const float* __restrict__ qkvb, float* __restrict__ var_k,
    float* __restrict__ var_v, float* __restrict__ maxvk) {
  const int bh = blockIdx.x;
  const int b = bh >> 3, h = bh & 7;
  __shared__ float red[256];
  const float* kb = qkvb + ((long)b * 384 + 128 + h * 16) * NPIX;
  const float* vb = qkvb + ((long)b * 384 + 256 + h * 16) * NPIX;
  float mx = 0.f;
  for (int j = 0; j < 4; j++) {
    int n = threadIdx.x + j * 256;
    float xk[16], xv[16], sk = 0.f, sv = 0.f;
#pragma unroll
    for (int d = 0; d < 16; d++) {
      xk[d] = kb[(long)d * NPIX + n]; sk += xk[d];
      xv[d] = vb[(long)d * NPIX + n]; sv += xv[d];
    }
    float mk = sk * (1.f / 16.f), mv = sv * (1.f / 16.f);
    float vk_ = 0.f, vv_ = 0.f;
#pragma unroll
    for (int d = 0; d < 16; d++) {
      float a = xk[d] - mk; vk_ += a * a;
      float c = xv[d] - mv; vv_ += c * c;
    }
    vk_ *= (1.f / 15.f); vv_ *= (1.f / 15.f);
    var_k[(long)bh * NPIX + n] = vk_;
    var_v[(long)bh * NPIX + n] = vv_;
    mx = fmaxf(mx, vk_);
  }
  red[threadIdx.x] = mx;
  __syncthreads();
  for (int s = 128; s > 0; s >>= 1) {
    if (threadIdx.x < s) red[threadIdx.x] = fmaxf(red[threadIdx.x], red[threadIdx.x + s]);
    __syncthreads();
  }
  if (threadIdx.x == 0) maxvk[bh] = red[0];
}

// ---------------------------------------------------------------------------
// Stat attention: to[b,h,n,:] = sum_m softmax_m(cn*vk[m]) * v[b,h,m,:]
// Grid (64 bh, 8 n-chunks of 128); thread = (n, d-half of 8).
// ---------------------------------------------------------------------------
__global__ __launch_bounds__(256) void stat_attn_kernel(
    const float* __restrict__ qkvb, const float* __restrict__ var_k,
    const float* __restrict__ var_v, const float* __restrict__ maxvk,
    float* __restrict__ to_cn) {
  const int bh = blockIdx.x;
  const int b = bh >> 3, h = bh & 7;
  const int tid = threadIdx.x;
  const int nl = tid & 127, dh = tid >> 7;
  const int n = blockIdx.y * 128 + nl;
  __shared__ float vk[NPIX];
  __shared__ float vs[256][20];  // 80B rows: 16B-aligned for b128 reads
  const float* vbase = qkvb + ((long)b * 384 + 256 + h * 16) * NPIX;
  for (int i = tid; i < NPIX; i += 256) vk[i] = var_k[(long)bh * NPIX + i];
  const float cn = var_v[(long)bh * NPIX + n] * 0.25f;
  const float mv = maxvk[bh];
  float denom = 0.f;
  float acc[8];
#pragma unroll
  for (int j = 0; j < 8; j++) acc[j] = 0.f;
  for (int m0 = 0; m0 < NPIX; m0 += 256) {
    __syncthreads();
#pragma unroll
    for (int p = 0; p < 16; p++) vs[tid][p] = vbase[(long)p * NPIX + m0 + tid];
    __syncthreads();
#pragma unroll 4
    for (int mm = 0; mm < 256; mm++) {
      float w = __expf(cn * (vk[m0 + mm] - mv));
      denom += w;
      const float4 vA = *(const float4*)&vs[mm][dh * 8];
      const float4 vB = *(const float4*)&vs[mm][dh * 8 + 4];
      acc[0] += w * vA.x; acc[1] += w * vA.y; acc[2] += w * vA.z; acc[3] += w * vA.w;
      acc[4] += w * vB.x; acc[5] += w * vB.y; acc[6] += w * vB.z; acc[7] += w * vB.w;
    }
  }
  float inv = 1.f / denom;
#pragma unroll
  for (int j = 0; j < 8; j++)
    to_cn[((long)b * CC + h * 16 + dh * 8 + j) * NPIX + n] = acc[j] * inv;
}

// ---------------------------------------------------------------------------
// Bit-pack signs of fused spatial q/k projections.
// ---------------------------------------------------------------------------
__global__ __launch_bounds__(256) void pack_kernel(
    const float* __restrict__ sqkv,
    unsigned long long* __restrict__ qbits, unsigned long long* __restrict__ kbits) {
  const int wave = threadIdx.x >> 6, lane = threadIdx.x & 63;
  const long p = (long)blockIdx.x * 4 + wave;  // 0..8191
  const int b = (int)(p >> 10), n = (int)(p & 1023);
  const float* base = sqkv + (long)b * 384 * NPIX + n;
  unsigned long long q0 = __ballot(base[(long)lane * NPIX] > 0.f);
  unsigned long long q1 = __ballot(base[(long)(64 + lane) * NPIX] > 0.f);
  unsigned long long k0 = __ballot(base[(long)(128 + lane) * NPIX] > 0.f);
  unsigned long long k1 = __ballot(base[(long)(192 + lane) * NPIX] > 0.f);
  if (lane == 0) {
    qbits[p * 2] = q0; qbits[p * 2 + 1] = q1;
    kbits[p * 2] = k0; kbits[p * 2 + 1] = k1;
  }
}

// ---------------------------------------------------------------------------
// Fused binary-attention GEMM, 512 threads (8 waves -> 2 waves/SIMD for
// latency hiding), K-chunk 32, 2x4 micro-tile.
// ob[b,c,n] = (sum_m vv[b,c,m] * w[m,n]) / (sum_m w[m,n]),
// w[m,n] = exp((128-2*popc(q[n]^k[m]))/sqrt(128)) synthesized on the fly.
// ---------------------------------------------------------------------------
__global__ __launch_bounds__(512) void obgemm_kernel(
    const float* __restrict__ vv, const unsigned long long* __restrict__ qbits,
    const unsigned long long* __restrict__ kbits, float* __restrict__ ob) {
  const int b = blockIdx.z;
  const int c0 = blockIdx.y * 64, n0 = blockIdx.x * 64;
  __shared__ float Ws[32][68];   // [k][c]
  __shared__ float Xs[32][68];   // [k][n]
  __shared__ unsigned long long qn[64][2];
  __shared__ float rd[64];
  const int tid = threadIdx.x;
  if (tid < 64) {
    qn[tid][0] = qbits[((long)b * 1024 + n0 + tid) * 2];
    qn[tid][1] = qbits[((long)b * 1024 + n0 + tid) * 2 + 1];
  }
  __syncthreads();
  const int tx = tid & 15, ty = tid >> 4;          // compute: c=ty*2+i, n=tx*4+j
  const int wr = tid >> 3, wc4 = (tid & 7) * 4;    // Ws staging
  const int xkr = tid >> 4, xnc = (tid & 15) * 4;  // Xs synthesis
  const float fs = 0.08838834764831845f;
  float acc[2][4] = {};
  float pcs[4] = {};
  for (int k0 = 0; k0 < 1024; k0 += 32) {
    const float4 wv =
        *(const float4*)(vv + ((long)b * 384 + c0 + wr) * 1024 + k0 + wc4);
    const unsigned long long kb0 = kbits[((long)b * 1024 + k0 + xkr) * 2];
    const unsigned long long kb1 = kbits[((long)b * 1024 + k0 + xkr) * 2 + 1];
    float w[4];
#pragma unroll
    for (int j = 0; j < 4; j++) {
      int ham = __popcll(qn[xnc + j][0] ^ kb0) + __popcll(qn[xnc + j][1] ^ kb1);
      w[j] = __expf((float)(128 - 2 * ham) * fs);
      pcs[j] += w[j];
    }
    Ws[wc4 + 0][wr] = wv.x; Ws[wc4 + 1][wr] = wv.y;
    Ws[wc4 + 2][wr] = wv.z; Ws[wc4 + 3][wr] = wv.w;
#pragma unroll
    for (int j = 0; j < 4; j++) Xs[xkr][xnc + j] = w[j];
    __syncthreads();
#pragma unroll
    for (int kk = 0; kk < 32; kk++) {
      const float2 a = *(const float2*)&Ws[kk][ty * 2];
      const float4 bx = *(const float4*)&Xs[kk][tx * 4];
      acc[0][0] += a.x * bx.x; acc[0][1] += a.x * bx.y;
      acc[0][2] += a.x * bx.z; acc[0][3] += a.x * bx.w;
      acc[1][0] += a.y * bx.x; acc[1][1] += a.y * bx.y;
      acc[1][2] += a.y * bx.z; acc[1][3] += a.y * bx.w;
    }
    __syncthreads();
  }
  // column denominators: reuse Ws as psum[32][68]
#pragma unroll
  for (int j = 0; j < 4; j++) Ws[xkr][xnc + j] = pcs[j];
  __syncthreads();
  if (tid < 64) {
    float d = 0.f;
#pragma unroll
    for (int r = 0; r < 32; r++) d += Ws[r][tid];
    rd[tid] = 1.f / d;
  }
  __syncthreads();
#pragma unroll
  for (int i = 0; i < 2; i++) {
    float4 o;
    o.x = acc[i][0] * rd[tx * 4 + 0];
    o.y = acc[i][1] * rd[tx * 4 + 1];
    o.z = acc[i][2] * rd[tx * 4 + 2];
    o.w = acc[i][3] * rd[tx * 4 + 3];
    *(float4*)(ob + ((long)b * 128 + c0 + ty * 2 + i) * 1024 + n0 + tx * 4) = o;
  }
}

// ---------------------------------------------------------------------------
// Fused depthwise 3x3 conv + combine:
// yc[b,256+c,n] += g*y1 + (1-a)*dwconv(y1) + a*obp.  One block per (b,c).
// ---------------------------------------------------------------------------
__global__ __launch_bounds__(256) void dwcombine_kernel(
    float* __restrict__ yc, const float* __restrict__ dw_w,
    const float* __restrict__ dw_b, const float* __restrict__ obp,
    const float* __restrict__ g, const float* __restrict__ alpha) {
  const int bc = blockIdx.x;
  const int b = bc >> 7, cx = bc & 127;
  const float* img = yc + ((long)b * 384 + 128 + cx) * NPIX;
  float* dst = yc + ((long)b * 384 + 256 + cx) * NPIX;
  float w[9];
#pragma unroll
  for (int i = 0; i < 9; i++) w[i] = dw_w[cx * 9 + i];
  const float bias = dw_b[cx];
  const float a = alpha[b];
  const float gg = g[bc];
  for (int i = threadIdx.x; i < 1024; i += 256) {
    int h = i >> 5, wx = i & 31;
    float s = bias;
#pragma unroll
    for (int ky = 0; ky < 3; ky++) {
      int hh = h + ky - 1;
      if (hh < 0 || hh > 31) continue;
#pragma unroll
      for (int kx = 0; kx < 3; kx++) {
        int ww2 = wx + kx - 1;
        if (ww2 < 0 || ww2 > 31) continue;
        s += img[hh * 32 + ww2] * w[ky * 3 + kx];
      }
    }
    dst[i] = dst[i] + gg * img[i] + (1.f - a) * s + a * obp[(long)bc * NPIX + i];
  }
}

// ---------------------------------------------------------------------------
extern "C" void kernel_launch(void* const* d_in, const int* in_sizes, int n_in,
                              void* d_out, int out_size, void* d_ws, size_t ws_size,
                              hipStream_t stream) {
  const float* x = (const float*)d_in[0];
  const float* cv1_w = (const float*)d_in[1];
  const float* cv1_b = (const float*)d_in[2];
  const float* fm_w1 = (const float*)d_in[3];
  const float* fm_w2 = (const float*)d_in[4];
  const float* ca_w1 = (const float*)d_in[5];
  const float* ca_w2 = (const float*)d_in[6];
  const float* qkv_w = (const float*)d_in[7];
  const float* tproj_w = (const float*)d_in[8];
  const float* tproj_b = (const float*)d_in[9];
  const float* dw_w = (const float*)d_in[10];
  const float* dw_b = (const float*)d_in[11];
  const float* rt_w = (const float*)d_in[12];
  const float* rt_b = (const float*)d_in[13];
  const float* q_w = (const float*)d_in[14];
  const float* k_w = (const float*)d_in[15];
  const float* v_w = (const float*)d_in[16];
  const float* sproj_w = (const float*)d_in[17];
  const float* sproj_b = (const float*)d_in[18];
  const float* cv2_w = (const float*)d_in[19];
  const float* cv2_b = (const float*)d_in[20];
  float* out = (float*)d_out;

  char* wsp = (char*)d_ws;
  size_t off = 0;
  auto alloc = [&](size_t bytes) {
    void* p = wsp + off;
    off += (bytes + 255) & ~(size_t)255;
    return p;
  };
  float* yc = (float*)alloc(8UL * 384 * 1024 * 4);
  float* qkvb = (float*)alloc(8UL * 384 * 1024 * 4);
  float* to_cn = (float*)alloc(8UL * 128 * 1024 * 4);
  float* sqkv = (float*)alloc(8UL * 384 * 1024 * 4);
  float* skv_w = (float*)alloc(384UL * 128 * 4);
  float* var_k = (float*)alloc(8UL * 8 * 1024 * 4);
  float* var_v = (float*)alloc(8UL * 8 * 1024 * 4);
  float* maxvk = (float*)alloc(64 * 4);
  float* pooled = (float*)alloc(1024 * 4);
  float* m1 = (float*)alloc(1024 * 4);
  float* g = (float*)alloc(1024 * 4);
  float* alpha = (float*)alloc(8 * 4);
  unsigned long long* qbits = (unsigned long long*)alloc(8192UL * 2 * 8);
  unsigned long long* kbits = (unsigned long long*)alloc(8192UL * 2 * 8);
  // aliases into qkvb (dead after stat_attn):
  float* obv = qkvb;                    // [8][128][1024]
  float* obp = qkvb + 8L * 128 * 1024;  // [8][128][1024]
  if (off > ws_size) return;

  dim3 blk(256);
  // 0. fuse spatial q/k/v weights into one [384][128] matrix
  fuse_w_kernel<<<dim3(192), blk, 0, stream>>>(q_w, k_w, v_w, skv_w);
  // 1. cv1: yc[:,0:256,:] = cv1_w @ x + cv1_b
  gemm_kernel<true, false><<<dim3(16, 4, 8), blk, 0, stream>>>(
      cv1_w, x, cv1_b, nullptr, yc, 256, 1024, 256, 256L * 1024, 384L * 1024, 0);
  // 2. FFT pooling + channel means
  fftpool_kernel<<<dim3(1024), blk, 0, stream>>>(yc, pooled, m1);
  // 3. gates
  gates_kernel<<<dim3(8), dim3(128), 0, stream>>>(pooled, m1, fm_w1, fm_w2,
                                                  ca_w1, ca_w2, rt_w, rt_b, g, alpha);
  // 4. qkv projection (stat attention)
  gemm_kernel<false, false><<<dim3(16, 6, 8), blk, 0, stream>>>(
      qkv_w, yc + 128 * 1024, nullptr, nullptr, qkvb, 384, 1024, 128,
      384L * 1024, 384L * 1024, 0);
  // 5. variances + per-bh max
  varmax_kernel<<<dim3(64), blk, 0, stream>>>(qkvb, var_k, var_v, maxvk);
  // 6. stat attention
  stat_attn_kernel<<<dim3(64, 8), blk, 0, stream>>>(qkvb, var_k, var_v, maxvk, to_cn);
  // 7. tproj -> yc[:,256:384,:] (stat_out)
  gemm_kernel<true, false><<<dim3(16, 2, 8), blk, 0, stream>>>(
      tproj_w, to_cn, tproj_b, nullptr, yc + 256 * 1024, 128, 1024, 128,
      128L * 1024, 384L * 1024, 0);
  // 8. fused spatial q/k/v projection
  gemm_kernel<false, false><<<dim3(16, 6, 8), blk, 0, stream>>>(
      skv_w, yc + 128 * 1024, nullptr, nullptr, sqkv, 384, 1024, 128,
      384L * 1024, 384L * 1024, 0);
  // 9. sign pack
  pack_kernel<<<dim3(2048), blk, 0, stream>>>(sqkv, qbits, kbits);
  // 10. fused a2-gen + denom + GEMM: ob = (vv @ w) / colsum(w)  [512 thr]
  obgemm_kernel<<<dim3(16, 2, 8), dim3(512), 0, stream>>>(sqkv, qbits, kbits, obv);
  // 11. sproj
  gemm_kernel<true, false><<<dim3(16, 2, 8), blk, 0, stream>>>(
      sproj_w, obv, sproj_b, nullptr, obp, 128, 1024, 128,
      128L * 1024, 128L * 1024, 0);
  // 12. fused depthwise conv + combine into yc attn region
  dwcombine_kernel<<<dim3(1024), blk, 0, stream>>>(yc, dw_w, dw_b, obp, g, alpha);
  // 13. cv2 + residual
  gemm_kernel<true, true><<<dim3(16, 4, 8), blk, 0, stream>>>(
      cv2_w, yc, cv2_b, x, out, 256, 1024, 384, 384L * 1024, 256L * 1024,
      256L * 1024);
}

// Round 9
// 264.875 us; speedup vs baseline: 1.5923x; 1.0402x over previous
//
#include <hip/hip_runtime.h>
#include <math.h>

// Problem constants
#define BATCH 8
#define C1C 256
#define C2C 256
#define CC 128
#define NPIX 1024   // 32*32
#define NH 8        // heads
#define HDD 16      // head dim

// ---------------------------------------------------------------------------
// Generic batched GEMM: Y[b] (M x N) = W (M x K) @ X[b] (K x N) (+bias) (+res)
// Tile 64x64, K-chunk 16, 256 threads, 4x4 micro-tile per thread.
// ---------------------------------------------------------------------------
template<bool HAS_BIAS, bool HAS_RES>
__global__ __launch_bounds__(256) void gemm_kernel(
    const float* __restrict__ W, const float* __restrict__ X,
    const float* __restrict__ bias, const float* __restrict__ res,
    float* __restrict__ Y, int M, int Nn, int K, long sX, long sY, long sR) {
  __shared__ float Ws[16][68];
  __shared__ float Xs[16][68];
  const int b = blockIdx.z;
  const float* Xb = X + (long)b * sX;
  float* Yb = Y + (long)b * sY;
  const int m0 = blockIdx.y * 64, n0 = blockIdx.x * 64;
  const int tid = threadIdx.x;
  const int tx = tid & 15, ty = tid >> 4;
  float acc[4][4] = {};
  for (int k0 = 0; k0 < K; k0 += 16) {
    {
      int r = tid >> 2;
      int c4 = (tid & 3) * 4;
      const float4 wv = *(const float4*)(W + (long)(m0 + r) * K + k0 + c4);
      Ws[c4 + 0][r] = wv.x; Ws[c4 + 1][r] = wv.y;
      Ws[c4 + 2][r] = wv.z; Ws[c4 + 3][r] = wv.w;
    }
    {
      int r = tid >> 4;
      int cR = (tid & 15) * 4;
      const float4 xv = *(const float4*)(Xb + (long)(k0 + r) * Nn + n0 + cR);
      *(float4*)&Xs[r][cR] = xv;
    }
    __syncthreads();
#pragma unroll
    for (int kk = 0; kk < 16; kk++) {
      float a[4], bx[4];
#pragma unroll
      for (int i = 0; i < 4; i++) a[i] = Ws[kk][ty * 4 + i];
#pragma unroll
      for (int j = 0; j < 4; j++) bx[j] = Xs[kk][tx * 4 + j];
#pragma unroll
      for (int i = 0; i < 4; i++)
#pragma unroll
        for (int j = 0; j < 4; j++) acc[i][j] += a[i] * bx[j];
    }
    __syncthreads();
  }
#pragma unroll
  for (int i = 0; i < 4; i++) {
    int m = m0 + ty * 4 + i;
    float bv = HAS_BIAS ? bias[m] : 0.f;
#pragma unroll
    for (int j = 0; j < 4; j++) {
      int n = n0 + tx * 4 + j;
      float v = acc[i][j] + bv;
      if (HAS_RES) v += res[(long)b * sR + (long)m * Nn + n];
      Yb[(long)m * Nn + n] = v;
    }
  }
}

// ---------------------------------------------------------------------------
// Concatenate spatial q/k/v weights into one [384][128] matrix.
// ---------------------------------------------------------------------------
__global__ __launch_bounds__(256) void fuse_w_kernel(
    const float* __restrict__ q_w, const float* __restrict__ k_w,
    const float* __restrict__ v_w, float* __restrict__ skv_w) {
  int i = blockIdx.x * 256 + threadIdx.x;  // 0 .. 3*16384-1
  int which = i >> 14, r = i & 16383;
  float v = (which == 0) ? q_w[r] : (which == 1) ? k_w[r] : v_w[r];
  skv_w[i] = v;
}

// ---------------------------------------------------------------------------
// FFT magnitude pooling: pooled[b,c] = mean |rfft2(y1[b,c], ortho)| over 32x17
// Also m1[b,c] = mean(y1[b,c]).  One block per (b,c) image.
// ---------------------------------------------------------------------------
__global__ __launch_bounds__(256) void fftpool_kernel(
    const float* __restrict__ yc, float* __restrict__ pooled, float* __restrict__ m1) {
  const int bc = blockIdx.x;
  const int b = bc >> 7, cx = bc & 127;
  const float* img = yc + ((long)b * 384 + 128 + cx) * NPIX;
  __shared__ float im[1024];
  __shared__ float Gr[32][17], Gi[32][17];
  __shared__ float cs[32], sn[32];
  __shared__ float red[256];
  const int t = threadIdx.x;
  if (t < 32) {
    float ang = -0.19634954084936207f * (float)t;  // -2*pi*t/32
    __sincosf(ang, &sn[t], &cs[t]);
  }
  float lsum = 0.f;
  for (int i = t; i < 1024; i += 256) { float v = img[i]; im[i] = v; lsum += v; }
  red[t] = lsum;
  __syncthreads();
  for (int s = 128; s > 0; s >>= 1) {
    if (t < s) red[t] += red[t + s];
    __syncthreads();
  }
  if (t == 0) m1[bc] = red[0] * (1.f / 1024.f);
  // stage 1: along w
  for (int i = t; i < 544; i += 256) {
    int h = i / 17, v = i % 17;
    float ar = 0.f, ai = 0.f;
    for (int w2 = 0; w2 < 32; w2++) {
      int k = (v * w2) & 31;
      float x = im[h * 32 + w2];
      ar += x * cs[k]; ai += x * sn[k];
    }
    Gr[h][v] = ar; Gi[h][v] = ai;
  }
  __syncthreads();
  // stage 2: along h, accumulate |X|
  float asum = 0.f;
  for (int i = t; i < 544; i += 256) {
    int u = i / 17, v = i % 17;
    float xr = 0.f, xi = 0.f;
    for (int h = 0; h < 32; h++) {
      int k = (u * h) & 31;
      float gr = Gr[h][v], gi = Gi[h][v];
      xr += gr * cs[k] - gi * sn[k];
      xi += gr * sn[k] + gi * cs[k];
    }
    asum += sqrtf(xr * xr + xi * xi);
  }
  red[t] = asum;
  __syncthreads();
  for (int s = 128; s > 0; s >>= 1) {
    if (t < s) red[t] += red[t + s];
    __syncthreads();
  }
  if (t == 0) pooled[bc] = red[0] * (1.f / (32.f * 544.f));
}

// ---------------------------------------------------------------------------
// Gates: fw/ca MLPs -> g = fw*ca; p_route -> alpha.  One block per batch.
// ---------------------------------------------------------------------------
__global__ __launch_bounds__(128) void gates_kernel(
    const float* __restrict__ pooled, const float* __restrict__ m1,
    const float* __restrict__ fm_w1, const float* __restrict__ fm_w2,
    const float* __restrict__ ca_w1, const float* __restrict__ ca_w2,
    const float* __restrict__ rt_w, const float* __restrict__ rt_b,
    float* __restrict__ g, float* __restrict__ alpha) {
  const int b = blockIdx.x, t = threadIdx.x;
  __shared__ float h1[8], fwv[128], xsm[128], h2[8];
  const float* pb = pooled + b * 128;
  const float* mb = m1 + b * 128;
  if (t < 8) {
    float s = 0.f;
    for (int c = 0; c < 128; c++) s += pb[c] * fm_w1[t * 128 + c];
    h1[t] = fmaxf(s, 0.f);
  }
  __syncthreads();
  {
    float s = 0.f;
    for (int r = 0; r < 8; r++) s += h1[r] * fm_w2[t * 8 + r];
    float fw = 1.f / (1.f + __expf(-s));
    fwv[t] = fw; xsm[t] = fw * mb[t];
  }
  __syncthreads();
  if (t < 8) {
    float s = 0.f;
    for (int c = 0; c < 128; c++) s += xsm[c] * ca_w1[t * 128 + c];
    h2[t] = fmaxf(s, 0.f);
  }
  __syncthreads();
  {
    float s = 0.f;
    for (int r = 0; r < 8; r++) s += h2[r] * ca_w2[t * 8 + r];
    float ca = 1.f / (1.f + __expf(-s));
    g[b * 128 + t] = fwv[t] * ca;
  }
  if (t == 0) {
    float s = 0.f;
    for (int c = 0; c < 128; c++) s += mb[c] * rt_w[c];
    s += rt_b[0];
    alpha[b] = 1.f / (1.f + __expf(-s));
  }
}

// ---------------------------------------------------------------------------
// Variance of k and v head vectors (ddof=1) + per-bh max(var_k).
// ---------------------------------------------------------------------------
__global__ __launch_bounds__(256) void varmax_kernel(
    const float* __restrict__ qkvb, float* __restrict__ var_k,
    float* __restrict__ var_v, float* __restrict__ maxvk) {
  const int bh = blockIdx.x;
  const int b = bh >> 3, h = bh & 7;
  __shared__ float red[256];
  const float* kb = qkvb + ((long)b * 384 + 128 + h * 16) * NPIX;
  const float* vb = qkvb + ((long)b * 384 + 256 + h * 16) * NPIX;
  float mx = 0.f;
  for (int j = 0; j < 4; j++) {
    int n = threadIdx.x + j * 256;
    float xk[16], xv[16], sk = 0.f, sv = 0.f;
#pragma unroll
    for (int d = 0; d < 16; d++) {
      xk[d] = kb[(long)d * NPIX + n]; sk += xk[d];
      xv[d] = vb[(long)d * NPIX + n]; sv += xv[d];
    }
    float mk = sk * (1.f / 16.f), mv = sv * (1.f / 16.f);
    float vk_ = 0.f, vv_ = 0.f;
#pragma unroll
    for (int d = 0; d < 16; d++) {
      float a = xk[d] - mk; vk_ += a * a;
      float c = xv[d] - mv; vv_ += c * c;
    }
    vk_ *= (1.f / 15.f); vv_ *= (1.f / 15.f);
    var_k[(long)bh * NPIX + n] = vk_;
    var_v[(long)bh * NPIX + n] = vv_;
    mx = fmaxf(mx, vk_);
  }
  red[threadIdx.x] = mx;
  __syncthreads();
  for (int s = 128; s > 0; s >>= 1) {
    if (threadIdx.x < s) red[threadIdx.x] = fmaxf(red[threadIdx.x], red[threadIdx.x + s]);
    __syncthreads();
  }
  if (threadIdx.x == 0) maxvk[bh] = red[0];
}

// ---------------------------------------------------------------------------
// Stat attention: to[b,h,n,:] = sum_m softmax_m(cn*vk[m]) * v[b,h,m,:]
// Grid (64 bh, 8 n-chunks of 128); thread = (n, d-half of 8).
// ---------------------------------------------------------------------------
__global__ __launch_bounds__(256) void stat_attn_kernel(
    const float* __restrict__ qkvb, const float* __restrict__ var_k,
    const float* __restrict__ var_v, const float* __restrict__ maxvk,
    float* __restrict__ to_cn) {
  const int bh = blockIdx.x;
  const int b = bh >> 3, h = bh & 7;
  const int tid = threadIdx.x;
  const int nl = tid & 127, dh = tid >> 7;
  const int n = blockIdx.y * 128 + nl;
  __shared__ float vk[NPIX];
  __shared__ float vs[256][20];  // 80B rows: 16B-aligned for b128 reads
  const float* vbase = qkvb + ((long)b * 384 + 256 + h * 16) * NPIX;
  for (int i = tid; i < NPIX; i += 256) vk[i] = var_k[(long)bh * NPIX + i];
  const float cn = var_v[(long)bh * NPIX + n] * 0.25f;
  const float mv = maxvk[bh];
  float denom = 0.f;
  float acc[8];
#pragma unroll
  for (int j = 0; j < 8; j++) acc[j] = 0.f;
  for (int m0 = 0; m0 < NPIX; m0 += 256) {
    __syncthreads();
#pragma unroll
    for (int p = 0; p < 16; p++) vs[tid][p] = vbase[(long)p * NPIX + m0 + tid];
    __syncthreads();
#pragma unroll 4
    for (int mm = 0; mm < 256; mm++) {
      float w = __expf(cn * (vk[m0 + mm] - mv));
      denom += w;
      const float4 vA = *(const float4*)&vs[mm][dh * 8];
      const float4 vB = *(const float4*)&vs[mm][dh * 8 + 4];
      acc[0] += w * vA.x; acc[1] += w * vA.y; acc[2] += w * vA.z; acc[3] += w * vA.w;
      acc[4] += w * vB.x; acc[5] += w * vB.y; acc[6] += w * vB.z; acc[7] += w * vB.w;
    }
  }
  float inv = 1.f / denom;
#pragma unroll
  for (int j = 0; j < 8; j++)
    to_cn[((long)b * CC + h * 16 + dh * 8 + j) * NPIX + n] = acc[j] * inv;
}

// ---------------------------------------------------------------------------
// Bit-pack signs of fused spatial q/k projections.
// ---------------------------------------------------------------------------
__global__ __launch_bounds__(256) void pack_kernel(
    const float* __restrict__ sqkv,
    unsigned long long* __restrict__ qbits, unsigned long long* __restrict__ kbits) {
  const int wave = threadIdx.x >> 6, lane = threadIdx.x & 63;
  const long p = (long)blockIdx.x * 4 + wave;  // 0..8191
  const int b = (int)(p >> 10), n = (int)(p & 1023);
  const float* base = sqkv + (long)b * 384 * NPIX + n;
  unsigned long long q0 = __ballot(base[(long)lane * NPIX] > 0.f);
  unsigned long long q1 = __ballot(base[(long)(64 + lane) * NPIX] > 0.f);
  unsigned long long k0 = __ballot(base[(long)(128 + lane) * NPIX] > 0.f);
  unsigned long long k1 = __ballot(base[(long)(192 + lane) * NPIX] > 0.f);
  if (lane == 0) {
    qbits[p * 2] = q0; qbits[p * 2 + 1] = q1;
    kbits[p * 2] = k0; kbits[p * 2 + 1] = k1;
  }
}

// ---------------------------------------------------------------------------
// K-split fused binary-attention GEMM (sproj pre-folded: pv = sproj_w @ vv).
// Each block: 64x64 output tile over K-range [sp*256, sp*256+256).
// pnum[sp][b][c][n] = sum_m pv[b,c,m]*w[m,n];  pden[sp][b][n] = sum_m w[m,n]
// (written by mt==0 blocks only).  Grid (16, 2*4, 8) = 1024 blocks.
// w[m,n] = exp((128-2*popc(q[n]^k[m]))/sqrt(128)), fp32-safe unnormalized.
// ---------------------------------------------------------------------------
__global__ __launch_bounds__(256) void obgemm_kernel(
    const float* __restrict__ pv, const unsigned long long* __restrict__ qbits,
    const unsigned long long* __restrict__ kbits, float* __restrict__ pnum,
    float* __restrict__ pden) {
  const int b = blockIdx.z;
  const int mt = blockIdx.y & 1, sp = blockIdx.y >> 1;
  const int c0 = mt * 64, n0 = blockIdx.x * 64;
  const int kb0 = sp * 256;
  __shared__ float Ws[16][68];
  __shared__ float Xs[16][68];
  __shared__ float psum[16][68];
  __shared__ unsigned long long qn[64][2];
  const int tid = threadIdx.x;
  if (tid < 64) {
    qn[tid][0] = qbits[((long)b * 1024 + n0 + tid) * 2];
    qn[tid][1] = qbits[((long)b * 1024 + n0 + tid) * 2 + 1];
  }
  __syncthreads();
  const int tx = tid & 15, ty = tid >> 4;
  const float fs = 0.08838834764831845f;
  float acc[4][4] = {};
  float pcs[4] = {};
  for (int k0 = kb0; k0 < kb0 + 256; k0 += 16) {
    {
      int r = tid >> 2, c4 = (tid & 3) * 4;
      const float4 wv = *(const float4*)(pv + ((long)b * 128 + c0 + r) * 1024 + k0 + c4);
      Ws[c4 + 0][r] = wv.x; Ws[c4 + 1][r] = wv.y;
      Ws[c4 + 2][r] = wv.z; Ws[c4 + 3][r] = wv.w;
    }
    {
      int kr = tid >> 4, nc = (tid & 15) * 4;
      unsigned long long kw0 = kbits[((long)b * 1024 + k0 + kr) * 2];
      unsigned long long kw1 = kbits[((long)b * 1024 + k0 + kr) * 2 + 1];
#pragma unroll
      for (int j = 0; j < 4; j++) {
        int ham = __popcll(qn[nc + j][0] ^ kw0) + __popcll(qn[nc + j][1] ^ kw1);
        float w = __expf((float)(128 - 2 * ham) * fs);
        Xs[kr][nc + j] = w;
        pcs[j] += w;
      }
    }
    __syncthreads();
#pragma unroll
    for (int kk = 0; kk < 16; kk++) {
      float a[4], bx[4];
#pragma unroll
      for (int i = 0; i < 4; i++) a[i] = Ws[kk][ty * 4 + i];
#pragma unroll
      for (int j = 0; j < 4; j++) bx[j] = Xs[kk][tx * 4 + j];
#pragma unroll
      for (int i = 0; i < 4; i++)
#pragma unroll
        for (int j = 0; j < 4; j++) acc[i][j] += a[i] * bx[j];
    }
    __syncthreads();
  }
  // partial-numerator write (vectorized)
  float* dst = pnum + (((long)sp * 8 + b) * 128 + c0) * 1024 + n0;
#pragma unroll
  for (int i = 0; i < 4; i++) {
    float4 o = make_float4(acc[i][0], acc[i][1], acc[i][2], acc[i][3]);
    *(float4*)(dst + (long)(ty * 4 + i) * 1024 + tx * 4) = o;
  }
  // partial denominators (only one m-tile needs to write them)
  {
    int kr = tid >> 4, nc = (tid & 15) * 4;
#pragma unroll
    for (int j = 0; j < 4; j++) psum[kr][nc + j] = pcs[j];
  }
  __syncthreads();
  if (mt == 0 && tid < 64) {
    float d = 0.f;
#pragma unroll
    for (int r = 0; r < 16; r++) d += psum[r][tid];
    pden[((long)sp * 8 + b) * 1024 + n0 + tid] = d;
  }
}

// ---------------------------------------------------------------------------
// Reduce K-split partials: obp[b,o,n] = sum_sp(pnum)/sum_sp(pden) + sproj_b[o]
// ---------------------------------------------------------------------------
__global__ __launch_bounds__(256) void obreduce_kernel(
    const float* __restrict__ pnum, const float* __restrict__ pden,
    const float* __restrict__ sproj_b, float* __restrict__ obp) {
  long i = (long)blockIdx.x * 256 + threadIdx.x;  // 8*128*1024
  int n = (int)(i & 1023);
  long bo = i >> 10;
  int b = (int)(bo >> 7), o = (int)(bo & 127);
  const long ns = 8L * 128 * 1024;
  float num = pnum[i] + pnum[i + ns] + pnum[i + 2 * ns] + pnum[i + 3 * ns];
  const long ds = 8L * 1024;
  long di = (long)b * 1024 + n;
  float den = pden[di] + pden[di + ds] + pden[di + 2 * ds] + pden[di + 3 * ds];
  obp[i] = num / den + sproj_b[o];
}

// ---------------------------------------------------------------------------
// Fused depthwise 3x3 conv + combine:
// yc[b,256+c,n] += g*y1 + (1-a)*dwconv(y1) + a*obp.  One block per (b,c).
// ---------------------------------------------------------------------------
__global__ __launch_bounds__(256) void dwcombine_kernel(
    float* __restrict__ yc, const float* __restrict__ dw_w,
    const float* __restrict__ dw_b, const float* __restrict__ obp,
    const float* __restrict__ g, const float* __restrict__ alpha) {
  const int bc = blockIdx.x;
  const int b = bc >> 7, cx = bc & 127;
  const float* img = yc + ((long)b * 384 + 128 + cx) * NPIX;
  float* dst = yc + ((long)b * 384 + 256 + cx) * NPIX;
  float w[9];
#pragma unroll
  for (int i = 0; i < 9; i++) w[i] = dw_w[cx * 9 + i];
  const float bias = dw_b[cx];
  const float a = alpha[b];
  const float gg = g[bc];
  for (int i = threadIdx.x; i < 1024; i += 256) {
    int h = i >> 5, wx = i & 31;
    float s = bias;
#pragma unroll
    for (int ky = 0; ky < 3; ky++) {
      int hh = h + ky - 1;
      if (hh < 0 || hh > 31) continue;
#pragma unroll
      for (int kx = 0; kx < 3; kx++) {
        int ww2 = wx + kx - 1;
        if (ww2 < 0 || ww2 > 31) continue;
        s += img[hh * 32 + ww2] * w[ky * 3 + kx];
      }
    }
    dst[i] = dst[i] + gg * img[i] + (1.f - a) * s + a * obp[(long)bc * NPIX + i];
  }
}

// ---------------------------------------------------------------------------
extern "C" void kernel_launch(void* const* d_in, const int* in_sizes, int n_in,
                              void* d_out, int out_size, void* d_ws, size_t ws_size,
                              hipStream_t stream) {
  const float* x = (const float*)d_in[0];
  const float* cv1_w = (const float*)d_in[1];
  const float* cv1_b = (const float*)d_in[2];
  const float* fm_w1 = (const float*)d_in[3];
  const float* fm_w2 = (const float*)d_in[4];
  const float* ca_w1 = (const float*)d_in[5];
  const float* ca_w2 = (const float*)d_in[6];
  const float* qkv_w = (const float*)d_in[7];
  const float* tproj_w = (const float*)d_in[8];
  const float* tproj_b = (const float*)d_in[9];
  const float* dw_w = (const float*)d_in[10];
  const float* dw_b = (const float*)d_in[11];
  const float* rt_w = (const float*)d_in[12];
  const float* rt_b = (const float*)d_in[13];
  const float* q_w = (const float*)d_in[14];
  const float* k_w = (const float*)d_in[15];
  const float* v_w = (const float*)d_in[16];
  const float* sproj_w = (const float*)d_in[17];
  const float* sproj_b = (const float*)d_in[18];
  const float* cv2_w = (const float*)d_in[19];
  const float* cv2_b = (const float*)d_in[20];
  float* out = (float*)d_out;

  char* wsp = (char*)d_ws;
  size_t off = 0;
  auto alloc = [&](size_t bytes) {
    void* p = wsp + off;
    off += (bytes + 255) & ~(size_t)255;
    return p;
  };
  float* yc = (float*)alloc(8UL * 384 * 1024 * 4);
  float* qkvb = (float*)alloc(8UL * 384 * 1024 * 4);   // also pnum[0..2]
  float* to_cn = (float*)alloc(8UL * 128 * 1024 * 4);  // also pnum[3]
  float* sqkv = (float*)alloc(8UL * 384 * 1024 * 4);   // also obp
  float* skv_w = (float*)alloc(384UL * 128 * 4);
  float* pv = (float*)alloc(8UL * 128 * 1024 * 4);
  float* pden = (float*)alloc(4UL * 8 * 1024 * 4);
  float* var_k = (float*)alloc(8UL * 8 * 1024 * 4);
  float* var_v = (float*)alloc(8UL * 8 * 1024 * 4);
  float* maxvk = (float*)alloc(64 * 4);
  float* pooled = (float*)alloc(1024 * 4);
  float* m1 = (float*)alloc(1024 * 4);
  float* g = (float*)alloc(1024 * 4);
  float* alpha = (float*)alloc(8 * 4);
  unsigned long long* qbits = (unsigned long long*)alloc(8192UL * 2 * 8);
  unsigned long long* kbits = (unsigned long long*)alloc(8192UL * 2 * 8);
  // aliases (lifetime-disjoint):
  float* pnum = qkvb;  // 16MB spans qkvb(12.6MB)+to_cn(4.2MB), both dead by step 10
  float* obp = sqkv;   // sqkv fully dead after pack + pv
  if (off > ws_size) return;

  dim3 blk(256);
  // 0. fuse spatial q/k/v weights into one [384][128] matrix
  fuse_w_kernel<<<dim3(192), blk, 0, stream>>>(q_w, k_w, v_w, skv_w);
  // 1. cv1: yc[:,0:256,:] = cv1_w @ x + cv1_b
  gemm_kernel<true, false><<<dim3(16, 4, 8), blk, 0, stream>>>(
      cv1_w, x, cv1_b, nullptr, yc, 256, 1024, 256, 256L * 1024, 384L * 1024, 0);
  // 2. FFT pooling + channel means
  fftpool_kernel<<<dim3(1024), blk, 0, stream>>>(yc, pooled, m1);
  // 3. gates
  gates_kernel<<<dim3(8), dim3(128), 0, stream>>>(pooled, m1, fm_w1, fm_w2,
                                                  ca_w1, ca_w2, rt_w, rt_b, g, alpha);
  // 4. qkv projection (stat attention)
  gemm_kernel<false, false><<<dim3(16, 6, 8), blk, 0, stream>>>(
      qkv_w, yc + 128 * 1024, nullptr, nullptr, qkvb, 384, 1024, 128,
      384L * 1024, 384L * 1024, 0);
  // 5. variances + per-bh max
  varmax_kernel<<<dim3(64), blk, 0, stream>>>(qkvb, var_k, var_v, maxvk);
  // 6. stat attention
  stat_attn_kernel<<<dim3(64, 8), blk, 0, stream>>>(qkvb, var_k, var_v, maxvk, to_cn);
  // 7. tproj -> yc[:,256:384,:] (stat_out)
  gemm_kernel<true, false><<<dim3(16, 2, 8), blk, 0, stream>>>(
      tproj_w, to_cn, tproj_b, nullptr, yc + 256 * 1024, 128, 1024, 128,
      128L * 1024, 384L * 1024, 0);
  // 8. fused spatial q/k/v projection
  gemm_kernel<false, false><<<dim3(16, 6, 8), blk, 0, stream>>>(
      skv_w, yc + 128 * 1024, nullptr, nullptr, sqkv, 384, 1024, 128,
      384L * 1024, 384L * 1024, 0);
  // 9. sign pack
  pack_kernel<<<dim3(2048), blk, 0, stream>>>(sqkv, qbits, kbits);
  // 9b. pv = sproj_w @ vv (sproj folded through attention by associativity)
  gemm_kernel<false, false><<<dim3(16, 2, 8), blk, 0, stream>>>(
      sproj_w, sqkv + 256 * 1024, nullptr, nullptr, pv, 128, 1024, 128,
      384L * 1024, 128L * 1024, 0);
  // 10. K-split fused a2-gen GEMM -> partials (1024 blocks, 4/CU)
  obgemm_kernel<<<dim3(16, 8, 8), blk, 0, stream>>>(pv, qbits, kbits, pnum, pden);
  // 10b. reduce partials + divide + bias -> obp
  obreduce_kernel<<<dim3(4096), blk, 0, stream>>>(pnum, pden, sproj_b, obp);
  // 11. fused depthwise conv + combine into yc attn region
  dwcombine_kernel<<<dim3(1024), blk, 0, stream>>>(yc, dw_w, dw_b, obp, g, alpha);
  // 12. cv2 + residual
  gemm_kernel<true, true><<<dim3(16, 4, 8), blk, 0, stream>>>(
      cv2_w, yc, cv2_b, x, out, 256, 1024, 384, 384L * 1024, 256L * 1024,
      256L * 1024);
}

// Round 10
// 259.450 us; speedup vs baseline: 1.6256x; 1.0209x over previous
//
#include <hip/hip_runtime.h>
#include <math.h>

// Problem constants
#define BATCH 8
#define C1C 256
#define C2C 256
#define CC 128
#define NPIX 1024   // 32*32
#define NH 8        // heads
#define HDD 16      // head dim

// ---------------------------------------------------------------------------
// Generic batched GEMM: Y[b] (M x N) = W (M x K) @ X[b] (K x N) (+bias) (+res)
// Tile 64x64, K-chunk 16, 256 threads, 4x4 micro-tile per thread.
// ---------------------------------------------------------------------------
template<bool HAS_BIAS, bool HAS_RES>
__global__ __launch_bounds__(256) void gemm_kernel(
    const float* __restrict__ W, const float* __restrict__ X,
    const float* __restrict__ bias, const float* __restrict__ res,
    float* __restrict__ Y, int M, int Nn, int K, long sX, long sY, long sR) {
  __shared__ float Ws[16][68];
  __shared__ float Xs[16][68];
  const int b = blockIdx.z;
  const float* Xb = X + (long)b * sX;
  float* Yb = Y + (long)b * sY;
  const int m0 = blockIdx.y * 64, n0 = blockIdx.x * 64;
  const int tid = threadIdx.x;
  const int tx = tid & 15, ty = tid >> 4;
  float acc[4][4] = {};
  for (int k0 = 0; k0 < K; k0 += 16) {
    {
      int r = tid >> 2;
      int c4 = (tid & 3) * 4;
      const float4 wv = *(const float4*)(W + (long)(m0 + r) * K + k0 + c4);
      Ws[c4 + 0][r] = wv.x; Ws[c4 + 1][r] = wv.y;
      Ws[c4 + 2][r] = wv.z; Ws[c4 + 3][r] = wv.w;
    }
    {
      int r = tid >> 4;
      int cR = (tid & 15) * 4;
      const float4 xv = *(const float4*)(Xb + (long)(k0 + r) * Nn + n0 + cR);
      *(float4*)&Xs[r][cR] = xv;
    }
    __syncthreads();
#pragma unroll
    for (int kk = 0; kk < 16; kk++) {
      float a[4], bx[4];
#pragma unroll
      for (int i = 0; i < 4; i++) a[i] = Ws[kk][ty * 4 + i];
#pragma unroll
      for (int j = 0; j < 4; j++) bx[j] = Xs[kk][tx * 4 + j];
#pragma unroll
      for (int i = 0; i < 4; i++)
#pragma unroll
        for (int j = 0; j < 4; j++) acc[i][j] += a[i] * bx[j];
    }
    __syncthreads();
  }
#pragma unroll
  for (int i = 0; i < 4; i++) {
    int m = m0 + ty * 4 + i;
    float bv = HAS_BIAS ? bias[m] : 0.f;
#pragma unroll
    for (int j = 0; j < 4; j++) {
      int n = n0 + tx * 4 + j;
      float v = acc[i][j] + bv;
      if (HAS_RES) v += res[(long)b * sR + (long)m * Nn + n];
      Yb[(long)m * Nn + n] = v;
    }
  }
}

// ---------------------------------------------------------------------------
// Concatenate spatial q/k/v weights into one [384][128] matrix.
// NOTE: launched after statreduce because skv_w aliases the spnum region.
// ---------------------------------------------------------------------------
__global__ __launch_bounds__(256) void fuse_w_kernel(
    const float* __restrict__ q_w, const float* __restrict__ k_w,
    const float* __restrict__ v_w, float* __restrict__ skv_w) {
  int i = blockIdx.x * 256 + threadIdx.x;  // 0 .. 3*16384-1
  int which = i >> 14, r = i & 16383;
  float v = (which == 0) ? q_w[r] : (which == 1) ? k_w[r] : v_w[r];
  skv_w[i] = v;
}

// ---------------------------------------------------------------------------
// FFT magnitude pooling: pooled[b,c] = mean |rfft2(y1[b,c], ortho)| over 32x17
// Also m1[b,c] = mean(y1[b,c]).  One block per (b,c) image.
// ---------------------------------------------------------------------------
__global__ __launch_bounds__(256) void fftpool_kernel(
    const float* __restrict__ yc, float* __restrict__ pooled, float* __restrict__ m1) {
  const int bc = blockIdx.x;
  const int b = bc >> 7, cx = bc & 127;
  const float* img = yc + ((long)b * 384 + 128 + cx) * NPIX;
  __shared__ float im[1024];
  __shared__ float Gr[32][17], Gi[32][17];
  __shared__ float cs[32], sn[32];
  __shared__ float red[256];
  const int t = threadIdx.x;
  if (t < 32) {
    float ang = -0.19634954084936207f * (float)t;  // -2*pi*t/32
    __sincosf(ang, &sn[t], &cs[t]);
  }
  float lsum = 0.f;
  for (int i = t; i < 1024; i += 256) { float v = img[i]; im[i] = v; lsum += v; }
  red[t] = lsum;
  __syncthreads();
  for (int s = 128; s > 0; s >>= 1) {
    if (t < s) red[t] += red[t + s];
    __syncthreads();
  }
  if (t == 0) m1[bc] = red[0] * (1.f / 1024.f);
  // stage 1: along w
  for (int i = t; i < 544; i += 256) {
    int h = i / 17, v = i % 17;
    float ar = 0.f, ai = 0.f;
    for (int w2 = 0; w2 < 32; w2++) {
      int k = (v * w2) & 31;
      float x = im[h * 32 + w2];
      ar += x * cs[k]; ai += x * sn[k];
    }
    Gr[h][v] = ar; Gi[h][v] = ai;
  }
  __syncthreads();
  // stage 2: along h, accumulate |X|
  float asum = 0.f;
  for (int i = t; i < 544; i += 256) {
    int u = i / 17, v = i % 17;
    float xr = 0.f, xi = 0.f;
    for (int h = 0; h < 32; h++) {
      int k = (u * h) & 31;
      float gr = Gr[h][v], gi = Gi[h][v];
      xr += gr * cs[k] - gi * sn[k];
      xi += gr * sn[k] + gi * cs[k];
    }
    asum += sqrtf(xr * xr + xi * xi);
  }
  red[t] = asum;
  __syncthreads();
  for (int s = 128; s > 0; s >>= 1) {
    if (t < s) red[t] += red[t + s];
    __syncthreads();
  }
  if (t == 0) pooled[bc] = red[0] * (1.f / (32.f * 544.f));
}

// ---------------------------------------------------------------------------
// Gates: fw/ca MLPs -> g = fw*ca; p_route -> alpha.  One block per batch.
// ---------------------------------------------------------------------------
__global__ __launch_bounds__(128) void gates_kernel(
    const float* __restrict__ pooled, const float* __restrict__ m1,
    const float* __restrict__ fm_w1, const float* __restrict__ fm_w2,
    const float* __restrict__ ca_w1, const float* __restrict__ ca_w2,
    const float* __restrict__ rt_w, const float* __restrict__ rt_b,
    float* __restrict__ g, float* __restrict__ alpha) {
  const int b = blockIdx.x, t = threadIdx.x;
  __shared__ float h1[8], fwv[128], xsm[128], h2[8];
  const float* pb = pooled + b * 128;
  const float* mb = m1 + b * 128;
  if (t < 8) {
    float s = 0.f;
    for (int c = 0; c < 128; c++) s += pb[c] * fm_w1[t * 128 + c];
    h1[t] = fmaxf(s, 0.f);
  }
  __syncthreads();
  {
    float s = 0.f;
    for (int r = 0; r < 8; r++) s += h1[r] * fm_w2[t * 8 + r];
    float fw = 1.f / (1.f + __expf(-s));
    fwv[t] = fw; xsm[t] = fw * mb[t];
  }
  __syncthreads();
  if (t < 8) {
    float s = 0.f;
    for (int c = 0; c < 128; c++) s += xsm[c] * ca_w1[t * 128 + c];
    h2[t] = fmaxf(s, 0.f);
  }
  __syncthreads();
  {
    float s = 0.f;
    for (int r = 0; r < 8; r++) s += h2[r] * ca_w2[t * 8 + r];
    float ca = 1.f / (1.f + __expf(-s));
    g[b * 128 + t] = fwv[t] * ca;
  }
  if (t == 0) {
    float s = 0.f;
    for (int c = 0; c < 128; c++) s += mb[c] * rt_w[c];
    s += rt_b[0];
    alpha[b] = 1.f / (1.f + __expf(-s));
  }
}

// ---------------------------------------------------------------------------
// Variance of k and v head vectors (ddof=1) + per-bh max(var_k).
// ---------------------------------------------------------------------------
__global__ __launch_bounds__(256) void varmax_kernel(
    const float* __restrict__ qkvb, float* __restrict__ var_k,
    float* __restrict__ var_v, float* __restrict__ maxvk) {
  const int bh = blockIdx.x;
  const int b = bh >> 3, h = bh & 7;
  __shared__ float red[256];
  const float* kb = qkvb + ((long)b * 384 + 128 + h * 16) * NPIX;
  const float* vb = qkvb + ((long)b * 384 + 256 + h * 16) * NPIX;
  float mx = 0.f;
  for (int j = 0; j < 4; j++) {
    int n = threadIdx.x + j * 256;
    float xk[16], xv[16], sk = 0.f, sv = 0.f;
#pragma unroll
    for (int d = 0; d < 16; d++) {
      xk[d] = kb[(long)d * NPIX + n]; sk += xk[d];
      xv[d] = vb[(long)d * NPIX + n]; sv += xv[d];
    }
    float mk = sk * (1.f / 16.f), mv = sv * (1.f / 16.f);
    float vk_ = 0.f, vv_ = 0.f;
#pragma unroll
    for (int d = 0; d < 16; d++) {
      float a = xk[d] - mk; vk_ += a * a;
      float c = xv[d] - mv; vv_ += c * c;
    }
    vk_ *= (1.f / 15.f); vv_ *= (1.f / 15.f);
    var_k[(long)bh * NPIX + n] = vk_;
    var_v[(long)bh * NPIX + n] = vv_;
    mx = fmaxf(mx, vk_);
  }
  red[threadIdx.x] = mx;
  __syncthreads();
  for (int s = 128; s > 0; s >>= 1) {
    if (threadIdx.x < s) red[threadIdx.x] = fmaxf(red[threadIdx.x], red[threadIdx.x + s]);
    __syncthreads();
  }
  if (threadIdx.x == 0) maxvk[bh] = red[0];
}

// ---------------------------------------------------------------------------
// Stat attention (m-split x4, 2n x 16d per thread):
// spnum[mc][bh][d][n] = sum_{m in chunk} exp(cn[n]*(vk[m]-mv)) * v[b,h,m,d]
// spden[mc][bh][n]    = sum_{m in chunk} exp(cn[n]*(vk[m]-mv))
// Grid (64 bh, 4 m-chunks of 256), 512 threads; thread owns n=2*tid, 2*tid+1.
// Per m-iter: 1 vk + 2 exp + 4 b128 (v shared by both n) + 32 FMA.
// ---------------------------------------------------------------------------
__global__ __launch_bounds__(512) void stat_attn_kernel(
    const float* __restrict__ qkvb, const float* __restrict__ var_k,
    const float* __restrict__ var_v, const float* __restrict__ maxvk,
    float* __restrict__ spnum, float* __restrict__ spden) {
  const int bh = blockIdx.x;
  const int b = bh >> 3, h = bh & 7;
  const int mc = blockIdx.y;
  const int m0 = mc * 256;
  const int tid = threadIdx.x;
  const int n = tid * 2;
  __shared__ float vk[256];
  __shared__ float vs[256][20];  // 80B rows: 16B-aligned for b128 reads
  const float* vbase = qkvb + ((long)b * 384 + 256 + h * 16) * NPIX;
  if (tid < 256) vk[tid] = var_k[(long)bh * NPIX + m0 + tid];
#pragma unroll
  for (int k = 0; k < 8; k++) {
    int i = tid + k * 512;
    int d = i >> 8, mm = i & 255;
    vs[mm][d] = vbase[(long)d * NPIX + m0 + mm];
  }
  const float2 cv2 = *(const float2*)&var_v[(long)bh * NPIX + n];
  const float c0 = cv2.x * 0.25f, c1 = cv2.y * 0.25f;
  const float mv = maxvk[bh];
  float acc0[16], acc1[16];
#pragma unroll
  for (int d = 0; d < 16; d++) { acc0[d] = 0.f; acc1[d] = 0.f; }
  float den0 = 0.f, den1 = 0.f;
  __syncthreads();
#pragma unroll 2
  for (int mm = 0; mm < 256; mm++) {
    float t = vk[mm] - mv;
    float e0 = __expf(c0 * t), e1 = __expf(c1 * t);
    den0 += e0; den1 += e1;
    const float4 vA = *(const float4*)&vs[mm][0];
    const float4 vB = *(const float4*)&vs[mm][4];
    const float4 vC = *(const float4*)&vs[mm][8];
    const float4 vD = *(const float4*)&vs[mm][12];
    acc0[0] += e0 * vA.x; acc0[1] += e0 * vA.y; acc0[2] += e0 * vA.z; acc0[3] += e0 * vA.w;
    acc0[4] += e0 * vB.x; acc0[5] += e0 * vB.y; acc0[6] += e0 * vB.z; acc0[7] += e0 * vB.w;
    acc0[8] += e0 * vC.x; acc0[9] += e0 * vC.y; acc0[10] += e0 * vC.z; acc0[11] += e0 * vC.w;
    acc0[12] += e0 * vD.x; acc0[13] += e0 * vD.y; acc0[14] += e0 * vD.z; acc0[15] += e0 * vD.w;
    acc1[0] += e1 * vA.x; acc1[1] += e1 * vA.y; acc1[2] += e1 * vA.z; acc1[3] += e1 * vA.w;
    acc1[4] += e1 * vB.x; acc1[5] += e1 * vB.y; acc1[6] += e1 * vB.z; acc1[7] += e1 * vB.w;
    acc1[8] += e1 * vC.x; acc1[9] += e1 * vC.y; acc1[10] += e1 * vC.z; acc1[11] += e1 * vC.w;
    acc1[12] += e1 * vD.x; acc1[13] += e1 * vD.y; acc1[14] += e1 * vD.z; acc1[15] += e1 * vD.w;
  }
  float* np = spnum + ((long)mc * 64 + bh) * 16 * 1024;
#pragma unroll
  for (int d = 0; d < 16; d++)
    *(float2*)(np + (long)d * 1024 + n) = make_float2(acc0[d], acc1[d]);
  *(float2*)(spden + ((long)mc * 64 + bh) * 1024 + n) = make_float2(den0, den1);
}

// ---------------------------------------------------------------------------
// Reduce stat partials: to_cn[(b*128+h*16+d)*1024+n] = sum(num)/sum(den)
// ---------------------------------------------------------------------------
__global__ __launch_bounds__(256) void statreduce_kernel(
    const float* __restrict__ spnum, const float* __restrict__ spden,
    float* __restrict__ to_cn) {
  long i = (long)blockIdx.x * 256 + threadIdx.x;  // 64*16*1024
  int n = (int)(i & 1023);
  long bhd = i >> 10;
  int bh = (int)(bhd >> 4);
  const long ns = 64L * 16 * 1024;
  float num = spnum[i] + spnum[i + ns] + spnum[i + 2 * ns] + spnum[i + 3 * ns];
  const long ds = 64L * 1024;
  long di = (long)bh * 1024 + n;
  float den = spden[di] + spden[di + ds] + spden[di + 2 * ds] + spden[di + 3 * ds];
  to_cn[i] = num / den;  // layout matches (b*128 + h*16 + d)*1024 + n
}

// ---------------------------------------------------------------------------
// Bit-pack signs of fused spatial q/k projections.
// ---------------------------------------------------------------------------
__global__ __launch_bounds__(256) void pack_kernel(
    const float* __restrict__ sqkv,
    unsigned long long* __restrict__ qbits, unsigned long long* __restrict__ kbits) {
  const int wave = threadIdx.x >> 6, lane = threadIdx.x & 63;
  const long p = (long)blockIdx.x * 4 + wave;  // 0..8191
  const int b = (int)(p >> 10), n = (int)(p & 1023);
  const float* base = sqkv + (long)b * 384 * NPIX + n;
  unsigned long long q0 = __ballot(base[(long)lane * NPIX] > 0.f);
  unsigned long long q1 = __ballot(base[(long)(64 + lane) * NPIX] > 0.f);
  unsigned long long k0 = __ballot(base[(long)(128 + lane) * NPIX] > 0.f);
  unsigned long long k1 = __ballot(base[(long)(192 + lane) * NPIX] > 0.f);
  if (lane == 0) {
    qbits[p * 2] = q0; qbits[p * 2 + 1] = q1;
    kbits[p * 2] = k0; kbits[p * 2 + 1] = k1;
  }
}

// ---------------------------------------------------------------------------
// K-split fused binary-attention GEMM (sproj pre-folded: pv = sproj_w @ vv).
// Each block: 64x64 output tile over K-range [sp*256, sp*256+256).
// pnum[sp][b][c][n] = sum_m pv[b,c,m]*w[m,n];  pden[sp][b][n] = sum_m w[m,n]
// (written by mt==0 blocks only).  Grid (16, 2*4, 8) = 1024 blocks.
// w[m,n] = exp((128-2*popc(q[n]^k[m]))/sqrt(128)), fp32-safe unnormalized.
// ---------------------------------------------------------------------------
__global__ __launch_bounds__(256) void obgemm_kernel(
    const float* __restrict__ pv, const unsigned long long* __restrict__ qbits,
    const unsigned long long* __restrict__ kbits, float* __restrict__ pnum,
    float* __restrict__ pden) {
  const int b = blockIdx.z;
  const int mt = blockIdx.y & 1, sp = blockIdx.y >> 1;
  const int c0 = mt * 64, n0 = blockIdx.x * 64;
  const int kb0 = sp * 256;
  __shared__ float Ws[16][68];
  __shared__ float Xs[16][68];
  __shared__ float psum[16][68];
  __shared__ unsigned long long qn[64][2];
  const int tid = threadIdx.x;
  if (tid < 64) {
    qn[tid][0] = qbits[((long)b * 1024 + n0 + tid) * 2];
    qn[tid][1] = qbits[((long)b * 1024 + n0 + tid) * 2 + 1];
  }
  __syncthreads();
  const int tx = tid & 15, ty = tid >> 4;
  const float fs = 0.08838834764831845f;
  float acc[4][4] = {};
  float pcs[4] = {};
  for (int k0 = kb0; k0 < kb0 + 256; k0 += 16) {
    {
      int r = tid >> 2, c4 = (tid & 3) * 4;
      const float4 wv = *(const float4*)(pv + ((long)b * 128 + c0 + r) * 1024 + k0 + c4);
      Ws[c4 + 0][r] = wv.x; Ws[c4 + 1][r] = wv.y;
      Ws[c4 + 2][r] = wv.z; Ws[c4 + 3][r] = wv.w;
    }
    {
      int kr = tid >> 4, nc = (tid & 15) * 4;
      unsigned long long kw0 = kbits[((long)b * 1024 + k0 + kr) * 2];
      unsigned long long kw1 = kbits[((long)b * 1024 + k0 + kr) * 2 + 1];
#pragma unroll
      for (int j = 0; j < 4; j++) {
        int ham = __popcll(qn[nc + j][0] ^ kw0) + __popcll(qn[nc + j][1] ^ kw1);
        float w = __expf((float)(128 - 2 * ham) * fs);
        Xs[kr][nc + j] = w;
        pcs[j] += w;
      }
    }
    __syncthreads();
#pragma unroll
    for (int kk = 0; kk < 16; kk++) {
      float a[4], bx[4];
#pragma unroll
      for (int i = 0; i < 4; i++) a[i] = Ws[kk][ty * 4 + i];
#pragma unroll
      for (int j = 0; j < 4; j++) bx[j] = Xs[kk][tx * 4 + j];
#pragma unroll
      for (int i = 0; i < 4; i++)
#pragma unroll
        for (int j = 0; j < 4; j++) acc[i][j] += a[i] * bx[j];
    }
    __syncthreads();
  }
  // partial-numerator write (vectorized)
  float* dst = pnum + (((long)sp * 8 + b) * 128 + c0) * 1024 + n0;
#pragma unroll
  for (int i = 0; i < 4; i++) {
    float4 o = make_float4(acc[i][0], acc[i][1], acc[i][2], acc[i][3]);
    *(float4*)(dst + (long)(ty * 4 + i) * 1024 + tx * 4) = o;
  }
  // partial denominators (only one m-tile needs to write them)
  {
    int kr = tid >> 4, nc = (tid & 15) * 4;
#pragma unroll
    for (int j = 0; j < 4; j++) psum[kr][nc + j] = pcs[j];
  }
  __syncthreads();
  if (mt == 0 && tid < 64) {
    float d = 0.f;
#pragma unroll
    for (int r = 0; r < 16; r++) d += psum[r][tid];
    pden[((long)sp * 8 + b) * 1024 + n0 + tid] = d;
  }
}

// ---------------------------------------------------------------------------
// Reduce K-split partials: obp[b,o,n] = sum_sp(pnum)/sum_sp(pden) + sproj_b[o]
// ---------------------------------------------------------------------------
__global__ __launch_bounds__(256) void obreduce_kernel(
    const float* __restrict__ pnum, const float* __restrict__ pden,
    const float* __restrict__ sproj_b, float* __restrict__ obp) {
  long i = (long)blockIdx.x * 256 + threadIdx.x;  // 8*128*1024
  int n = (int)(i & 1023);
  long bo = i >> 10;
  int b = (int)(bo >> 7), o = (int)(bo & 127);
  const long ns = 8L * 128 * 1024;
  float num = pnum[i] + pnum[i + ns] + pnum[i + 2 * ns] + pnum[i + 3 * ns];
  const long ds = 8L * 1024;
  long di = (long)b * 1024 + n;
  float den = pden[di] + pden[di + ds] + pden[di + 2 * ds] + pden[di + 3 * ds];
  obp[i] = num / den + sproj_b[o];
}

// ---------------------------------------------------------------------------
// Fused depthwise 3x3 conv + combine:
// yc[b,256+c,n] += g*y1 + (1-a)*dwconv(y1) + a*obp.  One block per (b,c).
// ---------------------------------------------------------------------------
__global__ __launch_bounds__(256) void dwcombine_kernel(
    float* __restrict__ yc, const float* __restrict__ dw_w,
    const float* __restrict__ dw_b, const float* __restrict__ obp,
    const float* __restrict__ g, const float* __restrict__ alpha) {
  const int bc = blockIdx.x;
  const int b = bc >> 7, cx = bc & 127;
  const float* img = yc + ((long)b * 384 + 128 + cx) * NPIX;
  float* dst = yc + ((long)b * 384 + 256 + cx) * NPIX;
  float w[9];
#pragma unroll
  for (int i = 0; i < 9; i++) w[i] = dw_w[cx * 9 + i];
  const float bias = dw_b[cx];
  const float a = alpha[b];
  const float gg = g[bc];
  for (int i = threadIdx.x; i < 1024; i += 256) {
    int h = i >> 5, wx = i & 31;
    float s = bias;
#pragma unroll
    for (int ky = 0; ky < 3; ky++) {
      int hh = h + ky - 1;
      if (hh < 0 || hh > 31) continue;
#pragma unroll
      for (int kx = 0; kx < 3; kx++) {
        int ww2 = wx + kx - 1;
        if (ww2 < 0 || ww2 > 31) continue;
        s += img[hh * 32 + ww2] * w[ky * 3 + kx];
      }
    }
    dst[i] = dst[i] + gg * img[i] + (1.f - a) * s + a * obp[(long)bc * NPIX + i];
  }
}

// ---------------------------------------------------------------------------
extern "C" void kernel_launch(void* const* d_in, const int* in_sizes, int n_in,
                              void* d_out, int out_size, void* d_ws, size_t ws_size,
                              hipStream_t stream) {
  const float* x = (const float*)d_in[0];
  const float* cv1_w = (const float*)d_in[1];
  const float* cv1_b = (const float*)d_in[2];
  const float* fm_w1 = (const float*)d_in[3];
  const float* fm_w2 = (const float*)d_in[4];
  const float* ca_w1 = (const float*)d_in[5];
  const float* ca_w2 = (const float*)d_in[6];
  const float* qkv_w = (const float*)d_in[7];
  const float* tproj_w = (const float*)d_in[8];
  const float* tproj_b = (const float*)d_in[9];
  const float* dw_w = (const float*)d_in[10];
  const float* dw_b = (const float*)d_in[11];
  const float* rt_w = (const float*)d_in[12];
  const float* rt_b = (const float*)d_in[13];
  const float* q_w = (const float*)d_in[14];
  const float* k_w = (const float*)d_in[15];
  const float* v_w = (const float*)d_in[16];
  const float* sproj_w = (const float*)d_in[17];
  const float* sproj_b = (const float*)d_in[18];
  const float* cv2_w = (const float*)d_in[19];
  const float* cv2_b = (const float*)d_in[20];
  float* out = (float*)d_out;

  char* wsp = (char*)d_ws;
  size_t off = 0;
  auto alloc = [&](size_t bytes) {
    void* p = wsp + off;
    off += (bytes + 255) & ~(size_t)255;
    return p;
  };
  float* yc = (float*)alloc(8UL * 384 * 1024 * 4);
  float* qkvb = (float*)alloc(8UL * 384 * 1024 * 4);   // also ob pnum[0..2]
  float* to_cn = (float*)alloc(8UL * 128 * 1024 * 4);  // also ob pnum[3]
  float* sqkv = (float*)alloc(8UL * 384 * 1024 * 4);   // also obp; also spnum head
  float* skv_w = (float*)alloc(384UL * 128 * 4);       // inside spnum span
  float* pv = (float*)alloc(8UL * 128 * 1024 * 4);     // spnum tail
  float* pden = (float*)alloc(4UL * 8 * 1024 * 4);
  float* spden = (float*)alloc(4UL * 64 * 1024 * 4);
  float* var_k = (float*)alloc(8UL * 8 * 1024 * 4);
  float* var_v = (float*)alloc(8UL * 8 * 1024 * 4);
  float* maxvk = (float*)alloc(64 * 4);
  float* pooled = (float*)alloc(1024 * 4);
  float* m1 = (float*)alloc(1024 * 4);
  float* g = (float*)alloc(1024 * 4);
  float* alpha = (float*)alloc(8 * 4);
  unsigned long long* qbits = (unsigned long long*)alloc(8192UL * 2 * 8);
  unsigned long long* kbits = (unsigned long long*)alloc(8192UL * 2 * 8);
  // aliases (lifetime-disjoint):
  float* pnum = qkvb;   // ob partials: 16MB spans qkvb+to_cn, dead by step 10
  float* obp = sqkv;    // sqkv dead after pack + pv
  float* spnum = sqkv;  // stat partials: 16.8MB spans sqkv+skv_w+pv, free at step 6
                        // (fuse_w/sqkv-gemm/pv-gemm all run after statreduce)
  if (off > ws_size) return;

  dim3 blk(256);
  // 1. cv1: yc[:,0:256,:] = cv1_w @ x + cv1_b
  gemm_kernel<true, false><<<dim3(16, 4, 8), blk, 0, stream>>>(
      cv1_w, x, cv1_b, nullptr, yc, 256, 1024, 256, 256L * 1024, 384L * 1024, 0);
  // 2. FFT pooling + channel means
  fftpool_kernel<<<dim3(1024), blk, 0, stream>>>(yc, pooled, m1);
  // 3. gates
  gates_kernel<<<dim3(8), dim3(128), 0, stream>>>(pooled, m1, fm_w1, fm_w2,
                                                  ca_w1, ca_w2, rt_w, rt_b, g, alpha);
  // 4. qkv projection (stat attention)
  gemm_kernel<false, false><<<dim3(16, 6, 8), blk, 0, stream>>>(
      qkv_w, yc + 128 * 1024, nullptr, nullptr, qkvb, 384, 1024, 128,
      384L * 1024, 384L * 1024, 0);
  // 5. variances + per-bh max
  varmax_kernel<<<dim3(64), blk, 0, stream>>>(qkvb, var_k, var_v, maxvk);
  // 6. stat attention (m-split x4) -> partials in spnum/spden
  stat_attn_kernel<<<dim3(64, 4), dim3(512), 0, stream>>>(qkvb, var_k, var_v,
                                                          maxvk, spnum, spden);
  // 6b. reduce stat partials -> to_cn
  statreduce_kernel<<<dim3(4096), blk, 0, stream>>>(spnum, spden, to_cn);
  // 7. tproj -> yc[:,256:384,:] (stat_out)
  gemm_kernel<true, false><<<dim3(16, 2, 8), blk, 0, stream>>>(
      tproj_w, to_cn, tproj_b, nullptr, yc + 256 * 1024, 128, 1024, 128,
      128L * 1024, 384L * 1024, 0);
  // 7b. fuse spatial q/k/v weights (after statreduce: skv_w aliases spnum)
  fuse_w_kernel<<<dim3(192), blk, 0, stream>>>(q_w, k_w, v_w, skv_w);
  // 8. fused spatial q/k/v projection
  gemm_kernel<false, false><<<dim3(16, 6, 8), blk, 0, stream>>>(
      skv_w, yc + 128 * 1024, nullptr, nullptr, sqkv, 384, 1024, 128,
      384L * 1024, 384L * 1024, 0);
  // 9. sign pack
  pack_kernel<<<dim3(2048), blk, 0, stream>>>(sqkv, qbits, kbits);
  // 9b. pv = sproj_w @ vv (sproj folded through attention by associativity)
  gemm_kernel<false, false><<<dim3(16, 2, 8), blk, 0, stream>>>(
      sproj_w, sqkv + 256 * 1024, nullptr, nullptr, pv, 128, 1024, 128,
      384L * 1024, 128L * 1024, 0);
  // 10. K-split fused a2-gen GEMM -> partials (1024 blocks, 4/CU)
  obgemm_kernel<<<dim3(16, 8, 8), blk, 0, stream>>>(pv, qbits, kbits, pnum, pden);
  // 10b. reduce partials + divide + bias -> obp
  obreduce_kernel<<<dim3(4096), blk, 0, stream>>>(pnum, pden, sproj_b, obp);
  // 11. fused depthwise conv + combine into yc attn region
  dwcombine_kernel<<<dim3(1024), blk, 0, stream>>>(yc, dw_w, dw_b, obp, g, alpha);
  // 12. cv2 + residual
  gemm_kernel<true, true><<<dim3(16, 4, 8), blk, 0, stream>>>(
      cv2_w, yc, cv2_b, x, out, 256, 1024, 384, 384L * 1024, 256L * 1024,
      256L * 1024);
}

// Round 11
// 254.428 us; speedup vs baseline: 1.6577x; 1.0197x over previous
//
#include <hip/hip_runtime.h>
#include <math.h>

// Problem constants
#define BATCH 8
#define C1C 256
#define C2C 256
#define CC 128
#define NPIX 1024   // 32*32
#define NH 8        // heads
#define HDD 16      // head dim

__device__ inline unsigned short f2bf(float x) {  // fp32 -> bf16 RNE
  unsigned int u = __float_as_uint(x);
  return (unsigned short)((u + 0x7FFFu + ((u >> 16) & 1u)) >> 16);
}
__device__ inline float bf2f(unsigned short h) {
  return __uint_as_float((unsigned int)h << 16);
}

// ---------------------------------------------------------------------------
// Generic batched GEMM: Y[b] (M x N) = W (M x K) @ X[b] (K x N) (+bias) (+res)
// Tile 64x64, K-chunk 16, 256 threads, 4x4 micro-tile per thread.
// ---------------------------------------------------------------------------
template<bool HAS_BIAS, bool HAS_RES>
__global__ __launch_bounds__(256) void gemm_kernel(
    const float* __restrict__ W, const float* __restrict__ X,
    const float* __restrict__ bias, const float* __restrict__ res,
    float* __restrict__ Y, int M, int Nn, int K, long sX, long sY, long sR) {
  __shared__ float Ws[16][68];
  __shared__ float Xs[16][68];
  const int b = blockIdx.z;
  const float* Xb = X + (long)b * sX;
  float* Yb = Y + (long)b * sY;
  const int m0 = blockIdx.y * 64, n0 = blockIdx.x * 64;
  const int tid = threadIdx.x;
  const int tx = tid & 15, ty = tid >> 4;
  float acc[4][4] = {};
  for (int k0 = 0; k0 < K; k0 += 16) {
    {
      int r = tid >> 2;
      int c4 = (tid & 3) * 4;
      const float4 wv = *(const float4*)(W + (long)(m0 + r) * K + k0 + c4);
      Ws[c4 + 0][r] = wv.x; Ws[c4 + 1][r] = wv.y;
      Ws[c4 + 2][r] = wv.z; Ws[c4 + 3][r] = wv.w;
    }
    {
      int r = tid >> 4;
      int cR = (tid & 15) * 4;
      const float4 xv = *(const float4*)(Xb + (long)(k0 + r) * Nn + n0 + cR);
      *(float4*)&Xs[r][cR] = xv;
    }
    __syncthreads();
#pragma unroll
    for (int kk = 0; kk < 16; kk++) {
      float a[4], bx[4];
#pragma unroll
      for (int i = 0; i < 4; i++) a[i] = Ws[kk][ty * 4 + i];
#pragma unroll
      for (int j = 0; j < 4; j++) bx[j] = Xs[kk][tx * 4 + j];
#pragma unroll
      for (int i = 0; i < 4; i++)
#pragma unroll
        for (int j = 0; j < 4; j++) acc[i][j] += a[i] * bx[j];
    }
    __syncthreads();
  }
#pragma unroll
  for (int i = 0; i < 4; i++) {
    int m = m0 + ty * 4 + i;
    float bv = HAS_BIAS ? bias[m] : 0.f;
#pragma unroll
    for (int j = 0; j < 4; j++) {
      int n = n0 + tx * 4 + j;
      float v = acc[i][j] + bv;
      if (HAS_RES) v += res[(long)b * sR + (long)m * Nn + n];
      Yb[(long)m * Nn + n] = v;
    }
  }
}

// ---------------------------------------------------------------------------
// Concatenate spatial q/k/v weights into one [384][128] matrix.
// NOTE: launched after statreduce because skv_w aliases the spnum region.
// ---------------------------------------------------------------------------
__global__ __launch_bounds__(256) void fuse_w_kernel(
    const float* __restrict__ q_w, const float* __restrict__ k_w,
    const float* __restrict__ v_w, float* __restrict__ skv_w) {
  int i = blockIdx.x * 256 + threadIdx.x;  // 0 .. 3*16384-1
  int which = i >> 14, r = i & 16383;
  float v = (which == 0) ? q_w[r] : (which == 1) ? k_w[r] : v_w[r];
  skv_w[i] = v;
}

// ---------------------------------------------------------------------------
// FFT magnitude pooling: pooled[b,c] = mean |rfft2(y1[b,c], ortho)| over 32x17
// Also m1[b,c] = mean(y1[b,c]).  One block per (b,c) image.
// ---------------------------------------------------------------------------
__global__ __launch_bounds__(256) void fftpool_kernel(
    const float* __restrict__ yc, float* __restrict__ pooled, float* __restrict__ m1) {
  const int bc = blockIdx.x;
  const int b = bc >> 7, cx = bc & 127;
  const float* img = yc + ((long)b * 384 + 128 + cx) * NPIX;
  __shared__ float im[1024];
  __shared__ float Gr[32][17], Gi[32][17];
  __shared__ float cs[32], sn[32];
  __shared__ float red[256];
  const int t = threadIdx.x;
  if (t < 32) {
    float ang = -0.19634954084936207f * (float)t;  // -2*pi*t/32
    __sincosf(ang, &sn[t], &cs[t]);
  }
  float lsum = 0.f;
  for (int i = t; i < 1024; i += 256) { float v = img[i]; im[i] = v; lsum += v; }
  red[t] = lsum;
  __syncthreads();
  for (int s = 128; s > 0; s >>= 1) {
    if (t < s) red[t] += red[t + s];
    __syncthreads();
  }
  if (t == 0) m1[bc] = red[0] * (1.f / 1024.f);
  // stage 1: along w
  for (int i = t; i < 544; i += 256) {
    int h = i / 17, v = i % 17;
    float ar = 0.f, ai = 0.f;
    for (int w2 = 0; w2 < 32; w2++) {
      int k = (v * w2) & 31;
      float x = im[h * 32 + w2];
      ar += x * cs[k]; ai += x * sn[k];
    }
    Gr[h][v] = ar; Gi[h][v] = ai;
  }
  __syncthreads();
  // stage 2: along h, accumulate |X|
  float asum = 0.f;
  for (int i = t; i < 544; i += 256) {
    int u = i / 17, v = i % 17;
    float xr = 0.f, xi = 0.f;
    for (int h = 0; h < 32; h++) {
      int k = (u * h) & 31;
      float gr = Gr[h][v], gi = Gi[h][v];
      xr += gr * cs[k] - gi * sn[k];
      xi += gr * sn[k] + gi * cs[k];
    }
    asum += sqrtf(xr * xr + xi * xi);
  }
  red[t] = asum;
  __syncthreads();
  for (int s = 128; s > 0; s >>= 1) {
    if (t < s) red[t] += red[t + s];
    __syncthreads();
  }
  if (t == 0) pooled[bc] = red[0] * (1.f / (32.f * 544.f));
}

// ---------------------------------------------------------------------------
// Gates: fw/ca MLPs -> g = fw*ca; p_route -> alpha.  One block per batch.
// ---------------------------------------------------------------------------
__global__ __launch_bounds__(128) void gates_kernel(
    const float* __restrict__ pooled, const float* __restrict__ m1,
    const float* __restrict__ fm_w1, const float* __restrict__ fm_w2,
    const float* __restrict__ ca_w1, const float* __restrict__ ca_w2,
    const float* __restrict__ rt_w, const float* __restrict__ rt_b,
    float* __restrict__ g, float* __restrict__ alpha) {
  const int b = blockIdx.x, t = threadIdx.x;
  __shared__ float h1[8], fwv[128], xsm[128], h2[8];
  const float* pb = pooled + b * 128;
  const float* mb = m1 + b * 128;
  if (t < 8) {
    float s = 0.f;
    for (int c = 0; c < 128; c++) s += pb[c] * fm_w1[t * 128 + c];
    h1[t] = fmaxf(s, 0.f);
  }
  __syncthreads();
  {
    float s = 0.f;
    for (int r = 0; r < 8; r++) s += h1[r] * fm_w2[t * 8 + r];
    float fw = 1.f / (1.f + __expf(-s));
    fwv[t] = fw; xsm[t] = fw * mb[t];
  }
  __syncthreads();
  if (t < 8) {
    float s = 0.f;
    for (int c = 0; c < 128; c++) s += xsm[c] * ca_w1[t * 128 + c];
    h2[t] = fmaxf(s, 0.f);
  }
  __syncthreads();
  {
    float s = 0.f;
    for (int r = 0; r < 8; r++) s += h2[r] * ca_w2[t * 8 + r];
    float ca = 1.f / (1.f + __expf(-s));
    g[b * 128 + t] = fwv[t] * ca;
  }
  if (t == 0) {
    float s = 0.f;
    for (int c = 0; c < 128; c++) s += mb[c] * rt_w[c];
    s += rt_b[0];
    alpha[b] = 1.f / (1.f + __expf(-s));
  }
}

// ---------------------------------------------------------------------------
// Variance of k and v head vectors (ddof=1) + per-bh max(var_k).
// Also emits vT[bh][n][16] = v head vector (transposed copy for stat_attn).
// ---------------------------------------------------------------------------
__global__ __launch_bounds__(256) void varmax_kernel(
    const float* __restrict__ qkvb, float* __restrict__ var_k,
    float* __restrict__ var_v, float* __restrict__ maxvk,
    float* __restrict__ vT) {
  const int bh = blockIdx.x;
  const int b = bh >> 3, h = bh & 7;
  __shared__ float red[256];
  const float* kb = qkvb + ((long)b * 384 + 128 + h * 16) * NPIX;
  const float* vb = qkvb + ((long)b * 384 + 256 + h * 16) * NPIX;
  float mx = 0.f;
  for (int j = 0; j < 4; j++) {
    int n = threadIdx.x + j * 256;
    float xk[16], xv[16], sk = 0.f, sv = 0.f;
#pragma unroll
    for (int d = 0; d < 16; d++) {
      xk[d] = kb[(long)d * NPIX + n]; sk += xk[d];
      xv[d] = vb[(long)d * NPIX + n]; sv += xv[d];
    }
    float mk = sk * (1.f / 16.f), mv = sv * (1.f / 16.f);
    float vk_ = 0.f, vv_ = 0.f;
#pragma unroll
    for (int d = 0; d < 16; d++) {
      float a = xk[d] - mk; vk_ += a * a;
      float c = xv[d] - mv; vv_ += c * c;
    }
    vk_ *= (1.f / 15.f); vv_ *= (1.f / 15.f);
    var_k[(long)bh * NPIX + n] = vk_;
    var_v[(long)bh * NPIX + n] = vv_;
    mx = fmaxf(mx, vk_);
    float* vtr = vT + ((long)bh * NPIX + n) * 16;
    *(float4*)(vtr + 0)  = make_float4(xv[0], xv[1], xv[2], xv[3]);
    *(float4*)(vtr + 4)  = make_float4(xv[4], xv[5], xv[6], xv[7]);
    *(float4*)(vtr + 8)  = make_float4(xv[8], xv[9], xv[10], xv[11]);
    *(float4*)(vtr + 12) = make_float4(xv[12], xv[13], xv[14], xv[15]);
  }
  red[threadIdx.x] = mx;
  __syncthreads();
  for (int s = 128; s > 0; s >>= 1) {
    if (threadIdx.x < s) red[threadIdx.x] = fmaxf(red[threadIdx.x], red[threadIdx.x + s]);
    __syncthreads();
  }
  if (threadIdx.x == 0) maxvk[bh] = red[0];
}

// ---------------------------------------------------------------------------
// Stat attention (m-split x8 -> 512 blocks = 2/CU = 16 waves/CU).
// Thread owns 2n x 16d.  V read via vT with BLOCK-UNIFORM addresses
// (scalar-cache path; no LDS, no __syncthreads).  Partials in packed bf16.
// spnum word[mc][bh][d][nw] = (bf16(acc_n0), bf16(acc_n1)); spden fp32.
// ---------------------------------------------------------------------------
__global__ __launch_bounds__(512) void stat_attn_kernel(
    const float* __restrict__ vT, const float* __restrict__ var_k,
    const float* __restrict__ var_v, const float* __restrict__ maxvk,
    unsigned int* __restrict__ spnum, float* __restrict__ spden) {
  const int bh = blockIdx.x;
  const int mc = blockIdx.y;   // 0..7
  const int m0 = mc * 128;
  const int tid = threadIdx.x;
  const int n = tid * 2;
  const float2 cvv = *(const float2*)&var_v[(long)bh * NPIX + n];
  const float c0 = cvv.x * 0.25f, c1 = cvv.y * 0.25f;
  const float mv = maxvk[bh];
  const float* __restrict__ vrow = vT + ((long)bh * NPIX + m0) * 16;
  const float* __restrict__ vkp = var_k + (long)bh * NPIX + m0;
  float acc0[16], acc1[16];
#pragma unroll
  for (int d = 0; d < 16; d++) { acc0[d] = 0.f; acc1[d] = 0.f; }
  float den0 = 0.f, den1 = 0.f;
#pragma unroll 2
  for (int mm = 0; mm < 128; mm++) {
    float t = vkp[mm] - mv;  // uniform
    float e0 = __expf(c0 * t), e1 = __expf(c1 * t);
    den0 += e0; den1 += e1;
    const float* vr = vrow + mm * 16;  // uniform address -> scalar loads
    const float4 vA = *(const float4*)(vr + 0);
    const float4 vB = *(const float4*)(vr + 4);
    const float4 vC = *(const float4*)(vr + 8);
    const float4 vD = *(const float4*)(vr + 12);
    acc0[0] += e0 * vA.x; acc0[1] += e0 * vA.y; acc0[2] += e0 * vA.z; acc0[3] += e0 * vA.w;
    acc0[4] += e0 * vB.x; acc0[5] += e0 * vB.y; acc0[6] += e0 * vB.z; acc0[7] += e0 * vB.w;
    acc0[8] += e0 * vC.x; acc0[9] += e0 * vC.y; acc0[10] += e0 * vC.z; acc0[11] += e0 * vC.w;
    acc0[12] += e0 * vD.x; acc0[13] += e0 * vD.y; acc0[14] += e0 * vD.z; acc0[15] += e0 * vD.w;
    acc1[0] += e1 * vA.x; acc1[1] += e1 * vA.y; acc1[2] += e1 * vA.z; acc1[3] += e1 * vA.w;
    acc1[4] += e1 * vB.x; acc1[5] += e1 * vB.y; acc1[6] += e1 * vB.z; acc1[7] += e1 * vB.w;
    acc1[8] += e1 * vC.x; acc1[9] += e1 * vC.y; acc1[10] += e1 * vC.z; acc1[11] += e1 * vC.w;
    acc1[12] += e1 * vD.x; acc1[13] += e1 * vD.y; acc1[14] += e1 * vD.z; acc1[15] += e1 * vD.w;
  }
  unsigned int* np = spnum + ((long)(mc * 64 + bh) * 16) * 512 + tid;
#pragma unroll
  for (int d = 0; d < 16; d++)
    np[(long)d * 512] = (unsigned int)f2bf(acc0[d]) | ((unsigned int)f2bf(acc1[d]) << 16);
  *(float2*)&spden[((long)mc * 64 + bh) * 1024 + n] = make_float2(den0, den1);
}

// ---------------------------------------------------------------------------
// Reduce stat partials (8 chunks, packed-bf16 numerators, fp32 denominators):
// to_cn[(bh*16+d)*1024 + n] = sum(num)/sum(den).  One thread per packed word.
// ---------------------------------------------------------------------------
__global__ __launch_bounds__(256) void statreduce_kernel(
    const unsigned int* __restrict__ spnum, const float* __restrict__ spden,
    float* __restrict__ to_cn) {
  long i = (long)blockIdx.x * 256 + threadIdx.x;  // 64*16*512 words
  int nw = (int)(i & 511);
  long bhd = i >> 9;  // bh*16+d
  int bh = (int)(bhd >> 4);
  const long ns = 64L * 16 * 512;
  float num0 = 0.f, num1 = 0.f;
#pragma unroll
  for (int s = 0; s < 8; s++) {
    unsigned int w = spnum[i + (long)s * ns];
    num0 += bf2f((unsigned short)(w & 0xFFFFu));
    num1 += bf2f((unsigned short)(w >> 16));
  }
  const long ds = 64L * 1024;
  long di = (long)bh * 1024 + nw * 2;
  float den0 = 0.f, den1 = 0.f;
#pragma unroll
  for (int s = 0; s < 8; s++) {
    float2 dv = *(const float2*)&spden[di + (long)s * ds];
    den0 += dv.x; den1 += dv.y;
  }
  *(float2*)&to_cn[bhd * 1024 + nw * 2] = make_float2(num0 / den0, num1 / den1);
}

// ---------------------------------------------------------------------------
// Bit-pack signs of fused spatial q/k projections.
// ---------------------------------------------------------------------------
__global__ __launch_bounds__(256) void pack_kernel(
    const float* __restrict__ sqkv,
    unsigned long long* __restrict__ qbits, unsigned long long* __restrict__ kbits) {
  const int wave = threadIdx.x >> 6, lane = threadIdx.x & 63;
  const long p = (long)blockIdx.x * 4 + wave;  // 0..8191
  const int b = (int)(p >> 10), n = (int)(p & 1023);
  const float* base = sqkv + (long)b * 384 * NPIX + n;
  unsigned long long q0 = __ballot(base[(long)lane * NPIX] > 0.f);
  unsigned long long q1 = __ballot(base[(long)(64 + lane) * NPIX] > 0.f);
  unsigned long long k0 = __ballot(base[(long)(128 + lane) * NPIX] > 0.f);
  unsigned long long k1 = __ballot(base[(long)(192 + lane) * NPIX] > 0.f);
  if (lane == 0) {
    qbits[p * 2] = q0; qbits[p * 2 + 1] = q1;
    kbits[p * 2] = k0; kbits[p * 2 + 1] = k1;
  }
}

// ---------------------------------------------------------------------------
// K-split fused binary-attention GEMM (sproj pre-folded: pv = sproj_w @ vv).
// Each block: 64x64 output tile over K-range [sp*256, sp*256+256).
// pnum[sp][b][c][n] = sum_m pv[b,c,m]*w[m,n];  pden[sp][b][n] = sum_m w[m,n]
// (written by mt==0 blocks only).  Grid (16, 2*4, 8) = 1024 blocks.
// w[m,n] = exp((128-2*popc(q[n]^k[m]))/sqrt(128)), fp32-safe unnormalized.
// ---------------------------------------------------------------------------
__global__ __launch_bounds__(256) void obgemm_kernel(
    const float* __restrict__ pv, const unsigned long long* __restrict__ qbits,
    const unsigned long long* __restrict__ kbits, float* __restrict__ pnum,
    float* __restrict__ pden) {
  const int b = blockIdx.z;
  const int mt = blockIdx.y & 1, sp = blockIdx.y >> 1;
  const int c0 = mt * 64, n0 = blockIdx.x * 64;
  const int kb0 = sp * 256;
  __shared__ float Ws[16][68];
  __shared__ float Xs[16][68];
  __shared__ float psum[16][68];
  __shared__ unsigned long long qn[64][2];
  const int tid = threadIdx.x;
  if (tid < 64) {
    qn[tid][0] = qbits[((long)b * 1024 + n0 + tid) * 2];
    qn[tid][1] = qbits[((long)b * 1024 + n0 + tid) * 2 + 1];
  }
  __syncthreads();
  const int tx = tid & 15, ty = tid >> 4;
  const float fs = 0.08838834764831845f;
  float acc[4][4] = {};
  float pcs[4] = {};
  for (int k0 = kb0; k0 < kb0 + 256; k0 += 16) {
    {
      int r = tid >> 2, c4 = (tid & 3) * 4;
      const float4 wv = *(const float4*)(pv + ((long)b * 128 + c0 + r) * 1024 + k0 + c4);
      Ws[c4 + 0][r] = wv.x; Ws[c4 + 1][r] = wv.y;
      Ws[c4 + 2][r] = wv.z; Ws[c4 + 3][r] = wv.w;
    }
    {
      int kr = tid >> 4, nc = (tid & 15) * 4;
      unsigned long long kw0 = kbits[((long)b * 1024 + k0 + kr) * 2];
      unsigned long long kw1 = kbits[((long)b * 1024 + k0 + kr) * 2 + 1];
#pragma unroll
      for (int j = 0; j < 4; j++) {
        int ham = __popcll(qn[nc + j][0] ^ kw0) + __popcll(qn[nc + j][1] ^ kw1);
        float w = __expf((float)(128 - 2 * ham) * fs);
        Xs[kr][nc + j] = w;
        pcs[j] += w;
      }
    }
    __syncthreads();
#pragma unroll
    for (int kk = 0; kk < 16; kk++) {
      float a[4], bx[4];
#pragma unroll
      for (int i = 0; i < 4; i++) a[i] = Ws[kk][ty * 4 + i];
#pragma unroll
      for (int j = 0; j < 4; j++) bx[j] = Xs[kk][tx * 4 + j];
#pragma unroll
      for (int i = 0; i < 4; i++)
#pragma unroll
        for (int j = 0; j < 4; j++) acc[i][j] += a[i] * bx[j];
    }
    __syncthreads();
  }
  // partial-numerator write (vectorized)
  float* dst = pnum + (((long)sp * 8 + b) * 128 + c0) * 1024 + n0;
#pragma unroll
  for (int i = 0; i < 4; i++) {
    float4 o = make_float4(acc[i][0], acc[i][1], acc[i][2], acc[i][3]);
    *(float4*)(dst + (long)(ty * 4 + i) * 1024 + tx * 4) = o;
  }
  // partial denominators (only one m-tile needs to write them)
  {
    int kr = tid >> 4, nc = (tid & 15) * 4;
#pragma unroll
    for (int j = 0; j < 4; j++) psum[kr][nc + j] = pcs[j];
  }
  __syncthreads();
  if (mt == 0 && tid < 64) {
    float d = 0.f;
#pragma unroll
    for (int r = 0; r < 16; r++) d += psum[r][tid];
    pden[((long)sp * 8 + b) * 1024 + n0 + tid] = d;
  }
}

// ---------------------------------------------------------------------------
// Reduce K-split partials: obp[b,o,n] = sum_sp(pnum)/sum_sp(pden) + sproj_b[o]
// ---------------------------------------------------------------------------
__global__ __launch_bounds__(256) void obreduce_kernel(
    const float* __restrict__ pnum, const float* __restrict__ pden,
    const float* __restrict__ sproj_b, float* __restrict__ obp) {
  long i = (long)blockIdx.x * 256 + threadIdx.x;  // 8*128*1024
  int n = (int)(i & 1023);
  long bo = i >> 10;
  int b = (int)(bo >> 7), o = (int)(bo & 127);
  const long ns = 8L * 128 * 1024;
  float num = pnum[i] + pnum[i + ns] + pnum[i + 2 * ns] + pnum[i + 3 * ns];
  const long ds = 8L * 1024;
  long di = (long)b * 1024 + n;
  float den = pden[di] + pden[di + ds] + pden[di + 2 * ds] + pden[di + 3 * ds];
  obp[i] = num / den + sproj_b[o];
}

// ---------------------------------------------------------------------------
// Fused depthwise 3x3 conv + combine:
// yc[b,256+c,n] += g*y1 + (1-a)*dwconv(y1) + a*obp.  One block per (b,c).
// ---------------------------------------------------------------------------
__global__ __launch_bounds__(256) void dwcombine_kernel(
    float* __restrict__ yc, const float* __restrict__ dw_w,
    const float* __restrict__ dw_b, const float* __restrict__ obp,
    const float* __restrict__ g, const float* __restrict__ alpha) {
  const int bc = blockIdx.x;
  const int b = bc >> 7, cx = bc & 127;
  const float* img = yc + ((long)b * 384 + 128 + cx) * NPIX;
  float* dst = yc + ((long)b * 384 + 256 + cx) * NPIX;
  float w[9];
#pragma unroll
  for (int i = 0; i < 9; i++) w[i] = dw_w[cx * 9 + i];
  const float bias = dw_b[cx];
  const float a = alpha[b];
  const float gg = g[bc];
  for (int i = threadIdx.x; i < 1024; i += 256) {
    int h = i >> 5, wx = i & 31;
    float s = bias;
#pragma unroll
    for (int ky = 0; ky < 3; ky++) {
      int hh = h + ky - 1;
      if (hh < 0 || hh > 31) continue;
#pragma unroll
      for (int kx = 0; kx < 3; kx++) {
        int ww2 = wx + kx - 1;
        if (ww2 < 0 || ww2 > 31) continue;
        s += img[hh * 32 + ww2] * w[ky * 3 + kx];
      }
    }
    dst[i] = dst[i] + gg * img[i] + (1.f - a) * s + a * obp[(long)bc * NPIX + i];
  }
}

// ---------------------------------------------------------------------------
extern "C" void kernel_launch(void* const* d_in, const int* in_sizes, int n_in,
                              void* d_out, int out_size, void* d_ws, size_t ws_size,
                              hipStream_t stream) {
  const float* x = (const float*)d_in[0];
  const float* cv1_w = (const float*)d_in[1];
  const float* cv1_b = (const float*)d_in[2];
  const float* fm_w1 = (const float*)d_in[3];
  const float* fm_w2 = (const float*)d_in[4];
  const float* ca_w1 = (const float*)d_in[5];
  const float* ca_w2 = (const float*)d_in[6];
  const float* qkv_w = (const float*)d_in[7];
  const float* tproj_w = (const float*)d_in[8];
  const float* tproj_b = (const float*)d_in[9];
  const float* dw_w = (const float*)d_in[10];
  const float* dw_b = (const float*)d_in[11];
  const float* rt_w = (const float*)d_in[12];
  const float* rt_b = (const float*)d_in[13];
  const float* q_w = (const float*)d_in[14];
  const float* k_w = (const float*)d_in[15];
  const float* v_w = (const float*)d_in[16];
  const float* sproj_w = (const float*)d_in[17];
  const float* sproj_b = (const float*)d_in[18];
  const float* cv2_w = (const float*)d_in[19];
  const float* cv2_b = (const float*)d_in[20];
  float* out = (float*)d_out;

  char* wsp = (char*)d_ws;
  size_t off = 0;
  auto alloc = [&](size_t bytes) {
    void* p = wsp + off;
    off += (bytes + 255) & ~(size_t)255;
    return p;
  };
  float* yc = (float*)alloc(8UL * 384 * 1024 * 4);
  float* qkvb = (float*)alloc(8UL * 384 * 1024 * 4);   // also ob pnum[0..2]
  float* to_cn = (float*)alloc(8UL * 128 * 1024 * 4);  // also ob pnum[3]
  float* sqkv = (float*)alloc(8UL * 384 * 1024 * 4);   // also obp; spnum head
  float* skv_w = (float*)alloc(384UL * 128 * 4);       // inside spnum span
  float* pv = (float*)alloc(8UL * 128 * 1024 * 4);     // spnum tail
  float* vT = (float*)alloc(64UL * 1024 * 16 * 4);
  float* pden = (float*)alloc(4UL * 8 * 1024 * 4);
  float* spden = (float*)alloc(8UL * 64 * 1024 * 4);
  float* var_k = (float*)alloc(8UL * 8 * 1024 * 4);
  float* var_v = (float*)alloc(8UL * 8 * 1024 * 4);
  float* maxvk = (float*)alloc(64 * 4);
  float* pooled = (float*)alloc(1024 * 4);
  float* m1 = (float*)alloc(1024 * 4);
  float* g = (float*)alloc(1024 * 4);
  float* alpha = (float*)alloc(8 * 4);
  unsigned long long* qbits = (unsigned long long*)alloc(8192UL * 2 * 8);
  unsigned long long* kbits = (unsigned long long*)alloc(8192UL * 2 * 8);
  // aliases (lifetime-disjoint):
  float* pnum = qkvb;  // ob partials: 16MB spans qkvb+to_cn, dead by step 10
  float* obp = sqkv;   // sqkv dead after pack + pv
  unsigned int* spnum = (unsigned int*)sqkv;  // 16.78MB bf16 partials span
                                              // sqkv+skv_w+pv (16.97MB free at step 6)
  if (off > ws_size) return;

  dim3 blk(256);
  // 1. cv1: yc[:,0:256,:] = cv1_w @ x + cv1_b
  gemm_kernel<true, false><<<dim3(16, 4, 8), blk, 0, stream>>>(
      cv1_w, x, cv1_b, nullptr, yc, 256, 1024, 256, 256L * 1024, 384L * 1024, 0);
  // 2. FFT pooling + channel means
  fftpool_kernel<<<dim3(1024), blk, 0, stream>>>(yc, pooled, m1);
  // 3. gates
  gates_kernel<<<dim3(8), dim3(128), 0, stream>>>(pooled, m1, fm_w1, fm_w2,
                                                  ca_w1, ca_w2, rt_w, rt_b, g, alpha);
  // 4. qkv projection (stat attention)
  gemm_kernel<false, false><<<dim3(16, 6, 8), blk, 0, stream>>>(
      qkv_w, yc + 128 * 1024, nullptr, nullptr, qkvb, 384, 1024, 128,
      384L * 1024, 384L * 1024, 0);
  // 5. variances + per-bh max + transposed V copy
  varmax_kernel<<<dim3(64), blk, 0, stream>>>(qkvb, var_k, var_v, maxvk, vT);
  // 6. stat attention (m-split x8, scalar-path V reads) -> bf16 partials
  stat_attn_kernel<<<dim3(64, 8), dim3(512), 0, stream>>>(vT, var_k, var_v,
                                                          maxvk, spnum, spden);
  // 6b. reduce stat partials -> to_cn
  statreduce_kernel<<<dim3(2048), blk, 0, stream>>>(spnum, spden, to_cn);
  // 7. tproj -> yc[:,256:384,:] (stat_out)
  gemm_kernel<true, false><<<dim3(16, 2, 8), blk, 0, stream>>>(
      tproj_w, to_cn, tproj_b, nullptr, yc + 256 * 1024, 128, 1024, 128,
      128L * 1024, 384L * 1024, 0);
  // 7b. fuse spatial q/k/v weights (after statreduce: skv_w aliases spnum)
  fuse_w_kernel<<<dim3(192), blk, 0, stream>>>(q_w, k_w, v_w, skv_w);
  // 8. fused spatial q/k/v projection
  gemm_kernel<false, false><<<dim3(16, 6, 8), blk, 0, stream>>>(
      skv_w, yc + 128 * 1024, nullptr, nullptr, sqkv, 384, 1024, 128,
      384L * 1024, 384L * 1024, 0);
  // 9. sign pack
  pack_kernel<<<dim3(2048), blk, 0, stream>>>(sqkv, qbits, kbits);
  // 9b. pv = sproj_w @ vv (sproj folded through attention by associativity)
  gemm_kernel<false, false><<<dim3(16, 2, 8), blk, 0, stream>>>(
      sproj_w, sqkv + 256 * 1024, nullptr, nullptr, pv, 128, 1024, 128,
      384L * 1024, 128L * 1024, 0);
  // 10. K-split fused a2-gen GEMM -> partials (1024 blocks, 4/CU)
  obgemm_kernel<<<dim3(16, 8, 8), blk, 0, stream>>>(pv, qbits, kbits, pnum, pden);
  // 10b. reduce partials + divide + bias -> obp
  obreduce_kernel<<<dim3(4096), blk, 0, stream>>>(pnum, pden, sproj_b, obp);
  // 11. fused depthwise conv + combine into yc attn region
  dwcombine_kernel<<<dim3(1024), blk, 0, stream>>>(yc, dw_w, dw_b, obp, g, alpha);
  // 12. cv2 + residual
  gemm_kernel<true, true><<<dim3(16, 4, 8), blk, 0, stream>>>(
      cv2_w, yc, cv2_b, x, out, 256, 1024, 384, 384L * 1024, 256L * 1024,
      256L * 1024);
}

// Round 12
// 209.441 us; speedup vs baseline: 2.0137x; 1.2148x over previous
//
#include <hip/hip_runtime.h>
#include <math.h>

// Problem constants
#define BATCH 8
#define NPIX 1024   // 32*32

typedef __attribute__((ext_vector_type(8))) short short8v;
typedef __attribute__((ext_vector_type(4))) float f32x4;

__device__ inline unsigned short f2bf(float x) {  // fp32 -> bf16 RNE
  unsigned int u = __float_as_uint(x);
  return (unsigned short)((u + 0x7FFFu + ((u >> 16) & 1u)) >> 16);
}
__device__ inline float bf2f(unsigned short h) {
  return __uint_as_float((unsigned int)h << 16);
}

// ---------------------------------------------------------------------------
// Convert all weights to one bf16 arena (offsets hardcoded):
// [0,65536) cv1_w | [65536,114688) qkv_w | [114688,131072) tproj_w
// [131072,147456) sproj_w | [147456,245760) cv2_w | [245760,294912) q|k|v
// ---------------------------------------------------------------------------
__global__ __launch_bounds__(256) void convw_kernel(
    const float* __restrict__ cv1_w, const float* __restrict__ qkv_w,
    const float* __restrict__ tproj_w, const float* __restrict__ sproj_w,
    const float* __restrict__ cv2_w, const float* __restrict__ q_w,
    const float* __restrict__ k_w, const float* __restrict__ v_w,
    short* __restrict__ wb) {
  int i = blockIdx.x * 256 + threadIdx.x;  // < 294912
  float v;
  if (i < 65536) v = cv1_w[i];
  else if (i < 114688) v = qkv_w[i - 65536];
  else if (i < 131072) v = tproj_w[i - 114688];
  else if (i < 147456) v = sproj_w[i - 131072];
  else if (i < 245760) v = cv2_w[i - 147456];
  else {
    int j = i - 245760, wsel = j >> 14, r = j & 16383;
    v = (wsel == 0) ? q_w[r] : (wsel == 1) ? k_w[r] : v_w[r];
  }
  wb[i] = (short)f2bf(v);
}

// ---------------------------------------------------------------------------
// Transpose + convert: dst[b][n][c] (bf16) = src[b][c][n] (fp32).
// Grid (C/64, 16, 8), 256 threads, LDS 64x65 tile.
// ---------------------------------------------------------------------------
__global__ __launch_bounds__(256) void tconv_kernel(
    const float* __restrict__ src, long sSrc, int C, short* __restrict__ dst) {
  __shared__ float t[64][65];
  const int b = blockIdx.z;
  const int c0 = blockIdx.x * 64, n0 = blockIdx.y * 64;
  const float* s = src + (long)b * sSrc;
  short* d = dst + (long)b * 1024 * C;
  const int tid = threadIdx.x;
#pragma unroll
  for (int p = 0; p < 16; p++) {
    int idx = tid + p * 256;
    int cl = idx >> 6, nl = idx & 63;
    t[cl][nl] = s[(long)(c0 + cl) * 1024 + n0 + nl];
  }
  __syncthreads();
#pragma unroll
  for (int p = 0; p < 16; p++) {
    int idx = tid + p * 256;
    int nl = idx >> 6, cl = idx & 63;
    d[(long)(n0 + nl) * C + c0 + cl] = (short)f2bf(t[cl][nl]);
  }
}

// ---------------------------------------------------------------------------
// MFMA bf16 GEMM: Y[b](MxN=1024) = Wb(MxK bf16) @ X where XT[b] is (N x K)
// bf16 (k-contiguous).  64x64 tile, 4 waves (2x2), each wave 2x2 MFMA tiles
// of 16x16x32.  A-frag lane l: row=l&15, k=(l>>4)*8+[0..8); B-frag from XT
// same pattern; C/D: col=lane&15, row=(lane>>4)*4+reg (guide-verified).
// ---------------------------------------------------------------------------
template<bool HAS_BIAS, bool HAS_RES>
__global__ __launch_bounds__(256) void mgemm_kernel(
    const short* __restrict__ Wb, const short* __restrict__ XT,
    const float* __restrict__ bias, const float* __restrict__ res,
    float* __restrict__ Y, int K, long sXT, long sY, long sR) {
  __shared__ __align__(16) short As[64][40];  // 80B rows: 2-way-free banks
  __shared__ __align__(16) short Bs[64][40];
  const int b = blockIdx.z;
  const int n0 = blockIdx.x * 64, m0 = blockIdx.y * 64;
  const int tid = threadIdx.x;
  const int l = tid & 63, w = tid >> 6;
  const int wm = w >> 1, wn = w & 1;
  const short* Xb = XT + (long)b * sXT;
  const int sr = tid >> 2, sko = (tid & 3) * 8;
  const int fr = l & 15, fk = (l >> 4) * 8;
  f32x4 acc[2][2] = {};
  for (int k0 = 0; k0 < K; k0 += 32) {
    *(uint4*)&As[sr][sko] = *(const uint4*)(Wb + (long)(m0 + sr) * K + k0 + sko);
    *(uint4*)&Bs[sr][sko] = *(const uint4*)(Xb + (long)(n0 + sr) * K + k0 + sko);
    __syncthreads();
    short8v a0 = *(short8v*)&As[wm * 32 + fr][fk];
    short8v a1 = *(short8v*)&As[wm * 32 + 16 + fr][fk];
    short8v b0 = *(short8v*)&Bs[wn * 32 + fr][fk];
    short8v b1 = *(short8v*)&Bs[wn * 32 + 16 + fr][fk];
    acc[0][0] = __builtin_amdgcn_mfma_f32_16x16x32_bf16(a0, b0, acc[0][0], 0, 0, 0);
    acc[0][1] = __builtin_amdgcn_mfma_f32_16x16x32_bf16(a0, b1, acc[0][1], 0, 0, 0);
    acc[1][0] = __builtin_amdgcn_mfma_f32_16x16x32_bf16(a1, b0, acc[1][0], 0, 0, 0);
    acc[1][1] = __builtin_amdgcn_mfma_f32_16x16x32_bf16(a1, b1, acc[1][1], 0, 0, 0);
    __syncthreads();
  }
  float* Yb = Y + (long)b * sY;
#pragma unroll
  for (int tm = 0; tm < 2; tm++) {
#pragma unroll
    for (int i = 0; i < 4; i++) {
      int m = m0 + wm * 32 + tm * 16 + (l >> 4) * 4 + i;
      float bv = HAS_BIAS ? bias[m] : 0.f;
#pragma unroll
      for (int tn = 0; tn < 2; tn++) {
        int n = n0 + wn * 32 + tn * 16 + (l & 15);
        float v = acc[tm][tn][i] + bv;
        if (HAS_RES) v += res[(long)b * sR + (long)m * 1024 + n];
        Yb[(long)m * 1024 + n] = v;
      }
    }
  }
}

// ---------------------------------------------------------------------------
// FFT magnitude pooling: pooled[b,c] = mean |rfft2(y1[b,c], ortho)| over 32x17
// Also m1[b,c] = mean(y1[b,c]).  One block per (b,c) image.
// ---------------------------------------------------------------------------
__global__ __launch_bounds__(256) void fftpool_kernel(
    const float* __restrict__ yc, float* __restrict__ pooled, float* __restrict__ m1) {
  const int bc = blockIdx.x;
  const int b = bc >> 7, cx = bc & 127;
  const float* img = yc + ((long)b * 384 + 128 + cx) * NPIX;
  __shared__ float im[1024];
  __shared__ float Gr[32][17], Gi[32][17];
  __shared__ float cs[32], sn[32];
  __shared__ float red[256];
  const int t = threadIdx.x;
  if (t < 32) {
    float ang = -0.19634954084936207f * (float)t;  // -2*pi*t/32
    __sincosf(ang, &sn[t], &cs[t]);
  }
  float lsum = 0.f;
  for (int i = t; i < 1024; i += 256) { float v = img[i]; im[i] = v; lsum += v; }
  red[t] = lsum;
  __syncthreads();
  for (int s = 128; s > 0; s >>= 1) {
    if (t < s) red[t] += red[t + s];
    __syncthreads();
  }
  if (t == 0) m1[bc] = red[0] * (1.f / 1024.f);
  // stage 1: along w
  for (int i = t; i < 544; i += 256) {
    int h = i / 17, v = i % 17;
    float ar = 0.f, ai = 0.f;
    for (int w2 = 0; w2 < 32; w2++) {
      int k = (v * w2) & 31;
      float x = im[h * 32 + w2];
      ar += x * cs[k]; ai += x * sn[k];
    }
    Gr[h][v] = ar; Gi[h][v] = ai;
  }
  __syncthreads();
  // stage 2: along h, accumulate |X|
  float asum = 0.f;
  for (int i = t; i < 544; i += 256) {
    int u = i / 17, v = i % 17;
    float xr = 0.f, xi = 0.f;
    for (int h = 0; h < 32; h++) {
      int k = (u * h) & 31;
      float gr = Gr[h][v], gi = Gi[h][v];
      xr += gr * cs[k] - gi * sn[k];
      xi += gr * sn[k] + gi * cs[k];
    }
    asum += sqrtf(xr * xr + xi * xi);
  }
  red[t] = asum;
  __syncthreads();
  for (int s = 128; s > 0; s >>= 1) {
    if (t < s) red[t] += red[t + s];
    __syncthreads();
  }
  if (t == 0) pooled[bc] = red[0] * (1.f / (32.f * 544.f));
}

// ---------------------------------------------------------------------------
// Gates: fw/ca MLPs -> g = fw*ca; p_route -> alpha.  One block per batch.
// ---------------------------------------------------------------------------
__global__ __launch_bounds__(128) void gates_kernel(
    const float* __restrict__ pooled, const float* __restrict__ m1,
    const float* __restrict__ fm_w1, const float* __restrict__ fm_w2,
    const float* __restrict__ ca_w1, const float* __restrict__ ca_w2,
    const float* __restrict__ rt_w, const float* __restrict__ rt_b,
    float* __restrict__ g, float* __restrict__ alpha) {
  const int b = blockIdx.x, t = threadIdx.x;
  __shared__ float h1[8], fwv[128], xsm[128], h2[8];
  const float* pb = pooled + b * 128;
  const float* mb = m1 + b * 128;
  if (t < 8) {
    float s = 0.f;
    for (int c = 0; c < 128; c++) s += pb[c] * fm_w1[t * 128 + c];
    h1[t] = fmaxf(s, 0.f);
  }
  __syncthreads();
  {
    float s = 0.f;
    for (int r = 0; r < 8; r++) s += h1[r] * fm_w2[t * 8 + r];
    float fw = 1.f / (1.f + __expf(-s));
    fwv[t] = fw; xsm[t] = fw * mb[t];
  }
  __syncthreads();
  if (t < 8) {
    float s = 0.f;
    for (int c = 0; c < 128; c++) s += xsm[c] * ca_w1[t * 128 + c];
    h2[t] = fmaxf(s, 0.f);
  }
  __syncthreads();
  {
    float s = 0.f;
    for (int r = 0; r < 8; r++) s += h2[r] * ca_w2[t * 8 + r];
    float ca = 1.f / (1.f + __expf(-s));
    g[b * 128 + t] = fwv[t] * ca;
  }
  if (t == 0) {
    float s = 0.f;
    for (int c = 0; c < 128; c++) s += mb[c] * rt_w[c];
    s += rt_b[0];
    alpha[b] = 1.f / (1.f + __expf(-s));
  }
}

// ---------------------------------------------------------------------------
// Variance of k and v head vectors (ddof=1) + per-bh max(var_k).
// Also emits vT[bh][n][16] = v head vector (transposed copy for stat_attn).
// ---------------------------------------------------------------------------
__global__ __launch_bounds__(256) void varmax_kernel(
    const float* __restrict__ qkvb, float* __restrict__ var_k,
    float* __restrict__ var_v, float* __restrict__ maxvk,
    float* __restrict__ vT) {
  const int bh = blockIdx.x;
  const int b = bh >> 3, h = bh & 7;
  __shared__ float red[256];
  const float* kb = qkvb + ((long)b * 384 + 128 + h * 16) * NPIX;
  const float* vb = qkvb + ((long)b * 384 + 256 + h * 16) * NPIX;
  float mx = 0.f;
  for (int j = 0; j < 4; j++) {
    int n = threadIdx.x + j * 256;
    float xk[16], xv[16], sk = 0.f, sv = 0.f;
#pragma unroll
    for (int d = 0; d < 16; d++) {
      xk[d] = kb[(long)d * NPIX + n]; sk += xk[d];
      xv[d] = vb[(long)d * NPIX + n]; sv += xv[d];
    }
    float mk = sk * (1.f / 16.f), mv = sv * (1.f / 16.f);
    float vk_ = 0.f, vv_ = 0.f;
#pragma unroll
    for (int d = 0; d < 16; d++) {
      float a = xk[d] - mk; vk_ += a * a;
      float c = xv[d] - mv; vv_ += c * c;
    }
    vk_ *= (1.f / 15.f); vv_ *= (1.f / 15.f);
    var_k[(long)bh * NPIX + n] = vk_;
    var_v[(long)bh * NPIX + n] = vv_;
    mx = fmaxf(mx, vk_);
    float* vtr = vT + ((long)bh * NPIX + n) * 16;
    *(float4*)(vtr + 0)  = make_float4(xv[0], xv[1], xv[2], xv[3]);
    *(float4*)(vtr + 4)  = make_float4(xv[4], xv[5], xv[6], xv[7]);
    *(float4*)(vtr + 8)  = make_float4(xv[8], xv[9], xv[10], xv[11]);
    *(float4*)(vtr + 12) = make_float4(xv[12], xv[13], xv[14], xv[15]);
  }
  red[threadIdx.x] = mx;
  __syncthreads();
  for (int s = 128; s > 0; s >>= 1) {
    if (threadIdx.x < s) red[threadIdx.x] = fmaxf(red[threadIdx.x], red[threadIdx.x + s]);
    __syncthreads();
  }
  if (threadIdx.x == 0) maxvk[bh] = red[0];
}

// ---------------------------------------------------------------------------
// Stat attention (m-split x8 -> 512 blocks).  Thread owns 2n x 16d.
// V read via vT with block-uniform addresses.  Partials packed bf16.
// ---------------------------------------------------------------------------
__global__ __launch_bounds__(512) void stat_attn_kernel(
    const float* __restrict__ vT, const float* __restrict__ var_k,
    const float* __restrict__ var_v, const float* __restrict__ maxvk,
    unsigned int* __restrict__ spnum, float* __restrict__ spden) {
  const int bh = blockIdx.x;
  const int mc = blockIdx.y;   // 0..7
  const int m0 = mc * 128;
  const int tid = threadIdx.x;
  const int n = tid * 2;
  const float2 cvv = *(const float2*)&var_v[(long)bh * NPIX + n];
  const float c0 = cvv.x * 0.25f, c1 = cvv.y * 0.25f;
  const float mv = maxvk[bh];
  const float* __restrict__ vrow = vT + ((long)bh * NPIX + m0) * 16;
  const float* __restrict__ vkp = var_k + (long)bh * NPIX + m0;
  float acc0[16], acc1[16];
#pragma unroll
  for (int d = 0; d < 16; d++) { acc0[d] = 0.f; acc1[d] = 0.f; }
  float den0 = 0.f, den1 = 0.f;
#pragma unroll 2
  for (int mm = 0; mm < 128; mm++) {
    float t = vkp[mm] - mv;  // uniform
    float e0 = __expf(c0 * t), e1 = __expf(c1 * t);
    den0 += e0; den1 += e1;
    const float* vr = vrow + mm * 16;  // uniform address -> scalar loads
    const float4 vA = *(const float4*)(vr + 0);
    const float4 vB = *(const float4*)(vr + 4);
    const float4 vC = *(const float4*)(vr + 8);
    const float4 vD = *(const float4*)(vr + 12);
    acc0[0] += e0 * vA.x; acc0[1] += e0 * vA.y; acc0[2] += e0 * vA.z; acc0[3] += e0 * vA.w;
    acc0[4] += e0 * vB.x; acc0[5] += e0 * vB.y; acc0[6] += e0 * vB.z; acc0[7] += e0 * vB.w;
    acc0[8] += e0 * vC.x; acc0[9] += e0 * vC.y; acc0[10] += e0 * vC.z; acc0[11] += e0 * vC.w;
    acc0[12] += e0 * vD.x; acc0[13] += e0 * vD.y; acc0[14] += e0 * vD.z; acc0[15] += e0 * vD.w;
    acc1[0] += e1 * vA.x; acc1[1] += e1 * vA.y; acc1[2] += e1 * vA.z; acc1[3] += e1 * vA.w;
    acc1[4] += e1 * vB.x; acc1[5] += e1 * vB.y; acc1[6] += e1 * vB.z; acc1[7] += e1 * vB.w;
    acc1[8] += e1 * vC.x; acc1[9] += e1 * vC.y; acc1[10] += e1 * vC.z; acc1[11] += e1 * vC.w;
    acc1[12] += e1 * vD.x; acc1[13] += e1 * vD.y; acc1[14] += e1 * vD.z; acc1[15] += e1 * vD.w;
  }
  unsigned int* np = spnum + ((long)(mc * 64 + bh) * 16) * 512 + tid;
#pragma unroll
  for (int d = 0; d < 16; d++)
    np[(long)d * 512] = (unsigned int)f2bf(acc0[d]) | ((unsigned int)f2bf(acc1[d]) << 16);
  *(float2*)&spden[((long)mc * 64 + bh) * 1024 + n] = make_float2(den0, den1);
}

// ---------------------------------------------------------------------------
// Reduce stat partials -> to_cn[(bh*16+d)*1024 + n] = sum(num)/sum(den)
// ---------------------------------------------------------------------------
__global__ __launch_bounds__(256) void statreduce_kernel(
    const unsigned int* __restrict__ spnum, const float* __restrict__ spden,
    float* __restrict__ to_cn) {
  long i = (long)blockIdx.x * 256 + threadIdx.x;  // 64*16*512 words
  int nw = (int)(i & 511);
  long bhd = i >> 9;  // bh*16+d
  int bh = (int)(bhd >> 4);
  const long ns = 64L * 16 * 512;
  float num0 = 0.f, num1 = 0.f;
#pragma unroll
  for (int s = 0; s < 8; s++) {
    unsigned int w = spnum[i + (long)s * ns];
    num0 += bf2f((unsigned short)(w & 0xFFFFu));
    num1 += bf2f((unsigned short)(w >> 16));
  }
  const long ds = 64L * 1024;
  long di = (long)bh * 1024 + nw * 2;
  float den0 = 0.f, den1 = 0.f;
#pragma unroll
  for (int s = 0; s < 8; s++) {
    float2 dv = *(const float2*)&spden[di + (long)s * ds];
    den0 += dv.x; den1 += dv.y;
  }
  *(float2*)&to_cn[bhd * 1024 + nw * 2] = make_float2(num0 / den0, num1 / den1);
}

// ---------------------------------------------------------------------------
// Bit-pack signs of fused spatial q/k projections.
// ---------------------------------------------------------------------------
__global__ __launch_bounds__(256) void pack_kernel(
    const float* __restrict__ sqkv,
    unsigned long long* __restrict__ qbits, unsigned long long* __restrict__ kbits) {
  const int wave = threadIdx.x >> 6, lane = threadIdx.x & 63;
  const long p = (long)blockIdx.x * 4 + wave;  // 0..8191
  const int b = (int)(p >> 10), n = (int)(p & 1023);
  const float* base = sqkv + (long)b * 384 * NPIX + n;
  unsigned long long q0 = __ballot(base[(long)lane * NPIX] > 0.f);
  unsigned long long q1 = __ballot(base[(long)(64 + lane) * NPIX] > 0.f);
  unsigned long long k0 = __ballot(base[(long)(128 + lane) * NPIX] > 0.f);
  unsigned long long k1 = __ballot(base[(long)(192 + lane) * NPIX] > 0.f);
  if (lane == 0) {
    qbits[p * 2] = q0; qbits[p * 2 + 1] = q1;
    kbits[p * 2] = k0; kbits[p * 2 + 1] = k1;
  }
}

// ---------------------------------------------------------------------------
// K-split fused binary-attention GEMM (sproj pre-folded: pv = sproj_w @ vv).
// ---------------------------------------------------------------------------
__global__ __launch_bounds__(256) void obgemm_kernel(
    const float* __restrict__ pv, const unsigned long long* __restrict__ qbits,
    const unsigned long long* __restrict__ kbits, float* __restrict__ pnum,
    float* __restrict__ pden) {
  const int b = blockIdx.z;
  const int mt = blockIdx.y & 1, sp = blockIdx.y >> 1;
  const int c0 = mt * 64, n0 = blockIdx.x * 64;
  const int kb0 = sp * 256;
  __shared__ float Ws[16][68];
  __shared__ float Xs[16][68];
  __shared__ float psum[16][68];
  __shared__ unsigned long long qn[64][2];
  const int tid = threadIdx.x;
  if (tid < 64) {
    qn[tid][0] = qbits[((long)b * 1024 + n0 + tid) * 2];
    qn[tid][1] = qbits[((long)b * 1024 + n0 + tid) * 2 + 1];
  }
  __syncthreads();
  const int tx = tid & 15, ty = tid >> 4;
  const float fs = 0.08838834764831845f;
  float acc[4][4] = {};
  float pcs[4] = {};
  for (int k0 = kb0; k0 < kb0 + 256; k0 += 16) {
    {
      int r = tid >> 2, c4 = (tid & 3) * 4;
      const float4 wv = *(const float4*)(pv + ((long)b * 128 + c0 + r) * 1024 + k0 + c4);
      Ws[c4 + 0][r] = wv.x; Ws[c4 + 1][r] = wv.y;
      Ws[c4 + 2][r] = wv.z; Ws[c4 + 3][r] = wv.w;
    }
    {
      int kr = tid >> 4, nc = (tid & 15) * 4;
      unsigned long long kw0 = kbits[((long)b * 1024 + k0 + kr) * 2];
      unsigned long long kw1 = kbits[((long)b * 1024 + k0 + kr) * 2 + 1];
#pragma unroll
      for (int j = 0; j < 4; j++) {
        int ham = __popcll(qn[nc + j][0] ^ kw0) + __popcll(qn[nc + j][1] ^ kw1);
        float w = __expf((float)(128 - 2 * ham) * fs);
        Xs[kr][nc + j] = w;
        pcs[j] += w;
      }
    }
    __syncthreads();
#pragma unroll
    for (int kk = 0; kk < 16; kk++) {
      float a[4], bx[4];
#pragma unroll
      for (int i = 0; i < 4; i++) a[i] = Ws[kk][ty * 4 + i];
#pragma unroll
      for (int j = 0; j < 4; j++) bx[j] = Xs[kk][tx * 4 + j];
#pragma unroll
      for (int i = 0; i < 4; i++)
#pragma unroll
        for (int j = 0; j < 4; j++) acc[i][j] += a[i] * bx[j];
    }
    __syncthreads();
  }
  float* dst = pnum + (((long)sp * 8 + b) * 128 + c0) * 1024 + n0;
#pragma unroll
  for (int i = 0; i < 4; i++) {
    float4 o = make_float4(acc[i][0], acc[i][1], acc[i][2], acc[i][3]);
    *(float4*)(dst + (long)(ty * 4 + i) * 1024 + tx * 4) = o;
  }
  {
    int kr = tid >> 4, nc = (tid & 15) * 4;
#pragma unroll
    for (int j = 0; j < 4; j++) psum[kr][nc + j] = pcs[j];
  }
  __syncthreads();
  if (mt == 0 && tid < 64) {
    float d = 0.f;
#pragma unroll
    for (int r = 0; r < 16; r++) d += psum[r][tid];
    pden[((long)sp * 8 + b) * 1024 + n0 + tid] = d;
  }
}

// ---------------------------------------------------------------------------
// Reduce K-split partials: obp = sum(pnum)/sum(pden) + sproj_b
// ---------------------------------------------------------------------------
__global__ __launch_bounds__(256) void obreduce_kernel(
    const float* __restrict__ pnum, const float* __restrict__ pden,
    const float* __restrict__ sproj_b, float* __restrict__ obp) {
  long i = (long)blockIdx.x * 256 + threadIdx.x;  // 8*128*1024
  int n = (int)(i & 1023);
  long bo = i >> 10;
  int b = (int)(bo >> 7), o = (int)(bo & 127);
  const long ns = 8L * 128 * 1024;
  float num = pnum[i] + pnum[i + ns] + pnum[i + 2 * ns] + pnum[i + 3 * ns];
  const long ds = 8L * 1024;
  long di = (long)b * 1024 + n;
  float den = pden[di] + pden[di + ds] + pden[di + 2 * ds] + pden[di + 3 * ds];
  obp[i] = num / den + sproj_b[o];
}

// ---------------------------------------------------------------------------
// Fused depthwise 3x3 conv + combine.
// ---------------------------------------------------------------------------
__global__ __launch_bounds__(256) void dwcombine_kernel(
    float* __restrict__ yc, const float* __restrict__ dw_w,
    const float* __restrict__ dw_b, const float* __restrict__ obp,
    const float* __restrict__ g, const float* __restrict__ alpha) {
  const int bc = blockIdx.x;
  const int b = bc >> 7, cx = bc & 127;
  const float* img = yc + ((long)b * 384 + 128 + cx) * NPIX;
  float* dst = yc + ((long)b * 384 + 256 + cx) * NPIX;
  float w[9];
#pragma unroll
  for (int i = 0; i < 9; i++) w[i] = dw_w[cx * 9 + i];
  const float bias = dw_b[cx];
  const float a = alpha[b];
  const float gg = g[bc];
  for (int i = threadIdx.x; i < 1024; i += 256) {
    int h = i >> 5, wx = i & 31;
    float s = bias;
#pragma unroll
    for (int ky = 0; ky < 3; ky++) {
      int hh = h + ky - 1;
      if (hh < 0 || hh > 31) continue;
#pragma unroll
      for (int kx = 0; kx < 3; kx++) {
        int ww2 = wx + kx - 1;
        if (ww2 < 0 || ww2 > 31) continue;
        s += img[hh * 32 + ww2] * w[ky * 3 + kx];
      }
    }
    dst[i] = dst[i] + gg * img[i] + (1.f - a) * s + a * obp[(long)bc * NPIX + i];
  }
}

// ---------------------------------------------------------------------------
extern "C" void kernel_launch(void* const* d_in, const int* in_sizes, int n_in,
                              void* d_out, int out_size, void* d_ws, size_t ws_size,
                              hipStream_t stream) {
  const float* x = (const float*)d_in[0];
  const float* cv1_w = (const float*)d_in[1];
  const float* cv1_b = (const float*)d_in[2];
  const float* fm_w1 = (const float*)d_in[3];
  const float* fm_w2 = (const float*)d_in[4];
  const float* ca_w1 = (const float*)d_in[5];
  const float* ca_w2 = (const float*)d_in[6];
  const float* qkv_w = (const float*)d_in[7];
  const float* tproj_w = (const float*)d_in[8];
  const float* tproj_b = (const float*)d_in[9];
  const float* dw_w = (const float*)d_in[10];
  const float* dw_b = (const float*)d_in[11];
  const float* rt_w = (const float*)d_in[12];
  const float* rt_b = (const float*)d_in[13];
  const float* q_w = (const float*)d_in[14];
  const float* k_w = (const float*)d_in[15];
  const float* v_w = (const float*)d_in[16];
  const float* sproj_w = (const float*)d_in[17];
  const float* sproj_b = (const float*)d_in[18];
  const float* cv2_w = (const float*)d_in[19];
  const float* cv2_b = (const float*)d_in[20];
  float* out = (float*)d_out;

  char* wsp = (char*)d_ws;
  size_t off = 0;
  auto alloc = [&](size_t bytes) {
    void* p = wsp + off;
    off += (bytes + 255) & ~(size_t)255;
    return p;
  };
  float* yc = (float*)alloc(8UL * 384 * 1024 * 4);
  float* qkvb = (float*)alloc(8UL * 384 * 1024 * 4);   // pnum head
  float* to_cn = (float*)alloc(8UL * 128 * 1024 * 4);  // pnum tail (exact 16MB)
  float* sqkv = (float*)alloc(8UL * 384 * 1024 * 4);   // spnum head; obp
  float* pv = (float*)alloc(8UL * 128 * 1024 * 4);     // spnum tail (exact)
  short* xT = (short*)alloc(8UL * 1024 * 256 * 2);     // ycT head
  short* y1T = (short*)alloc(8UL * 1024 * 128 * 2);    // ycT tail (exact)
  short* tcT = (short*)alloc(8UL * 1024 * 128 * 2);
  short* vvT = (short*)alloc(8UL * 1024 * 128 * 2);
  short* wb = (short*)alloc(294912UL * 2);
  float* vT = (float*)alloc(64UL * 1024 * 16 * 4);
  float* pden = (float*)alloc(4UL * 8 * 1024 * 4);
  float* spden = (float*)alloc(8UL * 64 * 1024 * 4);
  float* var_k = (float*)alloc(8UL * 8 * 1024 * 4);
  float* var_v = (float*)alloc(8UL * 8 * 1024 * 4);
  float* maxvk = (float*)alloc(64 * 4);
  float* pooled = (float*)alloc(1024 * 4);
  float* m1 = (float*)alloc(1024 * 4);
  float* g = (float*)alloc(1024 * 4);
  float* alpha = (float*)alloc(8 * 4);
  unsigned long long* qbits = (unsigned long long*)alloc(8192UL * 2 * 8);
  unsigned long long* kbits = (unsigned long long*)alloc(8192UL * 2 * 8);
  // aliases (lifetime-disjoint, adjacency guaranteed by alloc order):
  float* pnum = qkvb;                         // 16MB = qkvb+to_cn exactly
  float* obp = sqkv;                          // 4.19MB head of sqkv
  unsigned int* spnum = (unsigned int*)sqkv;  // 16.78MB = sqkv+pv exactly
  short* ycT = xT;                            // 6.29MB = xT+y1T exactly
  // weight arena offsets
  const short* cv1b = wb;
  const short* qkvwb = wb + 65536;
  const short* tprojb = wb + 114688;
  const short* sprojb = wb + 131072;
  const short* cv2b = wb + 147456;
  const short* skvb = wb + 245760;
  if (off > ws_size) return;

  dim3 blk(256);
  // 0. weights -> bf16 arena
  convw_kernel<<<dim3(1152), blk, 0, stream>>>(cv1_w, qkv_w, tproj_w, sproj_w,
                                               cv2_w, q_w, k_w, v_w, wb);
  // 0b. xT = transpose(x) bf16
  tconv_kernel<<<dim3(4, 16, 8), blk, 0, stream>>>(x, 256L * 1024, 256, xT);
  // 1. cv1 (MFMA): yc[:,0:256,:] = cv1_w @ x + cv1_b
  mgemm_kernel<true, false><<<dim3(16, 4, 8), blk, 0, stream>>>(
      cv1b, xT, cv1_b, nullptr, yc, 256, 1024L * 256, 384L * 1024, 0);
  // 2. FFT pooling + channel means
  fftpool_kernel<<<dim3(1024), blk, 0, stream>>>(yc, pooled, m1);
  // 3. gates
  gates_kernel<<<dim3(8), dim3(128), 0, stream>>>(pooled, m1, fm_w1, fm_w2,
                                                  ca_w1, ca_w2, rt_w, rt_b, g, alpha);
  // 3b. y1T = transpose(y1) bf16
  tconv_kernel<<<dim3(2, 16, 8), blk, 0, stream>>>(yc + 128 * 1024, 384L * 1024,
                                                   128, y1T);
  // 4. qkv projection (MFMA)
  mgemm_kernel<false, false><<<dim3(16, 6, 8), blk, 0, stream>>>(
      qkvwb, y1T, nullptr, nullptr, qkvb, 128, 1024L * 128, 384L * 1024, 0);
  // 5. variances + per-bh max + transposed V copy
  varmax_kernel<<<dim3(64), blk, 0, stream>>>(qkvb, var_k, var_v, maxvk, vT);
  // 6. stat attention -> bf16 partials; reduce
  stat_attn_kernel<<<dim3(64, 8), dim3(512), 0, stream>>>(vT, var_k, var_v,
                                                          maxvk, spnum, spden);
  statreduce_kernel<<<dim3(2048), blk, 0, stream>>>(spnum, spden, to_cn);
  // 7. tcT = transpose(to_cn); tproj (MFMA) -> yc[:,256:384,:]
  tconv_kernel<<<dim3(2, 16, 8), blk, 0, stream>>>(to_cn, 128L * 1024, 128, tcT);
  mgemm_kernel<true, false><<<dim3(16, 2, 8), blk, 0, stream>>>(
      tprojb, tcT, tproj_b, nullptr, yc + 256 * 1024, 128, 1024L * 128,
      384L * 1024, 0);
  // 8. fused spatial q/k/v projection (MFMA)
  mgemm_kernel<false, false><<<dim3(16, 6, 8), blk, 0, stream>>>(
      skvb, y1T, nullptr, nullptr, sqkv, 128, 1024L * 128, 384L * 1024, 0);
  // 9. sign pack
  pack_kernel<<<dim3(2048), blk, 0, stream>>>(sqkv, qbits, kbits);
  // 9b. vvT = transpose(vv); pv = sproj_w @ vv (MFMA)
  tconv_kernel<<<dim3(2, 16, 8), blk, 0, stream>>>(sqkv + 256 * 1024,
                                                   384L * 1024, 128, vvT);
  mgemm_kernel<false, false><<<dim3(16, 2, 8), blk, 0, stream>>>(
      sprojb, vvT, nullptr, nullptr, pv, 128, 1024L * 128, 128L * 1024, 0);
  // 10. K-split fused a2-gen GEMM -> partials; reduce
  obgemm_kernel<<<dim3(16, 8, 8), blk, 0, stream>>>(pv, qbits, kbits, pnum, pden);
  obreduce_kernel<<<dim3(4096), blk, 0, stream>>>(pnum, pden, sproj_b, obp);
  // 11. fused depthwise conv + combine into yc attn region
  dwcombine_kernel<<<dim3(1024), blk, 0, stream>>>(yc, dw_w, dw_b, obp, g, alpha);
  // 12. ycT = transpose(yc, 384ch); cv2 (MFMA) + residual
  tconv_kernel<<<dim3(6, 16, 8), blk, 0, stream>>>(yc, 384L * 1024, 384, ycT);
  mgemm_kernel<true, true><<<dim3(16, 4, 8), blk, 0, stream>>>(
      cv2b, ycT, cv2_b, x, out, 384, 1024L * 384, 256L * 1024, 256L * 1024);
}

// Round 14
// 177.996 us; speedup vs baseline: 2.3695x; 1.1767x over previous
//
#include <hip/hip_runtime.h>
#include <math.h>

// Problem constants
#define BATCH 8
#define NPIX 1024   // 32*32

typedef __attribute__((ext_vector_type(8))) short short8v;
typedef __attribute__((ext_vector_type(4))) float f32x4;

__device__ inline unsigned short f2bf(float x) {  // fp32 -> bf16 RNE
  unsigned int u = __float_as_uint(x);
  return (unsigned short)((u + 0x7FFFu + ((u >> 16) & 1u)) >> 16);
}
__device__ inline float bf2f(unsigned short h) {
  return __uint_as_float((unsigned int)h << 16);
}

// ---------------------------------------------------------------------------
// Convert all weights to one bf16 arena (offsets hardcoded):
// [0,65536) cv1_w | [65536,114688) qkv_w | [114688,131072) tproj_w
// [131072,147456) sproj_w | [147456,245760) cv2_w | [245760,294912) q|k|v
// ---------------------------------------------------------------------------
__global__ __launch_bounds__(256) void convw_kernel(
    const float* __restrict__ cv1_w, const float* __restrict__ qkv_w,
    const float* __restrict__ tproj_w, const float* __restrict__ sproj_w,
    const float* __restrict__ cv2_w, const float* __restrict__ q_w,
    const float* __restrict__ k_w, const float* __restrict__ v_w,
    short* __restrict__ wb) {
  int i = blockIdx.x * 256 + threadIdx.x;  // < 294912
  float v;
  if (i < 65536) v = cv1_w[i];
  else if (i < 114688) v = qkv_w[i - 65536];
  else if (i < 131072) v = tproj_w[i - 114688];
  else if (i < 147456) v = sproj_w[i - 131072];
  else if (i < 245760) v = cv2_w[i - 147456];
  else {
    int j = i - 245760, wsel = j >> 14, r = j & 16383;
    v = (wsel == 0) ? q_w[r] : (wsel == 1) ? k_w[r] : v_w[r];
  }
  wb[i] = (short)f2bf(v);
}

// ---------------------------------------------------------------------------
// Transpose + convert: dst[b][n][c] (bf16) = src[b][c][n] (fp32).
// Grid (C/64, 16, 8), 256 threads, LDS 64x65 tile.
// ---------------------------------------------------------------------------
__global__ __launch_bounds__(256) void tconv_kernel(
    const float* __restrict__ src, long sSrc, int C, short* __restrict__ dst) {
  __shared__ float t[64][65];
  const int b = blockIdx.z;
  const int c0 = blockIdx.x * 64, n0 = blockIdx.y * 64;
  const float* s = src + (long)b * sSrc;
  short* d = dst + (long)b * 1024 * C;
  const int tid = threadIdx.x;
#pragma unroll
  for (int p = 0; p < 16; p++) {
    int idx = tid + p * 256;
    int cl = idx >> 6, nl = idx & 63;
    t[cl][nl] = s[(long)(c0 + cl) * 1024 + n0 + nl];
  }
  __syncthreads();
#pragma unroll
  for (int p = 0; p < 16; p++) {
    int idx = tid + p * 256;
    int nl = idx >> 6, cl = idx & 63;
    d[(long)(n0 + nl) * C + c0 + cl] = (short)f2bf(t[cl][nl]);
  }
}

// ---------------------------------------------------------------------------
// MFMA bf16 GEMM: Y[b](MxN=1024) = Wb(MxK bf16) @ X where XT[b] is (N x K)
// bf16 (k-contiguous).  64x64 tile, 4 waves (2x2), each wave 2x2 MFMA tiles
// of 16x16x32.  C/D: col=lane&15, row=(lane>>4)*4+reg (guide-verified).
// BF16OUT: write bf16 (for pv feeding the MFMA binary-attention GEMM).
// ---------------------------------------------------------------------------
template<bool HAS_BIAS, bool HAS_RES, bool BF16OUT>
__global__ __launch_bounds__(256) void mgemm_kernel(
    const short* __restrict__ Wb, const short* __restrict__ XT,
    const float* __restrict__ bias, const float* __restrict__ res,
    void* __restrict__ Yv, int K, long sXT, long sY, long sR) {
  __shared__ __align__(16) short As[64][40];  // 80B rows
  __shared__ __align__(16) short Bs[64][40];
  const int b = blockIdx.z;
  const int n0 = blockIdx.x * 64, m0 = blockIdx.y * 64;
  const int tid = threadIdx.x;
  const int l = tid & 63, w = tid >> 6;
  const int wm = w >> 1, wn = w & 1;
  const short* Xb = XT + (long)b * sXT;
  const int sr = tid >> 2, sko = (tid & 3) * 8;
  const int fr = l & 15, fk = (l >> 4) * 8;
  f32x4 acc[2][2] = {};
  for (int k0 = 0; k0 < K; k0 += 32) {
    *(uint4*)&As[sr][sko] = *(const uint4*)(Wb + (long)(m0 + sr) * K + k0 + sko);
    *(uint4*)&Bs[sr][sko] = *(const uint4*)(Xb + (long)(n0 + sr) * K + k0 + sko);
    __syncthreads();
    short8v a0 = *(short8v*)&As[wm * 32 + fr][fk];
    short8v a1 = *(short8v*)&As[wm * 32 + 16 + fr][fk];
    short8v b0 = *(short8v*)&Bs[wn * 32 + fr][fk];
    short8v b1 = *(short8v*)&Bs[wn * 32 + 16 + fr][fk];
    acc[0][0] = __builtin_amdgcn_mfma_f32_16x16x32_bf16(a0, b0, acc[0][0], 0, 0, 0);
    acc[0][1] = __builtin_amdgcn_mfma_f32_16x16x32_bf16(a0, b1, acc[0][1], 0, 0, 0);
    acc[1][0] = __builtin_amdgcn_mfma_f32_16x16x32_bf16(a1, b0, acc[1][0], 0, 0, 0);
    acc[1][1] = __builtin_amdgcn_mfma_f32_16x16x32_bf16(a1, b1, acc[1][1], 0, 0, 0);
    __syncthreads();
  }
#pragma unroll
  for (int tm = 0; tm < 2; tm++) {
#pragma unroll
    for (int i = 0; i < 4; i++) {
      int m = m0 + wm * 32 + tm * 16 + (l >> 4) * 4 + i;
      float bv = HAS_BIAS ? bias[m] : 0.f;
#pragma unroll
      for (int tn = 0; tn < 2; tn++) {
        int n = n0 + wn * 32 + tn * 16 + (l & 15);
        float v = acc[tm][tn][i] + bv;
        if (HAS_RES) v += res[(long)b * sR + (long)m * 1024 + n];
        if (BF16OUT)
          ((short*)Yv)[(long)b * sY + (long)m * 1024 + n] = (short)f2bf(v);
        else
          ((float*)Yv)[(long)b * sY + (long)m * 1024 + n] = v;
      }
    }
  }
}

// ---------------------------------------------------------------------------
// FFT magnitude pooling + channel means.  One block per (b,c) image.
// ---------------------------------------------------------------------------
__global__ __launch_bounds__(256) void fftpool_kernel(
    const float* __restrict__ yc, float* __restrict__ pooled, float* __restrict__ m1) {
  const int bc = blockIdx.x;
  const int b = bc >> 7, cx = bc & 127;
  const float* img = yc + ((long)b * 384 + 128 + cx) * NPIX;
  __shared__ float im[1024];
  __shared__ float Gr[32][17], Gi[32][17];
  __shared__ float cs[32], sn[32];
  __shared__ float red[256];
  const int t = threadIdx.x;
  if (t < 32) {
    float ang = -0.19634954084936207f * (float)t;  // -2*pi*t/32
    __sincosf(ang, &sn[t], &cs[t]);
  }
  float lsum = 0.f;
  for (int i = t; i < 1024; i += 256) { float v = img[i]; im[i] = v; lsum += v; }
  red[t] = lsum;
  __syncthreads();
  for (int s = 128; s > 0; s >>= 1) {
    if (t < s) red[t] += red[t + s];
    __syncthreads();
  }
  if (t == 0) m1[bc] = red[0] * (1.f / 1024.f);
  for (int i = t; i < 544; i += 256) {
    int h = i / 17, v = i % 17;
    float ar = 0.f, ai = 0.f;
    for (int w2 = 0; w2 < 32; w2++) {
      int k = (v * w2) & 31;
      float x = im[h * 32 + w2];
      ar += x * cs[k]; ai += x * sn[k];
    }
    Gr[h][v] = ar; Gi[h][v] = ai;
  }
  __syncthreads();
  float asum = 0.f;
  for (int i = t; i < 544; i += 256) {
    int u = i / 17, v = i % 17;
    float xr = 0.f, xi = 0.f;
    for (int h = 0; h < 32; h++) {
      int k = (u * h) & 31;
      float gr = Gr[h][v], gi = Gi[h][v];
      xr += gr * cs[k] - gi * sn[k];
      xi += gr * sn[k] + gi * cs[k];
    }
    asum += sqrtf(xr * xr + xi * xi);
  }
  red[t] = asum;
  __syncthreads();
  for (int s = 128; s > 0; s >>= 1) {
    if (t < s) red[t] += red[t + s];
    __syncthreads();
  }
  if (t == 0) pooled[bc] = red[0] * (1.f / (32.f * 544.f));
}

// ---------------------------------------------------------------------------
// Gates: fw/ca MLPs -> g = fw*ca; p_route -> alpha.  One block per batch.
// ---------------------------------------------------------------------------
__global__ __launch_bounds__(128) void gates_kernel(
    const float* __restrict__ pooled, const float* __restrict__ m1,
    const float* __restrict__ fm_w1, const float* __restrict__ fm_w2,
    const float* __restrict__ ca_w1, const float* __restrict__ ca_w2,
    const float* __restrict__ rt_w, const float* __restrict__ rt_b,
    float* __restrict__ g, float* __restrict__ alpha) {
  const int b = blockIdx.x, t = threadIdx.x;
  __shared__ float h1[8], fwv[128], xsm[128], h2[8];
  const float* pb = pooled + b * 128;
  const float* mb = m1 + b * 128;
  if (t < 8) {
    float s = 0.f;
    for (int c = 0; c < 128; c++) s += pb[c] * fm_w1[t * 128 + c];
    h1[t] = fmaxf(s, 0.f);
  }
  __syncthreads();
  {
    float s = 0.f;
    for (int r = 0; r < 8; r++) s += h1[r] * fm_w2[t * 8 + r];
    float fw = 1.f / (1.f + __expf(-s));
    fwv[t] = fw; xsm[t] = fw * mb[t];
  }
  __syncthreads();
  if (t < 8) {
    float s = 0.f;
    for (int c = 0; c < 128; c++) s += xsm[c] * ca_w1[t * 128 + c];
    h2[t] = fmaxf(s, 0.f);
  }
  __syncthreads();
  {
    float s = 0.f;
    for (int r = 0; r < 8; r++) s += h2[r] * ca_w2[t * 8 + r];
    float ca = 1.f / (1.f + __expf(-s));
    g[b * 128 + t] = fwv[t] * ca;
  }
  if (t == 0) {
    float s = 0.f;
    for (int c = 0; c < 128; c++) s += mb[c] * rt_w[c];
    s += rt_b[0];
    alpha[b] = 1.f / (1.f + __expf(-s));
  }
}

// ---------------------------------------------------------------------------
// Variance of k and v head vectors (ddof=1) + per-bh max(var_k) + vT copy.
// ---------------------------------------------------------------------------
__global__ __launch_bounds__(256) void varmax_kernel(
    const float* __restrict__ qkvb, float* __restrict__ var_k,
    float* __restrict__ var_v, float* __restrict__ maxvk,
    float* __restrict__ vT) {
  const int bh = blockIdx.x;
  const int b = bh >> 3, h = bh & 7;
  __shared__ float red[256];
  const float* kb = qkvb + ((long)b * 384 + 128 + h * 16) * NPIX;
  const float* vb = qkvb + ((long)b * 384 + 256 + h * 16) * NPIX;
  float mx = 0.f;
  for (int j = 0; j < 4; j++) {
    int n = threadIdx.x + j * 256;
    float xk[16], xv[16], sk = 0.f, sv = 0.f;
#pragma unroll
    for (int d = 0; d < 16; d++) {
      xk[d] = kb[(long)d * NPIX + n]; sk += xk[d];
      xv[d] = vb[(long)d * NPIX + n]; sv += xv[d];
    }
    float mk = sk * (1.f / 16.f), mv = sv * (1.f / 16.f);
    float vk_ = 0.f, vv_ = 0.f;
#pragma unroll
    for (int d = 0; d < 16; d++) {
      float a = xk[d] - mk; vk_ += a * a;
      float c = xv[d] - mv; vv_ += c * c;
    }
    vk_ *= (1.f / 15.f); vv_ *= (1.f / 15.f);
    var_k[(long)bh * NPIX + n] = vk_;
    var_v[(long)bh * NPIX + n] = vv_;
    mx = fmaxf(mx, vk_);
    float* vtr = vT + ((long)bh * NPIX + n) * 16;
    *(float4*)(vtr + 0)  = make_float4(xv[0], xv[1], xv[2], xv[3]);
    *(float4*)(vtr + 4)  = make_float4(xv[4], xv[5], xv[6], xv[7]);
    *(float4*)(vtr + 8)  = make_float4(xv[8], xv[9], xv[10], xv[11]);
    *(float4*)(vtr + 12) = make_float4(xv[12], xv[13], xv[14], xv[15]);
  }
  red[threadIdx.x] = mx;
  __syncthreads();
  for (int s = 128; s > 0; s >>= 1) {
    if (threadIdx.x < s) red[threadIdx.x] = fmaxf(red[threadIdx.x], red[threadIdx.x + s]);
    __syncthreads();
  }
  if (threadIdx.x == 0) maxvk[bh] = red[0];
}

// ---------------------------------------------------------------------------
// Stat attention (m-split x8 -> 512 blocks).  Thread owns 2n x 16d.
// V read via vT with block-uniform addresses.  Partials packed bf16.
// ---------------------------------------------------------------------------
__global__ __launch_bounds__(512) void stat_attn_kernel(
    const float* __restrict__ vT, const float* __restrict__ var_k,
    const float* __restrict__ var_v, const float* __restrict__ maxvk,
    unsigned int* __restrict__ spnum, float* __restrict__ spden) {
  const int bh = blockIdx.x;
  const int mc = blockIdx.y;   // 0..7
  const int m0 = mc * 128;
  const int tid = threadIdx.x;
  const int n = tid * 2;
  const float2 cvv = *(const float2*)&var_v[(long)bh * NPIX + n];
  const float c0 = cvv.x * 0.25f, c1 = cvv.y * 0.25f;
  const float mv = maxvk[bh];
  const float* __restrict__ vrow = vT + ((long)bh * NPIX + m0) * 16;
  const float* __restrict__ vkp = var_k + (long)bh * NPIX + m0;
  float acc0[16], acc1[16];
#pragma unroll
  for (int d = 0; d < 16; d++) { acc0[d] = 0.f; acc1[d] = 0.f; }
  float den0 = 0.f, den1 = 0.f;
#pragma unroll 2
  for (int mm = 0; mm < 128; mm++) {
    float t = vkp[mm] - mv;  // uniform
    float e0 = __expf(c0 * t), e1 = __expf(c1 * t);
    den0 += e0; den1 += e1;
    const float* vr = vrow + mm * 16;  // uniform address -> scalar loads
    const float4 vA = *(const float4*)(vr + 0);
    const float4 vB = *(const float4*)(vr + 4);
    const float4 vC = *(const float4*)(vr + 8);
    const float4 vD = *(const float4*)(vr + 12);
    acc0[0] += e0 * vA.x; acc0[1] += e0 * vA.y; acc0[2] += e0 * vA.z; acc0[3] += e0 * vA.w;
    acc0[4] += e0 * vB.x; acc0[5] += e0 * vB.y; acc0[6] += e0 * vB.z; acc0[7] += e0 * vB.w;
    acc0[8] += e0 * vC.x; acc0[9] += e0 * vC.y; acc0[10] += e0 * vC.z; acc0[11] += e0 * vC.w;
    acc0[12] += e0 * vD.x; acc0[13] += e0 * vD.y; acc0[14] += e0 * vD.z; acc0[15] += e0 * vD.w;
    acc1[0] += e1 * vA.x; acc1[1] += e1 * vA.y; acc1[2] += e1 * vA.z; acc1[3] += e1 * vA.w;
    acc1[4] += e1 * vB.x; acc1[5] += e1 * vB.y; acc1[6] += e1 * vB.z; acc1[7] += e1 * vB.w;
    acc1[8] += e1 * vC.x; acc1[9] += e1 * vC.y; acc1[10] += e1 * vC.z; acc1[11] += e1 * vC.w;
    acc1[12] += e1 * vD.x; acc1[13] += e1 * vD.y; acc1[14] += e1 * vD.z; acc1[15] += e1 * vD.w;
  }
  unsigned int* np = spnum + ((long)(mc * 64 + bh) * 16) * 512 + tid;
#pragma unroll
  for (int d = 0; d < 16; d++)
    np[(long)d * 512] = (unsigned int)f2bf(acc0[d]) | ((unsigned int)f2bf(acc1[d]) << 16);
  *(float2*)&spden[((long)mc * 64 + bh) * 1024 + n] = make_float2(den0, den1);
}

// ---------------------------------------------------------------------------
// Reduce stat partials -> to_cn[(bh*16+d)*1024 + n] = sum(num)/sum(den)
// ---------------------------------------------------------------------------
__global__ __launch_bounds__(256) void statreduce_kernel(
    const unsigned int* __restrict__ spnum, const float* __restrict__ spden,
    float* __restrict__ to_cn) {
  long i = (long)blockIdx.x * 256 + threadIdx.x;  // 64*16*512 words
  int nw = (int)(i & 511);
  long bhd = i >> 9;  // bh*16+d
  int bh = (int)(bhd >> 4);
  const long ns = 64L * 16 * 512;
  float num0 = 0.f, num1 = 0.f;
#pragma unroll
  for (int s = 0; s < 8; s++) {
    unsigned int w = spnum[i + (long)s * ns];
    num0 += bf2f((unsigned short)(w & 0xFFFFu));
    num1 += bf2f((unsigned short)(w >> 16));
  }
  const long ds = 64L * 1024;
  long di = (long)bh * 1024 + nw * 2;
  float den0 = 0.f, den1 = 0.f;
#pragma unroll
  for (int s = 0; s < 8; s++) {
    float2 dv = *(const float2*)&spden[di + (long)s * ds];
    den0 += dv.x; den1 += dv.y;
  }
  *(float2*)&to_cn[bhd * 1024 + nw * 2] = make_float2(num0 / den0, num1 / den1);
}

// ---------------------------------------------------------------------------
// Bit-pack signs of fused spatial q/k projections.
// ---------------------------------------------------------------------------
__global__ __launch_bounds__(256) void pack_kernel(
    const float* __restrict__ sqkv,
    unsigned long long* __restrict__ qbits, unsigned long long* __restrict__ kbits) {
  const int wave = threadIdx.x >> 6, lane = threadIdx.x & 63;
  const long p = (long)blockIdx.x * 4 + wave;  // 0..8191
  const int b = (int)(p >> 10), n = (int)(p & 1023);
  const float* base = sqkv + (long)b * 384 * NPIX + n;
  unsigned long long q0 = __ballot(base[(long)lane * NPIX] > 0.f);
  unsigned long long q1 = __ballot(base[(long)(64 + lane) * NPIX] > 0.f);
  unsigned long long k0 = __ballot(base[(long)(128 + lane) * NPIX] > 0.f);
  unsigned long long k1 = __ballot(base[(long)(192 + lane) * NPIX] > 0.f);
  if (lane == 0) {
    qbits[p * 2] = q0; qbits[p * 2 + 1] = q1;
    kbits[p * 2] = k0; kbits[p * 2 + 1] = k1;
  }
}

// ---------------------------------------------------------------------------
// MFMA binary-attention GEMM with in-register w synthesis.
// pnum[sp][b][c][n] = sum_m pv[c,m]*w[m,n] over m in [sp*256, +256);
// pden[sp][b][n] = sum_m w[m,n].  w = exp((128-2*popc(q^k))/sqrt(128)) bf16.
// Grid (16 n-tiles, 4 sp, 8 b) = 512 blocks, 256 thr (4 waves).
// Wave w owns n in [n0+w*16, +16), all 128 c.  B-frag synthesized per lane:
// col=l&15 (n), k=(l>>4)*8+j (m).  A staged in LDS from pvb (bf16).
// ---------------------------------------------------------------------------
__global__ __launch_bounds__(256) void obgemm_kernel(
    const short* __restrict__ pvb, const unsigned long long* __restrict__ qbits,
    const unsigned long long* __restrict__ kbits, float* __restrict__ pnum,
    float* __restrict__ pden) {
  const int b = blockIdx.z;
  const int sp = blockIdx.y;
  const int n0 = blockIdx.x * 64;
  const int kb0 = sp * 256;
  __shared__ __align__(16) short As[128][40];
  __shared__ __align__(16) unsigned long long kbsh[256][2];
  const int tid = threadIdx.x;
  const int l = tid & 63, w = tid >> 6;
  const int ln = l & 15, lk = l >> 4;
  const int n = n0 + w * 16 + ln;
  const unsigned long long q0 = qbits[((long)b * 1024 + n) * 2];
  const unsigned long long q1 = qbits[((long)b * 1024 + n) * 2 + 1];
  // stage k bits for the whole 256-m range
  *(uint4*)&kbsh[tid][0] = *(const uint4*)(kbits + ((long)b * 1024 + kb0 + tid) * 2);
  const float fs = 0.08838834764831845f;
  const int sc = tid >> 1, sh = (tid & 1) * 16;  // A staging: row, short-offset
  const short* pvrow = pvb + ((long)b * 128 + sc) * 1024 + kb0;
  f32x4 acc[8] = {};
  float psum = 0.f;
  for (int ks = 0; ks < 8; ks++) {  // 32 m per step
    *(uint4*)&As[sc][sh] = *(const uint4*)(pvrow + ks * 32 + sh);
    *(uint4*)&As[sc][sh + 8] = *(const uint4*)(pvrow + ks * 32 + sh + 8);
    __syncthreads();
    // synthesize B-frag: 8 w values for (n, m = kb0+ks*32+lk*8+j)
    const int mloc = ks * 32 + lk * 8;
    short8v bfrag;
#pragma unroll
    for (int j = 0; j < 8; j++) {
      unsigned long long kw0 = kbsh[mloc + j][0];
      unsigned long long kw1 = kbsh[mloc + j][1];
      int ham = __popcll(kw0 ^ q0) + __popcll(kw1 ^ q1);
      float wv = __expf((float)(128 - 2 * ham) * fs);
      psum += wv;
      bfrag[j] = (short)f2bf(wv);
    }
#pragma unroll
    for (int ct = 0; ct < 8; ct++) {
      short8v afrag = *(short8v*)&As[ct * 16 + ln][lk * 8];
      acc[ct] = __builtin_amdgcn_mfma_f32_16x16x32_bf16(afrag, bfrag, acc[ct], 0, 0, 0);
    }
    __syncthreads();
  }
  // write partial numerators: c = ct*16 + lk*4 + i, col n
  float* dst = pnum + (((long)sp * 8 + b) * 128) * 1024 + n;
#pragma unroll
  for (int ct = 0; ct < 8; ct++)
#pragma unroll
    for (int i = 0; i < 4; i++)
      dst[(long)(ct * 16 + lk * 4 + i) * 1024] = acc[ct][i];
  // partial denominators: reduce psum over the 4 k-slice lane groups
  psum += __shfl_xor(psum, 16);
  psum += __shfl_xor(psum, 32);
  if (lk == 0)
    pden[((long)sp * 8 + b) * 1024 + n] = psum;
}

// ---------------------------------------------------------------------------
// Fused depthwise 3x3 conv + K-split ob reduce + combine:
// obv = sum_sp(pnum)/sum_sp(pden) + sproj_b;
// yc[b,256+c,n] += g*y1 + (1-a)*dwconv(y1) + a*obv.  One block per (b,c).
// ---------------------------------------------------------------------------
__global__ __launch_bounds__(256) void dwcombine_kernel(
    float* __restrict__ yc, const float* __restrict__ dw_w,
    const float* __restrict__ dw_b, const float* __restrict__ pnum,
    const float* __restrict__ pden, const float* __restrict__ sproj_b,
    const float* __restrict__ g, const float* __restrict__ alpha) {
  const int bc = blockIdx.x;
  const int b = bc >> 7, cx = bc & 127;
  const float* img = yc + ((long)b * 384 + 128 + cx) * NPIX;
  float* dst = yc + ((long)b * 384 + 256 + cx) * NPIX;
  float w[9];
#pragma unroll
  for (int i = 0; i < 9; i++) w[i] = dw_w[cx * 9 + i];
  const float bias = dw_b[cx];
  const float a = alpha[b];
  const float gg = g[bc];
  const float sb = sproj_b[cx];
  const long ns = 8L * 128 * 1024;
  const long ds = 8L * 1024;
  const long nbase = ((long)b * 128 + cx) * 1024;
  const long dbase = (long)b * 1024;
  for (int i = threadIdx.x; i < 1024; i += 256) {
    int h = i >> 5, wx = i & 31;
    float s = bias;
#pragma unroll
    for (int ky = 0; ky < 3; ky++) {
      int hh = h + ky - 1;
      if (hh < 0 || hh > 31) continue;
#pragma unroll
      for (int kx = 0; kx < 3; kx++) {
        int ww2 = wx + kx - 1;
        if (ww2 < 0 || ww2 > 31) continue;
        s += img[hh * 32 + ww2] * w[ky * 3 + kx];
      }
    }
    float num = pnum[nbase + i] + pnum[nbase + i + ns] +
                pnum[nbase + i + 2 * ns] + pnum[nbase + i + 3 * ns];
    float den = pden[dbase + i] + pden[dbase + i + ds] +
                pden[dbase + i + 2 * ds] + pden[dbase + i + 3 * ds];
    float obv = num / den + sb;
    dst[i] = dst[i] + gg * img[i] + (1.f - a) * s + a * obv;
  }
}

// ---------------------------------------------------------------------------
extern "C" void kernel_launch(void* const* d_in, const int* in_sizes, int n_in,
                              void* d_out, int out_size, void* d_ws, size_t ws_size,
                              hipStream_t stream) {
  const float* x = (const float*)d_in[0];
  const float* cv1_w = (const float*)d_in[1];
  const float* cv1_b = (const float*)d_in[2];
  const float* fm_w1 = (const float*)d_in[3];
  const float* fm_w2 = (const float*)d_in[4];
  const float* ca_w1 = (const float*)d_in[5];
  const float* ca_w2 = (const float*)d_in[6];
  const float* qkv_w = (const float*)d_in[7];
  const float* tproj_w = (const float*)d_in[8];
  const float* tproj_b = (const float*)d_in[9];
  const float* dw_w = (const float*)d_in[10];
  const float* dw_b = (const float*)d_in[11];
  const float* rt_w = (const float*)d_in[12];
  const float* rt_b = (const float*)d_in[13];
  const float* q_w = (const float*)d_in[14];
  const float* k_w = (const float*)d_in[15];
  const float* v_w = (const float*)d_in[16];
  const float* sproj_w = (const float*)d_in[17];
  const float* sproj_b = (const float*)d_in[18];
  const float* cv2_w = (const float*)d_in[19];
  const float* cv2_b = (const float*)d_in[20];
  float* out = (float*)d_out;

  char* wsp = (char*)d_ws;
  size_t off = 0;
  auto alloc = [&](size_t bytes) {
    void* p = wsp + off;
    off += (bytes + 255) & ~(size_t)255;
    return p;
  };
  float* yc = (float*)alloc(8UL * 384 * 1024 * 4);
  float* qkvb = (float*)alloc(8UL * 384 * 1024 * 4);   // pnum head
  float* to_cn = (float*)alloc(8UL * 128 * 1024 * 4);  // pnum tail (exact 16MB)
  float* sqkv = (float*)alloc(8UL * 384 * 1024 * 4);   // spnum head
  float* pv = (float*)alloc(8UL * 128 * 1024 * 4);     // spnum tail; pvb (bf16)
  short* xT = (short*)alloc(8UL * 1024 * 256 * 2);     // ycT head
  short* y1T = (short*)alloc(8UL * 1024 * 128 * 2);    // ycT tail (exact)
  short* tcT = (short*)alloc(8UL * 1024 * 128 * 2);
  short* vvT = (short*)alloc(8UL * 1024 * 128 * 2);
  short* wb = (short*)alloc(294912UL * 2);
  float* vT = (float*)alloc(64UL * 1024 * 16 * 4);
  float* pden = (float*)alloc(4UL * 8 * 1024 * 4);
  float* spden = (float*)alloc(8UL * 64 * 1024 * 4);
  float* var_k = (float*)alloc(8UL * 8 * 1024 * 4);
  float* var_v = (float*)alloc(8UL * 8 * 1024 * 4);
  float* maxvk = (float*)alloc(64 * 4);
  float* pooled = (float*)alloc(1024 * 4);
  float* m1 = (float*)alloc(1024 * 4);
  float* g = (float*)alloc(1024 * 4);
  float* alpha = (float*)alloc(8 * 4);
  unsigned long long* qbits = (unsigned long long*)alloc(8192UL * 2 * 8);
  unsigned long long* kbits = (unsigned long long*)alloc(8192UL * 2 * 8);
  // aliases (lifetime-disjoint, adjacency guaranteed by alloc order):
  float* pnum = qkvb;                         // 16MB = qkvb+to_cn exactly
  unsigned int* spnum = (unsigned int*)sqkv;  // 16.78MB = sqkv+pv exactly
  short* pvb = (short*)pv;                    // bf16 pv lives in pv buffer
  short* ycT = xT;                            // 6.29MB = xT+y1T exactly
  // weight arena offsets
  const short* cv1b = wb;
  const short* qkvwb = wb + 65536;
  const short* tprojb = wb + 114688;
  const short* sprojb = wb + 131072;
  const short* cv2b = wb + 147456;
  const short* skvb = wb + 245760;
  if (off > ws_size) return;

  dim3 blk(256);
  // 0. weights -> bf16 arena
  convw_kernel<<<dim3(1152), blk, 0, stream>>>(cv1_w, qkv_w, tproj_w, sproj_w,
                                               cv2_w, q_w, k_w, v_w, wb);
  // 0b. xT = transpose(x) bf16
  tconv_kernel<<<dim3(4, 16, 8), blk, 0, stream>>>(x, 256L * 1024, 256, xT);
  // 1. cv1 (MFMA): yc[:,0:256,:] = cv1_w @ x + cv1_b
  mgemm_kernel<true, false, false><<<dim3(16, 4, 8), blk, 0, stream>>>(
      cv1b, xT, cv1_b, nullptr, yc, 256, 1024L * 256, 384L * 1024, 0);
  // 2. FFT pooling + channel means
  fftpool_kernel<<<dim3(1024), blk, 0, stream>>>(yc, pooled, m1);
  // 3. gates
  gates_kernel<<<dim3(8), dim3(128), 0, stream>>>(pooled, m1, fm_w1, fm_w2,
                                                  ca_w1, ca_w2, rt_w, rt_b, g, alpha);
  // 3b. y1T = transpose(y1) bf16
  tconv_kernel<<<dim3(2, 16, 8), blk, 0, stream>>>(yc + 128 * 1024, 384L * 1024,
                                                   128, y1T);
  // 4. qkv projection (MFMA)
  mgemm_kernel<false, false, false><<<dim3(16, 6, 8), blk, 0, stream>>>(
      qkvwb, y1T, nullptr, nullptr, qkvb, 128, 1024L * 128, 384L * 1024, 0);
  // 5. variances + per-bh max + transposed V copy
  varmax_kernel<<<dim3(64), blk, 0, stream>>>(qkvb, var_k, var_v, maxvk, vT);
  // 6. stat attention -> bf16 partials; reduce
  stat_attn_kernel<<<dim3(64, 8), dim3(512), 0, stream>>>(vT, var_k, var_v,
                                                          maxvk, spnum, spden);
  statreduce_kernel<<<dim3(2048), blk, 0, stream>>>(spnum, spden, to_cn);
  // 7. tcT = transpose(to_cn); tproj (MFMA) -> yc[:,256:384,:]
  tconv_kernel<<<dim3(2, 16, 8), blk, 0, stream>>>(to_cn, 128L * 1024, 128, tcT);
  mgemm_kernel<true, false, false><<<dim3(16, 2, 8), blk, 0, stream>>>(
      tprojb, tcT, tproj_b, nullptr, yc + 256 * 1024, 128, 1024L * 128,
      384L * 1024, 0);
  // 8. fused spatial q/k/v projection (MFMA)
  mgemm_kernel<false, false, false><<<dim3(16, 6, 8), blk, 0, stream>>>(
      skvb, y1T, nullptr, nullptr, sqkv, 128, 1024L * 128, 384L * 1024, 0);
  // 9. sign pack
  pack_kernel<<<dim3(2048), blk, 0, stream>>>(sqkv, qbits, kbits);
  // 9b. vvT = transpose(vv); pv = sproj_w @ vv (MFMA, bf16 out)
  tconv_kernel<<<dim3(2, 16, 8), blk, 0, stream>>>(sqkv + 256 * 1024,
                                                   384L * 1024, 128, vvT);
  mgemm_kernel<false, false, true><<<dim3(16, 2, 8), blk, 0, stream>>>(
      sprojb, vvT, nullptr, nullptr, pvb, 128, 1024L * 128, 128L * 1024, 0);
  // 10. MFMA binary-attention GEMM (in-register w synth) -> partials
  obgemm_kernel<<<dim3(16, 4, 8), blk, 0, stream>>>(pvb, qbits, kbits, pnum, pden);
  // 11. fused depthwise conv + ob-reduce + combine into yc attn region
  dwcombine_kernel<<<dim3(1024), blk, 0, stream>>>(yc, dw_w, dw_b, pnum, pden,
                                                   sproj_b, g, alpha);
  // 12. ycT = transpose(yc, 384ch); cv2 (MFMA) + residual
  tconv_kernel<<<dim3(6, 16, 8), blk, 0, stream>>>(yc, 384L * 1024, 384, ycT);
  mgemm_kernel<true, true, false><<<dim3(16, 4, 8), blk, 0, stream>>>(
      cv2b, ycT, cv2_b, x, out, 384, 1024L * 384, 256L * 1024, 256L * 1024);
}

// Round 15
// 149.090 us; speedup vs baseline: 2.8289x; 1.1939x over previous
//
#include <hip/hip_runtime.h>
#include <math.h>

// Problem constants
#define BATCH 8
#define NPIX 1024   // 32*32

typedef __attribute__((ext_vector_type(8))) short short8v;
typedef __attribute__((ext_vector_type(4))) float f32x4;

__device__ inline unsigned short f2bf(float x) {  // fp32 -> bf16 RNE
  unsigned int u = __float_as_uint(x);
  return (unsigned short)((u + 0x7FFFu + ((u >> 16) & 1u)) >> 16);
}
__device__ inline float bf2f(unsigned short h) {
  return __uint_as_float((unsigned int)h << 16);
}

// ---------------------------------------------------------------------------
// Convert all weights to one bf16 arena (offsets hardcoded):
// [0,65536) cv1_w | [65536,114688) qkv_w | [114688,131072) tproj_w
// [131072,147456) sproj_w | [147456,245760) cv2_w | [245760,294912) q|k|v
// ---------------------------------------------------------------------------
__global__ __launch_bounds__(256) void convw_kernel(
    const float* __restrict__ cv1_w, const float* __restrict__ qkv_w,
    const float* __restrict__ tproj_w, const float* __restrict__ sproj_w,
    const float* __restrict__ cv2_w, const float* __restrict__ q_w,
    const float* __restrict__ k_w, const float* __restrict__ v_w,
    short* __restrict__ wb) {
  int i = blockIdx.x * 256 + threadIdx.x;  // < 294912
  float v;
  if (i < 65536) v = cv1_w[i];
  else if (i < 114688) v = qkv_w[i - 65536];
  else if (i < 131072) v = tproj_w[i - 114688];
  else if (i < 147456) v = sproj_w[i - 131072];
  else if (i < 245760) v = cv2_w[i - 147456];
  else {
    int j = i - 245760, wsel = j >> 14, r = j & 16383;
    v = (wsel == 0) ? q_w[r] : (wsel == 1) ? k_w[r] : v_w[r];
  }
  wb[i] = (short)f2bf(v);
}

// ---------------------------------------------------------------------------
// Transpose + convert: dst[b][n][c] (bf16) = src[b][c][n] (fp32).
// Grid (C/64, 16, 8), 256 threads, LDS 64x65 tile.
// ---------------------------------------------------------------------------
__global__ __launch_bounds__(256) void tconv_kernel(
    const float* __restrict__ src, long sSrc, int C, short* __restrict__ dst) {
  __shared__ float t[64][65];
  const int b = blockIdx.z;
  const int c0 = blockIdx.x * 64, n0 = blockIdx.y * 64;
  const float* s = src + (long)b * sSrc;
  short* d = dst + (long)b * 1024 * C;
  const int tid = threadIdx.x;
#pragma unroll
  for (int p = 0; p < 16; p++) {
    int idx = tid + p * 256;
    int cl = idx >> 6, nl = idx & 63;
    t[cl][nl] = s[(long)(c0 + cl) * 1024 + n0 + nl];
  }
  __syncthreads();
#pragma unroll
  for (int p = 0; p < 16; p++) {
    int idx = tid + p * 256;
    int nl = idx >> 6, cl = idx & 63;
    d[(long)(n0 + nl) * C + c0 + cl] = (short)f2bf(t[cl][nl]);
  }
}

// ---------------------------------------------------------------------------
// MFMA bf16 GEMM: Y[b](MxN=1024) = Wb(MxK bf16) @ X where XT[b] is (N x K)
// bf16 (k-contiguous).  64x64 tile, 4 waves (2x2), each wave 2x2 MFMA tiles
// of 16x16x32.  C/D: col=lane&15, row=(lane>>4)*4+reg (guide-verified).
// BF16OUT: write bf16 (for pv feeding the MFMA binary-attention GEMM).
// ---------------------------------------------------------------------------
template<bool HAS_BIAS, bool HAS_RES, bool BF16OUT>
__global__ __launch_bounds__(256) void mgemm_kernel(
    const short* __restrict__ Wb, const short* __restrict__ XT,
    const float* __restrict__ bias, const float* __restrict__ res,
    void* __restrict__ Yv, int K, long sXT, long sY, long sR) {
  __shared__ __align__(16) short As[64][40];  // 80B rows
  __shared__ __align__(16) short Bs[64][40];
  const int b = blockIdx.z;
  const int n0 = blockIdx.x * 64, m0 = blockIdx.y * 64;
  const int tid = threadIdx.x;
  const int l = tid & 63, w = tid >> 6;
  const int wm = w >> 1, wn = w & 1;
  const short* Xb = XT + (long)b * sXT;
  const int sr = tid >> 2, sko = (tid & 3) * 8;
  const int fr = l & 15, fk = (l >> 4) * 8;
  f32x4 acc[2][2] = {};
  for (int k0 = 0; k0 < K; k0 += 32) {
    *(uint4*)&As[sr][sko] = *(const uint4*)(Wb + (long)(m0 + sr) * K + k0 + sko);
    *(uint4*)&Bs[sr][sko] = *(const uint4*)(Xb + (long)(n0 + sr) * K + k0 + sko);
    __syncthreads();
    short8v a0 = *(short8v*)&As[wm * 32 + fr][fk];
    short8v a1 = *(short8v*)&As[wm * 32 + 16 + fr][fk];
    short8v b0 = *(short8v*)&Bs[wn * 32 + fr][fk];
    short8v b1 = *(short8v*)&Bs[wn * 32 + 16 + fr][fk];
    acc[0][0] = __builtin_amdgcn_mfma_f32_16x16x32_bf16(a0, b0, acc[0][0], 0, 0, 0);
    acc[0][1] = __builtin_amdgcn_mfma_f32_16x16x32_bf16(a0, b1, acc[0][1], 0, 0, 0);
    acc[1][0] = __builtin_amdgcn_mfma_f32_16x16x32_bf16(a1, b0, acc[1][0], 0, 0, 0);
    acc[1][1] = __builtin_amdgcn_mfma_f32_16x16x32_bf16(a1, b1, acc[1][1], 0, 0, 0);
    __syncthreads();
  }
#pragma unroll
  for (int tm = 0; tm < 2; tm++) {
#pragma unroll
    for (int i = 0; i < 4; i++) {
      int m = m0 + wm * 32 + tm * 16 + (l >> 4) * 4 + i;
      float bv = HAS_BIAS ? bias[m] : 0.f;
#pragma unroll
      for (int tn = 0; tn < 2; tn++) {
        int n = n0 + wn * 32 + tn * 16 + (l & 15);
        float v = acc[tm][tn][i] + bv;
        if (HAS_RES) v += res[(long)b * sR + (long)m * 1024 + n];
        if (BF16OUT)
          ((short*)Yv)[(long)b * sY + (long)m * 1024 + n] = (short)f2bf(v);
        else
          ((float*)Yv)[(long)b * sY + (long)m * 1024 + n] = v;
      }
    }
  }
}

// ---------------------------------------------------------------------------
// FFT magnitude pooling + channel means.  One block per (b,c) image.
// ---------------------------------------------------------------------------
__global__ __launch_bounds__(256) void fftpool_kernel(
    const float* __restrict__ yc, float* __restrict__ pooled, float* __restrict__ m1) {
  const int bc = blockIdx.x;
  const int b = bc >> 7, cx = bc & 127;
  const float* img = yc + ((long)b * 384 + 128 + cx) * NPIX;
  __shared__ float im[1024];
  __shared__ float Gr[32][17], Gi[32][17];
  __shared__ float cs[32], sn[32];
  __shared__ float red[256];
  const int t = threadIdx.x;
  if (t < 32) {
    float ang = -0.19634954084936207f * (float)t;  // -2*pi*t/32
    __sincosf(ang, &sn[t], &cs[t]);
  }
  float lsum = 0.f;
  for (int i = t; i < 1024; i += 256) { float v = img[i]; im[i] = v; lsum += v; }
  red[t] = lsum;
  __syncthreads();
  for (int s = 128; s > 0; s >>= 1) {
    if (t < s) red[t] += red[t + s];
    __syncthreads();
  }
  if (t == 0) m1[bc] = red[0] * (1.f / 1024.f);
  for (int i = t; i < 544; i += 256) {
    int h = i / 17, v = i % 17;
    float ar = 0.f, ai = 0.f;
    for (int w2 = 0; w2 < 32; w2++) {
      int k = (v * w2) & 31;
      float x = im[h * 32 + w2];
      ar += x * cs[k]; ai += x * sn[k];
    }
    Gr[h][v] = ar; Gi[h][v] = ai;
  }
  __syncthreads();
  float asum = 0.f;
  for (int i = t; i < 544; i += 256) {
    int u = i / 17, v = i % 17;
    float xr = 0.f, xi = 0.f;
    for (int h = 0; h < 32; h++) {
      int k = (u * h) & 31;
      float gr = Gr[h][v], gi = Gi[h][v];
      xr += gr * cs[k] - gi * sn[k];
      xi += gr * sn[k] + gi * cs[k];
    }
    asum += sqrtf(xr * xr + xi * xi);
  }
  red[t] = asum;
  __syncthreads();
  for (int s = 128; s > 0; s >>= 1) {
    if (t < s) red[t] += red[t + s];
    __syncthreads();
  }
  if (t == 0) pooled[bc] = red[0] * (1.f / (32.f * 544.f));
}

// ---------------------------------------------------------------------------
// Gates: fw/ca MLPs -> g = fw*ca; p_route -> alpha.  One block per batch.
// ---------------------------------------------------------------------------
__global__ __launch_bounds__(128) void gates_kernel(
    const float* __restrict__ pooled, const float* __restrict__ m1,
    const float* __restrict__ fm_w1, const float* __restrict__ fm_w2,
    const float* __restrict__ ca_w1, const float* __restrict__ ca_w2,
    const float* __restrict__ rt_w, const float* __restrict__ rt_b,
    float* __restrict__ g, float* __restrict__ alpha) {
  const int b = blockIdx.x, t = threadIdx.x;
  __shared__ float h1[8], fwv[128], xsm[128], h2[8];
  const float* pb = pooled + b * 128;
  const float* mb = m1 + b * 128;
  if (t < 8) {
    float s = 0.f;
    for (int c = 0; c < 128; c++) s += pb[c] * fm_w1[t * 128 + c];
    h1[t] = fmaxf(s, 0.f);
  }
  __syncthreads();
  {
    float s = 0.f;
    for (int r = 0; r < 8; r++) s += h1[r] * fm_w2[t * 8 + r];
    float fw = 1.f / (1.f + __expf(-s));
    fwv[t] = fw; xsm[t] = fw * mb[t];
  }
  __syncthreads();
  if (t < 8) {
    float s = 0.f;
    for (int c = 0; c < 128; c++) s += xsm[c] * ca_w1[t * 128 + c];
    h2[t] = fmaxf(s, 0.f);
  }
  __syncthreads();
  {
    float s = 0.f;
    for (int r = 0; r < 8; r++) s += h2[r] * ca_w2[t * 8 + r];
    float ca = 1.f / (1.f + __expf(-s));
    g[b * 128 + t] = fwv[t] * ca;
  }
  if (t == 0) {
    float s = 0.f;
    for (int c = 0; c < 128; c++) s += mb[c] * rt_w[c];
    s += rt_b[0];
    alpha[b] = 1.f / (1.f + __expf(-s));
  }
}

// ---------------------------------------------------------------------------
// Variance of k and v head vectors (ddof=1) + per-bh max(var_k).
// Emits vTb[bh][d][m] (bf16, m-contiguous) via in-LDS transpose for the
// MFMA stat-attention A-fragments.
// ---------------------------------------------------------------------------
__global__ __launch_bounds__(256) void varmax_kernel(
    const float* __restrict__ qkvb, float* __restrict__ var_k,
    float* __restrict__ var_v, float* __restrict__ maxvk,
    short* __restrict__ vTb) {
  const int bh = blockIdx.x;
  const int b = bh >> 3, h = bh & 7;
  __shared__ float red[256];
  __shared__ float trans[16][256];
  const float* kb = qkvb + ((long)b * 384 + 128 + h * 16) * NPIX;
  const float* vb = qkvb + ((long)b * 384 + 256 + h * 16) * NPIX;
  float mx = 0.f;
  for (int j = 0; j < 4; j++) {
    int n = threadIdx.x + j * 256;
    float xk[16], xv[16], sk = 0.f, sv = 0.f;
#pragma unroll
    for (int d = 0; d < 16; d++) {
      xk[d] = kb[(long)d * NPIX + n]; sk += xk[d];
      xv[d] = vb[(long)d * NPIX + n]; sv += xv[d];
    }
    float mk = sk * (1.f / 16.f), mv = sv * (1.f / 16.f);
    float vk_ = 0.f, vv_ = 0.f;
#pragma unroll
    for (int d = 0; d < 16; d++) {
      float a = xk[d] - mk; vk_ += a * a;
      float c = xv[d] - mv; vv_ += c * c;
    }
    vk_ *= (1.f / 15.f); vv_ *= (1.f / 15.f);
    var_k[(long)bh * NPIX + n] = vk_;
    var_v[(long)bh * NPIX + n] = vv_;
    mx = fmaxf(mx, vk_);
#pragma unroll
    for (int d = 0; d < 16; d++) trans[d][threadIdx.x] = xv[d];
    __syncthreads();
    {
      int d = threadIdx.x >> 4, mc = threadIdx.x & 15;
      __align__(16) short tmp[16];
#pragma unroll
      for (int e = 0; e < 16; e++) tmp[e] = (short)f2bf(trans[d][mc * 16 + e]);
      short* dst = vTb + ((long)bh * 16 + d) * 1024 + j * 256 + mc * 16;
      *(uint4*)dst = *(uint4*)tmp;
      *(uint4*)(dst + 8) = *(uint4*)(tmp + 8);
    }
    __syncthreads();
  }
  red[threadIdx.x] = mx;
  __syncthreads();
  for (int s = 128; s > 0; s >>= 1) {
    if (threadIdx.x < s) red[threadIdx.x] = fmaxf(red[threadIdx.x], red[threadIdx.x + s]);
    __syncthreads();
  }
  if (threadIdx.x == 0) maxvk[bh] = red[0];
}

// ---------------------------------------------------------------------------
// MFMA stat attention: to[d][n] = (sum_m v[m][d]*w[m,n]) / (sum_m w[m,n]),
// w[m,n] = exp(cn[n]*(vk[m]-mv)) synthesized per lane into the B-fragment
// (col=l&15 -> n, k=(l>>4)*8+j -> m).  A-frag = vTb[bh][d][m] contiguous.
// Full K=1024 in one block: no partials.  Den via shfl_xor butterfly over
// the 4 k-slice lane groups.  Writes tcT[b][n][h*16+d] bf16 directly
// (feeds tproj; no fp32 to_cn, no transpose kernel).
// Grid (64 bh, 16 n-chunks), 256 thr (4 waves, wave w owns 16 n).
// ---------------------------------------------------------------------------
__global__ __launch_bounds__(256) void stat_mfma_kernel(
    const short* __restrict__ vTb, const float* __restrict__ var_k,
    const float* __restrict__ var_v, const float* __restrict__ maxvk,
    short* __restrict__ tcT) {
  const int bh = blockIdx.x;
  const int b = bh >> 3, h = bh & 7;
  const int n0 = blockIdx.y * 64;
  const int tid = threadIdx.x;
  const int l = tid & 63, w = tid >> 6;
  const int ln = l & 15, lk = l >> 4;
  const int n = n0 + w * 16 + ln;
  __shared__ float vk[1024];
  for (int i = tid; i < 1024; i += 256) vk[i] = var_k[(long)bh * 1024 + i];
  const float cn = var_v[(long)bh * 1024 + n] * 0.25f;
  const float mv = maxvk[bh];
  const short* arow = vTb + ((long)bh * 16 + ln) * 1024 + lk * 8;
  __syncthreads();
  f32x4 acc = {};
  float psum = 0.f;
  for (int m0 = 0; m0 < 1024; m0 += 32) {
    short8v afrag = *(const short8v*)(arow + m0);
    short8v bfrag;
#pragma unroll
    for (int j = 0; j < 8; j++) {
      float wv = __expf(cn * (vk[m0 + lk * 8 + j] - mv));
      psum += wv;
      bfrag[j] = (short)f2bf(wv);
    }
    acc = __builtin_amdgcn_mfma_f32_16x16x32_bf16(afrag, bfrag, acc, 0, 0, 0);
  }
  psum += __shfl_xor(psum, 16);
  psum += __shfl_xor(psum, 32);
  const float inv = 1.f / psum;
  // lane holds to[d=lk*4+i][n]; write tcT[b][n][h*16+lk*4 .. +4] (8B aligned)
  unsigned long long pk =
      (unsigned long long)(unsigned short)f2bf(acc[0] * inv) |
      ((unsigned long long)(unsigned short)f2bf(acc[1] * inv) << 16) |
      ((unsigned long long)(unsigned short)f2bf(acc[2] * inv) << 32) |
      ((unsigned long long)(unsigned short)f2bf(acc[3] * inv) << 48);
  *(unsigned long long*)(tcT + ((long)b * 1024 + n) * 128 + h * 16 + lk * 4) = pk;
}

// ---------------------------------------------------------------------------
// Bit-pack signs of fused spatial q/k projections.
// ---------------------------------------------------------------------------
__global__ __launch_bounds__(256) void pack_kernel(
    const float* __restrict__ sqkv,
    unsigned long long* __restrict__ qbits, unsigned long long* __restrict__ kbits) {
  const int wave = threadIdx.x >> 6, lane = threadIdx.x & 63;
  const long p = (long)blockIdx.x * 4 + wave;  // 0..8191
  const int b = (int)(p >> 10), n = (int)(p & 1023);
  const float* base = sqkv + (long)b * 384 * NPIX + n;
  unsigned long long q0 = __ballot(base[(long)lane * NPIX] > 0.f);
  unsigned long long q1 = __ballot(base[(long)(64 + lane) * NPIX] > 0.f);
  unsigned long long k0 = __ballot(base[(long)(128 + lane) * NPIX] > 0.f);
  unsigned long long k1 = __ballot(base[(long)(192 + lane) * NPIX] > 0.f);
  if (lane == 0) {
    qbits[p * 2] = q0; qbits[p * 2 + 1] = q1;
    kbits[p * 2] = k0; kbits[p * 2 + 1] = k1;
  }
}

// ---------------------------------------------------------------------------
// MFMA binary-attention GEMM with in-register w synthesis.
// pnum[sp][b][c][n] = sum_m pv[c,m]*w[m,n] over m in [sp*256, +256);
// pden[sp][b][n] = sum_m w[m,n].  Grid (16, 4, 8), 256 thr (4 waves).
// ---------------------------------------------------------------------------
__global__ __launch_bounds__(256) void obgemm_kernel(
    const short* __restrict__ pvb, const unsigned long long* __restrict__ qbits,
    const unsigned long long* __restrict__ kbits, float* __restrict__ pnum,
    float* __restrict__ pden) {
  const int b = blockIdx.z;
  const int sp = blockIdx.y;
  const int n0 = blockIdx.x * 64;
  const int kb0 = sp * 256;
  __shared__ __align__(16) short As[128][40];
  __shared__ __align__(16) unsigned long long kbsh[256][2];
  const int tid = threadIdx.x;
  const int l = tid & 63, w = tid >> 6;
  const int ln = l & 15, lk = l >> 4;
  const int n = n0 + w * 16 + ln;
  const unsigned long long q0 = qbits[((long)b * 1024 + n) * 2];
  const unsigned long long q1 = qbits[((long)b * 1024 + n) * 2 + 1];
  *(uint4*)&kbsh[tid][0] = *(const uint4*)(kbits + ((long)b * 1024 + kb0 + tid) * 2);
  const float fs = 0.08838834764831845f;
  const int sc = tid >> 1, sh = (tid & 1) * 16;
  const short* pvrow = pvb + ((long)b * 128 + sc) * 1024 + kb0;
  f32x4 acc[8] = {};
  float psum = 0.f;
  for (int ks = 0; ks < 8; ks++) {  // 32 m per step
    *(uint4*)&As[sc][sh] = *(const uint4*)(pvrow + ks * 32 + sh);
    *(uint4*)&As[sc][sh + 8] = *(const uint4*)(pvrow + ks * 32 + sh + 8);
    __syncthreads();
    const int mloc = ks * 32 + lk * 8;
    short8v bfrag;
#pragma unroll
    for (int j = 0; j < 8; j++) {
      unsigned long long kw0 = kbsh[mloc + j][0];
      unsigned long long kw1 = kbsh[mloc + j][1];
      int ham = __popcll(kw0 ^ q0) + __popcll(kw1 ^ q1);
      float wv = __expf((float)(128 - 2 * ham) * fs);
      psum += wv;
      bfrag[j] = (short)f2bf(wv);
    }
#pragma unroll
    for (int ct = 0; ct < 8; ct++) {
      short8v afrag = *(short8v*)&As[ct * 16 + ln][lk * 8];
      acc[ct] = __builtin_amdgcn_mfma_f32_16x16x32_bf16(afrag, bfrag, acc[ct], 0, 0, 0);
    }
    __syncthreads();
  }
  float* dst = pnum + (((long)sp * 8 + b) * 128) * 1024 + n;
#pragma unroll
  for (int ct = 0; ct < 8; ct++)
#pragma unroll
    for (int i = 0; i < 4; i++)
      dst[(long)(ct * 16 + lk * 4 + i) * 1024] = acc[ct][i];
  psum += __shfl_xor(psum, 16);
  psum += __shfl_xor(psum, 32);
  if (lk == 0)
    pden[((long)sp * 8 + b) * 1024 + n] = psum;
}

// ---------------------------------------------------------------------------
// Fused depthwise 3x3 conv + K-split ob reduce + combine.
// ---------------------------------------------------------------------------
__global__ __launch_bounds__(256) void dwcombine_kernel(
    float* __restrict__ yc, const float* __restrict__ dw_w,
    const float* __restrict__ dw_b, const float* __restrict__ pnum,
    const float* __restrict__ pden, const float* __restrict__ sproj_b,
    const float* __restrict__ g, const float* __restrict__ alpha) {
  const int bc = blockIdx.x;
  const int b = bc >> 7, cx = bc & 127;
  const float* img = yc + ((long)b * 384 + 128 + cx) * NPIX;
  float* dst = yc + ((long)b * 384 + 256 + cx) * NPIX;
  float w[9];
#pragma unroll
  for (int i = 0; i < 9; i++) w[i] = dw_w[cx * 9 + i];
  const float bias = dw_b[cx];
  const float a = alpha[b];
  const float gg = g[bc];
  const float sb = sproj_b[cx];
  const long ns = 8L * 128 * 1024;
  const long ds = 8L * 1024;
  const long nbase = ((long)b * 128 + cx) * 1024;
  const long dbase = (long)b * 1024;
  for (int i = threadIdx.x; i < 1024; i += 256) {
    int h = i >> 5, wx = i & 31;
    float s = bias;
#pragma unroll
    for (int ky = 0; ky < 3; ky++) {
      int hh = h + ky - 1;
      if (hh < 0 || hh > 31) continue;
#pragma unroll
      for (int kx = 0; kx < 3; kx++) {
        int ww2 = wx + kx - 1;
        if (ww2 < 0 || ww2 > 31) continue;
        s += img[hh * 32 + ww2] * w[ky * 3 + kx];
      }
    }
    float num = pnum[nbase + i] + pnum[nbase + i + ns] +
                pnum[nbase + i + 2 * ns] + pnum[nbase + i + 3 * ns];
    float den = pden[dbase + i] + pden[dbase + i + ds] +
                pden[dbase + i + 2 * ds] + pden[dbase + i + 3 * ds];
    float obv = num / den + sb;
    dst[i] = dst[i] + gg * img[i] + (1.f - a) * s + a * obv;
  }
}

// ---------------------------------------------------------------------------
extern "C" void kernel_launch(void* const* d_in, const int* in_sizes, int n_in,
                              void* d_out, int out_size, void* d_ws, size_t ws_size,
                              hipStream_t stream) {
  const float* x = (const float*)d_in[0];
  const float* cv1_w = (const float*)d_in[1];
  const float* cv1_b = (const float*)d_in[2];
  const float* fm_w1 = (const float*)d_in[3];
  const float* fm_w2 = (const float*)d_in[4];
  const float* ca_w1 = (const float*)d_in[5];
  const float* ca_w2 = (const float*)d_in[6];
  const float* qkv_w = (const float*)d_in[7];
  const float* tproj_w = (const float*)d_in[8];
  const float* tproj_b = (const float*)d_in[9];
  const float* dw_w = (const float*)d_in[10];
  const float* dw_b = (const float*)d_in[11];
  const float* rt_w = (const float*)d_in[12];
  const float* rt_b = (const float*)d_in[13];
  const float* q_w = (const float*)d_in[14];
  const float* k_w = (const float*)d_in[15];
  const float* v_w = (const float*)d_in[16];
  const float* sproj_w = (const float*)d_in[17];
  const float* sproj_b = (const float*)d_in[18];
  const float* cv2_w = (const float*)d_in[19];
  const float* cv2_b = (const float*)d_in[20];
  float* out = (float*)d_out;

  char* wsp = (char*)d_ws;
  size_t off = 0;
  auto alloc = [&](size_t bytes) {
    void* p = wsp + off;
    off += (bytes + 255) & ~(size_t)255;
    return p;
  };
  float* yc = (float*)alloc(8UL * 384 * 1024 * 4);
  float* qkvb = (float*)alloc(8UL * 384 * 1024 * 4);   // pnum head
  float* pn_t = (float*)alloc(8UL * 128 * 1024 * 4);   // pnum tail (exact 16MB)
  float* sqkv = (float*)alloc(8UL * 384 * 1024 * 4);
  float* pv = (float*)alloc(8UL * 128 * 1024 * 4);     // pvb (bf16)
  short* xT = (short*)alloc(8UL * 1024 * 256 * 2);     // ycT head
  short* y1T = (short*)alloc(8UL * 1024 * 128 * 2);    // ycT tail (exact)
  short* tcT = (short*)alloc(8UL * 1024 * 128 * 2);
  short* vvT = (short*)alloc(8UL * 1024 * 128 * 2);
  short* wb = (short*)alloc(294912UL * 2);
  short* vTb = (short*)alloc(64UL * 16 * 1024 * 2);
  float* pden = (float*)alloc(4UL * 8 * 1024 * 4);
  float* var_k = (float*)alloc(8UL * 8 * 1024 * 4);
  float* var_v = (float*)alloc(8UL * 8 * 1024 * 4);
  float* maxvk = (float*)alloc(64 * 4);
  float* pooled = (float*)alloc(1024 * 4);
  float* m1 = (float*)alloc(1024 * 4);
  float* g = (float*)alloc(1024 * 4);
  float* alpha = (float*)alloc(8 * 4);
  unsigned long long* qbits = (unsigned long long*)alloc(8192UL * 2 * 8);
  unsigned long long* kbits = (unsigned long long*)alloc(8192UL * 2 * 8);
  (void)pn_t;
  // aliases (lifetime-disjoint, adjacency guaranteed by alloc order):
  float* pnum = qkvb;       // 16MB = qkvb+pn_t exactly; qkvb dead after varmax
  short* pvb = (short*)pv;  // bf16 pv lives in pv buffer
  short* ycT = xT;          // 6.29MB = xT+y1T exactly
  // weight arena offsets
  const short* cv1b = wb;
  const short* qkvwb = wb + 65536;
  const short* tprojb = wb + 114688;
  const short* sprojb = wb + 131072;
  const short* cv2b = wb + 147456;
  const short* skvb = wb + 245760;
  if (off > ws_size) return;

  dim3 blk(256);
  // 0. weights -> bf16 arena
  convw_kernel<<<dim3(1152), blk, 0, stream>>>(cv1_w, qkv_w, tproj_w, sproj_w,
                                               cv2_w, q_w, k_w, v_w, wb);
  // 0b. xT = transpose(x) bf16
  tconv_kernel<<<dim3(4, 16, 8), blk, 0, stream>>>(x, 256L * 1024, 256, xT);
  // 1. cv1 (MFMA): yc[:,0:256,:] = cv1_w @ x + cv1_b
  mgemm_kernel<true, false, false><<<dim3(16, 4, 8), blk, 0, stream>>>(
      cv1b, xT, cv1_b, nullptr, yc, 256, 1024L * 256, 384L * 1024, 0);
  // 2. FFT pooling + channel means
  fftpool_kernel<<<dim3(1024), blk, 0, stream>>>(yc, pooled, m1);
  // 3. gates
  gates_kernel<<<dim3(8), dim3(128), 0, stream>>>(pooled, m1, fm_w1, fm_w2,
                                                  ca_w1, ca_w2, rt_w, rt_b, g, alpha);
  // 3b. y1T = transpose(y1) bf16
  tconv_kernel<<<dim3(2, 16, 8), blk, 0, stream>>>(yc + 128 * 1024, 384L * 1024,
                                                   128, y1T);
  // 4. qkv projection (MFMA)
  mgemm_kernel<false, false, false><<<dim3(16, 6, 8), blk, 0, stream>>>(
      qkvwb, y1T, nullptr, nullptr, qkvb, 128, 1024L * 128, 384L * 1024, 0);
  // 5. variances + per-bh max + bf16 transposed V (vTb)
  varmax_kernel<<<dim3(64), blk, 0, stream>>>(qkvb, var_k, var_v, maxvk, vTb);
  // 6. MFMA stat attention -> tcT (bf16, transposed; no partials/reduce)
  stat_mfma_kernel<<<dim3(64, 16), blk, 0, stream>>>(vTb, var_k, var_v, maxvk, tcT);
  // 7. tproj (MFMA) -> yc[:,256:384,:]
  mgemm_kernel<true, false, false><<<dim3(16, 2, 8), blk, 0, stream>>>(
      tprojb, tcT, tproj_b, nullptr, yc + 256 * 1024, 128, 1024L * 128,
      384L * 1024, 0);
  // 8. fused spatial q/k/v projection (MFMA)
  mgemm_kernel<false, false, false><<<dim3(16, 6, 8), blk, 0, stream>>>(
      skvb, y1T, nullptr, nullptr, sqkv, 128, 1024L * 128, 384L * 1024, 0);
  // 9. sign pack
  pack_kernel<<<dim3(2048), blk, 0, stream>>>(sqkv, qbits, kbits);
  // 9b. vvT = transpose(vv); pv = sproj_w @ vv (MFMA, bf16 out)
  tconv_kernel<<<dim3(2, 16, 8), blk, 0, stream>>>(sqkv + 256 * 1024,
                                                   384L * 1024, 128, vvT);
  mgemm_kernel<false, false, true><<<dim3(16, 2, 8), blk, 0, stream>>>(
      sprojb, vvT, nullptr, nullptr, pvb, 128, 1024L * 128, 128L * 1024, 0);
  // 10. MFMA binary-attention GEMM (in-register w synth) -> partials
  obgemm_kernel<<<dim3(16, 4, 8), blk, 0, stream>>>(pvb, qbits, kbits, pnum, pden);
  // 11. fused depthwise conv + ob-reduce + combine into yc attn region
  dwcombine_kernel<<<dim3(1024), blk, 0, stream>>>(yc, dw_w, dw_b, pnum, pden,
                                                   sproj_b, g, alpha);
  // 12. ycT = transpose(yc, 384ch); cv2 (MFMA) + residual
  tconv_kernel<<<dim3(6, 16, 8), blk, 0, stream>>>(yc, 384L * 1024, 384, ycT);
  mgemm_kernel<true, true, false><<<dim3(16, 4, 8), blk, 0, stream>>>(
      cv2b, ycT, cv2_b, x, out, 384, 1024L * 384, 256L * 1024, 256L * 1024);
}

// Round 16
// 125.874 us; speedup vs baseline: 3.3507x; 1.1844x over previous
//
#include <hip/hip_runtime.h>
#include <math.h>

// Problem constants
#define BATCH 8
#define NPIX 1024   // 32*32

typedef __attribute__((ext_vector_type(8))) short short8v;
typedef __attribute__((ext_vector_type(4))) float f32x4;

__device__ inline unsigned short f2bf(float x) {  // fp32 -> bf16 RNE
  unsigned int u = __float_as_uint(x);
  return (unsigned short)((u + 0x7FFFu + ((u >> 16) & 1u)) >> 16);
}
__device__ inline float bf2f(unsigned short h) {
  return __uint_as_float((unsigned int)h << 16);
}
__device__ inline unsigned long long pack4bf(float a, float b, float c, float d) {
  return (unsigned long long)(unsigned short)f2bf(a) |
         ((unsigned long long)(unsigned short)f2bf(b) << 16) |
         ((unsigned long long)(unsigned short)f2bf(c) << 32) |
         ((unsigned long long)(unsigned short)f2bf(d) << 48);
}

// ---------------------------------------------------------------------------
// Weights -> bf16 arena:
// [0,65536) cv1 | [65536,163840) qkv|q|k|v (768x128) | [163840,180224) tproj
// [180224,196608) sproj | [196608,294912) cv2
// ---------------------------------------------------------------------------
__global__ __launch_bounds__(256) void convw_kernel(
    const float* __restrict__ cv1_w, const float* __restrict__ qkv_w,
    const float* __restrict__ tproj_w, const float* __restrict__ sproj_w,
    const float* __restrict__ cv2_w, const float* __restrict__ q_w,
    const float* __restrict__ k_w, const float* __restrict__ v_w,
    short* __restrict__ wb) {
  int i = blockIdx.x * 256 + threadIdx.x;  // < 294912
  float v;
  if (i < 65536) v = cv1_w[i];
  else if (i < 163840) {
    int j = i - 65536;
    if (j < 49152) v = qkv_w[j];
    else {
      int jj = j - 49152, wsel = jj >> 14, r = jj & 16383;
      v = (wsel == 0) ? q_w[r] : (wsel == 1) ? k_w[r] : v_w[r];
    }
  }
  else if (i < 180224) v = tproj_w[i - 163840];
  else if (i < 196608) v = sproj_w[i - 180224];
  else v = cv2_w[i - 196608];
  wb[i] = (short)f2bf(v);
}

// ---------------------------------------------------------------------------
// Transpose + convert: dst[b][n][dstOff+c] (bf16, row stride dstStride)
//                    = src[b][c][n] (fp32).  Grid (C/64, 16, 8).
// ---------------------------------------------------------------------------
__global__ __launch_bounds__(256) void tconv_kernel(
    const float* __restrict__ src, long sSrc, int dstStride, int dstOff,
    short* __restrict__ dst) {
  __shared__ float t[64][65];
  const int b = blockIdx.z;
  const int c0 = blockIdx.x * 64, n0 = blockIdx.y * 64;
  const float* s = src + (long)b * sSrc;
  short* d = dst + (long)b * 1024 * dstStride;
  const int tid = threadIdx.x;
#pragma unroll
  for (int p = 0; p < 16; p++) {
    int idx = tid + p * 256;
    int cl = idx >> 6, nl = idx & 63;
    t[cl][nl] = s[(long)(c0 + cl) * 1024 + n0 + nl];
  }
  __syncthreads();
#pragma unroll
  for (int p = 0; p < 16; p++) {
    int idx = tid + p * 256;
    int nl = idx >> 6, cl = idx & 63;
    d[(long)(n0 + nl) * dstStride + dstOff + c0 + cl] = (short)f2bf(t[cl][nl]);
  }
}

// ---------------------------------------------------------------------------
// MFMA bf16 GEMM, output modes:
//  0: fp32 std to Y0            (tproj->attn, cv2->out)
//  1: bf16 std to Y0            (pv)
//  2: cv1: bf16 TRANSPOSED ycT[n][m] (m 0..256) to Y0 + y1 fp32 (m>=128) Y1
//  3: qkvskv: m0<384 -> fp32 std Y0 (qkvb); else bf16 transposed
//     sqkvT[n][m-384] to Y1
// XT rows have stride ldx (k-contiguous bf16).
// ---------------------------------------------------------------------------
template<int MODE, bool HAS_BIAS, bool HAS_RES>
__global__ __launch_bounds__(256) void mgemm_kernel(
    const short* __restrict__ Wb, const short* __restrict__ XT, int ldx,
    const float* __restrict__ bias, const float* __restrict__ res,
    void* __restrict__ Y0, void* __restrict__ Y1,
    int K, long sXT, long sY, long sR) {
  __shared__ __align__(16) short As[64][40];
  __shared__ __align__(16) short Bs[64][40];
  const int b = blockIdx.z;
  const int n0 = blockIdx.x * 64, m0 = blockIdx.y * 64;
  const int tid = threadIdx.x;
  const int l = tid & 63, w = tid >> 6;
  const int wm = w >> 1, wn = w & 1;
  const short* Xb = XT + (long)b * sXT;
  const int sr = tid >> 2, sko = (tid & 3) * 8;
  const int fr = l & 15, fk = (l >> 4) * 8;
  f32x4 acc[2][2] = {};
  for (int k0 = 0; k0 < K; k0 += 32) {
    *(uint4*)&As[sr][sko] = *(const uint4*)(Wb + (long)(m0 + sr) * K + k0 + sko);
    *(uint4*)&Bs[sr][sko] = *(const uint4*)(Xb + (long)(n0 + sr) * ldx + k0 + sko);
    __syncthreads();
    short8v a0 = *(short8v*)&As[wm * 32 + fr][fk];
    short8v a1 = *(short8v*)&As[wm * 32 + 16 + fr][fk];
    short8v b0 = *(short8v*)&Bs[wn * 32 + fr][fk];
    short8v b1 = *(short8v*)&Bs[wn * 32 + 16 + fr][fk];
    acc[0][0] = __builtin_amdgcn_mfma_f32_16x16x32_bf16(a0, b0, acc[0][0], 0, 0, 0);
    acc[0][1] = __builtin_amdgcn_mfma_f32_16x16x32_bf16(a0, b1, acc[0][1], 0, 0, 0);
    acc[1][0] = __builtin_amdgcn_mfma_f32_16x16x32_bf16(a1, b0, acc[1][0], 0, 0, 0);
    acc[1][1] = __builtin_amdgcn_mfma_f32_16x16x32_bf16(a1, b1, acc[1][1], 0, 0, 0);
    __syncthreads();
  }
#pragma unroll
  for (int tm = 0; tm < 2; tm++) {
    const int m_base = m0 + wm * 32 + tm * 16 + (l >> 4) * 4;
#pragma unroll
    for (int tn = 0; tn < 2; tn++) {
      const int n = n0 + wn * 32 + tn * 16 + (l & 15);
      float v0 = acc[tm][tn][0], v1 = acc[tm][tn][1];
      float v2 = acc[tm][tn][2], v3 = acc[tm][tn][3];
      if (HAS_BIAS) {
        v0 += bias[m_base]; v1 += bias[m_base + 1];
        v2 += bias[m_base + 2]; v3 += bias[m_base + 3];
      }
      if (MODE == 0 || MODE == 1) {
        if (HAS_RES) {
          v0 += res[(long)b * sR + (long)(m_base + 0) * 1024 + n];
          v1 += res[(long)b * sR + (long)(m_base + 1) * 1024 + n];
          v2 += res[(long)b * sR + (long)(m_base + 2) * 1024 + n];
          v3 += res[(long)b * sR + (long)(m_base + 3) * 1024 + n];
        }
        if (MODE == 0) {
          float* Y = (float*)Y0 + (long)b * sY + n;
          Y[(long)(m_base + 0) * 1024] = v0; Y[(long)(m_base + 1) * 1024] = v1;
          Y[(long)(m_base + 2) * 1024] = v2; Y[(long)(m_base + 3) * 1024] = v3;
        } else {
          short* Y = (short*)Y0 + (long)b * sY + n;
          Y[(long)(m_base + 0) * 1024] = (short)f2bf(v0);
          Y[(long)(m_base + 1) * 1024] = (short)f2bf(v1);
          Y[(long)(m_base + 2) * 1024] = (short)f2bf(v2);
          Y[(long)(m_base + 3) * 1024] = (short)f2bf(v3);
        }
      } else if (MODE == 2) {
        *(unsigned long long*)((short*)Y0 + ((long)b * 1024 + n) * 384 + m_base) =
            pack4bf(v0, v1, v2, v3);
        if (m_base >= 128) {
          float* Y = (float*)Y1 + ((long)b * 128 + m_base - 128) * 1024 + n;
          Y[0] = v0; Y[1024] = v1; Y[2048] = v2; Y[3072] = v3;
        }
      } else {  // MODE 3
        if (m0 < 384) {
          float* Y = (float*)Y0 + (long)b * 384 * 1024 + (long)m_base * 1024 + n;
          Y[0] = v0; Y[1024] = v1; Y[2048] = v2; Y[3072] = v3;
        } else {
          *(unsigned long long*)((short*)Y1 + ((long)b * 1024 + n) * 384 +
                                 (m_base - 384)) = pack4bf(v0, v1, v2, v3);
        }
      }
    }
  }
}

// ---------------------------------------------------------------------------
// FFT magnitude pooling + channel means over y1[b][c][n].  Block per (b,c).
// ---------------------------------------------------------------------------
__global__ __launch_bounds__(256) void fftpool_kernel(
    const float* __restrict__ y1, float* __restrict__ pooled, float* __restrict__ m1) {
  const int bc = blockIdx.x;
  const float* img = y1 + (long)bc * NPIX;
  __shared__ float im[1024];
  __shared__ float Gr[32][17], Gi[32][17];
  __shared__ float cs[32], sn[32];
  __shared__ float red[256];
  const int t = threadIdx.x;
  if (t < 32) {
    float ang = -0.19634954084936207f * (float)t;  // -2*pi*t/32
    __sincosf(ang, &sn[t], &cs[t]);
  }
  float lsum = 0.f;
  for (int i = t; i < 1024; i += 256) { float v = img[i]; im[i] = v; lsum += v; }
  red[t] = lsum;
  __syncthreads();
  for (int s = 128; s > 0; s >>= 1) {
    if (t < s) red[t] += red[t + s];
    __syncthreads();
  }
  if (t == 0) m1[bc] = red[0] * (1.f / 1024.f);
  for (int i = t; i < 544; i += 256) {
    int h = i / 17, v = i % 17;
    float ar = 0.f, ai = 0.f;
    for (int w2 = 0; w2 < 32; w2++) {
      int k = (v * w2) & 31;
      float x = im[h * 32 + w2];
      ar += x * cs[k]; ai += x * sn[k];
    }
    Gr[h][v] = ar; Gi[h][v] = ai;
  }
  __syncthreads();
  float asum = 0.f;
  for (int i = t; i < 544; i += 256) {
    int u = i / 17, v = i % 17;
    float xr = 0.f, xi = 0.f;
    for (int h = 0; h < 32; h++) {
      int k = (u * h) & 31;
      float gr = Gr[h][v], gi = Gi[h][v];
      xr += gr * cs[k] - gi * sn[k];
      xi += gr * sn[k] + gi * cs[k];
    }
    asum += sqrtf(xr * xr + xi * xi);
  }
  red[t] = asum;
  __syncthreads();
  for (int s = 128; s > 0; s >>= 1) {
    if (t < s) red[t] += red[t + s];
    __syncthreads();
  }
  if (t == 0) pooled[bc] = red[0] * (1.f / (32.f * 544.f));
}

// ---------------------------------------------------------------------------
// Gates: fw/ca MLPs -> g = fw*ca; p_route -> alpha.  One block per batch.
// ---------------------------------------------------------------------------
__global__ __launch_bounds__(128) void gates_kernel(
    const float* __restrict__ pooled, const float* __restrict__ m1,
    const float* __restrict__ fm_w1, const float* __restrict__ fm_w2,
    const float* __restrict__ ca_w1, const float* __restrict__ ca_w2,
    const float* __restrict__ rt_w, const float* __restrict__ rt_b,
    float* __restrict__ g, float* __restrict__ alpha) {
  const int b = blockIdx.x, t = threadIdx.x;
  __shared__ float h1[8], fwv[128], xsm[128], h2[8];
  const float* pb = pooled + b * 128;
  const float* mb = m1 + b * 128;
  if (t < 8) {
    float s = 0.f;
    for (int c = 0; c < 128; c++) s += pb[c] * fm_w1[t * 128 + c];
    h1[t] = fmaxf(s, 0.f);
  }
  __syncthreads();
  {
    float s = 0.f;
    for (int r = 0; r < 8; r++) s += h1[r] * fm_w2[t * 8 + r];
    float fw = 1.f / (1.f + __expf(-s));
    fwv[t] = fw; xsm[t] = fw * mb[t];
  }
  __syncthreads();
  if (t < 8) {
    float s = 0.f;
    for (int c = 0; c < 128; c++) s += xsm[c] * ca_w1[t * 128 + c];
    h2[t] = fmaxf(s, 0.f);
  }
  __syncthreads();
  {
    float s = 0.f;
    for (int r = 0; r < 8; r++) s += h2[r] * ca_w2[t * 8 + r];
    float ca = 1.f / (1.f + __expf(-s));
    g[b * 128 + t] = fwv[t] * ca;
  }
  if (t == 0) {
    float s = 0.f;
    for (int c = 0; c < 128; c++) s += mb[c] * rt_w[c];
    s += rt_b[0];
    alpha[b] = 1.f / (1.f + __expf(-s));
  }
}

// ---------------------------------------------------------------------------
// Variance of k and v head vectors (ddof=1) + per-bh max(var_k).
// Emits vTb[bh][d][m] (bf16, m-contiguous) via in-LDS transpose.
// ---------------------------------------------------------------------------
__global__ __launch_bounds__(256) void varmax_kernel(
    const float* __restrict__ qkvb, float* __restrict__ var_k,
    float* __restrict__ var_v, float* __restrict__ maxvk,
    short* __restrict__ vTb) {
  const int bh = blockIdx.x;
  const int b = bh >> 3, h = bh & 7;
  __shared__ float red[256];
  __shared__ float trans[16][256];
  const float* kb = qkvb + ((long)b * 384 + 128 + h * 16) * NPIX;
  const float* vb = qkvb + ((long)b * 384 + 256 + h * 16) * NPIX;
  float mx = 0.f;
  for (int j = 0; j < 4; j++) {
    int n = threadIdx.x + j * 256;
    float xk[16], xv[16], sk = 0.f, sv = 0.f;
#pragma unroll
    for (int d = 0; d < 16; d++) {
      xk[d] = kb[(long)d * NPIX + n]; sk += xk[d];
      xv[d] = vb[(long)d * NPIX + n]; sv += xv[d];
    }
    float mk = sk * (1.f / 16.f), mv = sv * (1.f / 16.f);
    float vk_ = 0.f, vv_ = 0.f;
#pragma unroll
    for (int d = 0; d < 16; d++) {
      float a = xk[d] - mk; vk_ += a * a;
      float c = xv[d] - mv; vv_ += c * c;
    }
    vk_ *= (1.f / 15.f); vv_ *= (1.f / 15.f);
    var_k[(long)bh * NPIX + n] = vk_;
    var_v[(long)bh * NPIX + n] = vv_;
    mx = fmaxf(mx, vk_);
#pragma unroll
    for (int d = 0; d < 16; d++) trans[d][threadIdx.x] = xv[d];
    __syncthreads();
    {
      int d = threadIdx.x >> 4, mc = threadIdx.x & 15;
      __align__(16) short tmp[16];
#pragma unroll
      for (int e = 0; e < 16; e++) tmp[e] = (short)f2bf(trans[d][mc * 16 + e]);
      short* dst = vTb + ((long)bh * 16 + d) * 1024 + j * 256 + mc * 16;
      *(uint4*)dst = *(uint4*)tmp;
      *(uint4*)(dst + 8) = *(uint4*)(tmp + 8);
    }
    __syncthreads();
  }
  red[threadIdx.x] = mx;
  __syncthreads();
  for (int s = 128; s > 0; s >>= 1) {
    if (threadIdx.x < s) red[threadIdx.x] = fmaxf(red[threadIdx.x], red[threadIdx.x + s]);
    __syncthreads();
  }
  if (threadIdx.x == 0) maxvk[bh] = red[0];
}

// ---------------------------------------------------------------------------
// MFMA stat attention -> tcT[b][n][h*16+d] bf16 (no partials).
// ---------------------------------------------------------------------------
__global__ __launch_bounds__(256) void stat_mfma_kernel(
    const short* __restrict__ vTb, const float* __restrict__ var_k,
    const float* __restrict__ var_v, const float* __restrict__ maxvk,
    short* __restrict__ tcT) {
  const int bh = blockIdx.x;
  const int b = bh >> 3, h = bh & 7;
  const int n0 = blockIdx.y * 64;
  const int tid = threadIdx.x;
  const int l = tid & 63, w = tid >> 6;
  const int ln = l & 15, lk = l >> 4;
  const int n = n0 + w * 16 + ln;
  __shared__ float vk[1024];
  for (int i = tid; i < 1024; i += 256) vk[i] = var_k[(long)bh * 1024 + i];
  const float cn = var_v[(long)bh * 1024 + n] * 0.25f;
  const float mv = maxvk[bh];
  const short* arow = vTb + ((long)bh * 16 + ln) * 1024 + lk * 8;
  __syncthreads();
  f32x4 acc = {};
  float psum = 0.f;
  for (int m0 = 0; m0 < 1024; m0 += 32) {
    short8v afrag = *(const short8v*)(arow + m0);
    short8v bfrag;
#pragma unroll
    for (int j = 0; j < 8; j++) {
      float wv = __expf(cn * (vk[m0 + lk * 8 + j] - mv));
      psum += wv;
      bfrag[j] = (short)f2bf(wv);
    }
    acc = __builtin_amdgcn_mfma_f32_16x16x32_bf16(afrag, bfrag, acc, 0, 0, 0);
  }
  psum += __shfl_xor(psum, 16);
  psum += __shfl_xor(psum, 32);
  const float inv = 1.f / psum;
  *(unsigned long long*)(tcT + ((long)b * 1024 + n) * 128 + h * 16 + lk * 4) =
      pack4bf(acc[0] * inv, acc[1] * inv, acc[2] * inv, acc[3] * inv);
}

// ---------------------------------------------------------------------------
// Bit-pack signs from sqkvT[b][n][c] (bf16, c-contiguous -> coalesced).
// Wave per (b,n); ch 0..128 = q, 128..256 = k.
// ---------------------------------------------------------------------------
__global__ __launch_bounds__(256) void pack_kernel(
    const short* __restrict__ sqkvT,
    unsigned long long* __restrict__ qbits, unsigned long long* __restrict__ kbits) {
  const int wave = threadIdx.x >> 6, lane = threadIdx.x & 63;
  const long p = (long)blockIdx.x * 4 + wave;  // 0..8191 = b*1024+n
  const short* base = sqkvT + p * 384;
  unsigned long long q0 = __ballot(bf2f((unsigned short)base[lane]) > 0.f);
  unsigned long long q1 = __ballot(bf2f((unsigned short)base[64 + lane]) > 0.f);
  unsigned long long k0 = __ballot(bf2f((unsigned short)base[128 + lane]) > 0.f);
  unsigned long long k1 = __ballot(bf2f((unsigned short)base[192 + lane]) > 0.f);
  if (lane == 0) {
    qbits[p * 2] = q0; qbits[p * 2 + 1] = q1;
    kbits[p * 2] = k0; kbits[p * 2 + 1] = k1;
  }
}

// ---------------------------------------------------------------------------
// MFMA binary-attention GEMM with in-register w synthesis (K-split x4).
// ---------------------------------------------------------------------------
__global__ __launch_bounds__(256) void obgemm_kernel(
    const short* __restrict__ pvb, const unsigned long long* __restrict__ qbits,
    const unsigned long long* __restrict__ kbits, float* __restrict__ pnum,
    float* __restrict__ pden) {
  const int b = blockIdx.z;
  const int sp = blockIdx.y;
  const int n0 = blockIdx.x * 64;
  const int kb0 = sp * 256;
  __shared__ __align__(16) short As[128][40];
  __shared__ __align__(16) unsigned long long kbsh[256][2];
  const int tid = threadIdx.x;
  const int l = tid & 63, w = tid >> 6;
  const int ln = l & 15, lk = l >> 4;
  const int n = n0 + w * 16 + ln;
  const unsigned long long q0 = qbits[((long)b * 1024 + n) * 2];
  const unsigned long long q1 = qbits[((long)b * 1024 + n) * 2 + 1];
  *(uint4*)&kbsh[tid][0] = *(const uint4*)(kbits + ((long)b * 1024 + kb0 + tid) * 2);
  const float fs = 0.08838834764831845f;
  const int sc = tid >> 1, sh = (tid & 1) * 16;
  const short* pvrow = pvb + ((long)b * 128 + sc) * 1024 + kb0;
  f32x4 acc[8] = {};
  float psum = 0.f;
  for (int ks = 0; ks < 8; ks++) {  // 32 m per step
    *(uint4*)&As[sc][sh] = *(const uint4*)(pvrow + ks * 32 + sh);
    *(uint4*)&As[sc][sh + 8] = *(const uint4*)(pvrow + ks * 32 + sh + 8);
    __syncthreads();
    const int mloc = ks * 32 + lk * 8;
    short8v bfrag;
#pragma unroll
    for (int j = 0; j < 8; j++) {
      unsigned long long kw0 = kbsh[mloc + j][0];
      unsigned long long kw1 = kbsh[mloc + j][1];
      int ham = __popcll(kw0 ^ q0) + __popcll(kw1 ^ q1);
      float wv = __expf((float)(128 - 2 * ham) * fs);
      psum += wv;
      bfrag[j] = (short)f2bf(wv);
    }
#pragma unroll
    for (int ct = 0; ct < 8; ct++) {
      short8v afrag = *(short8v*)&As[ct * 16 + ln][lk * 8];
      acc[ct] = __builtin_amdgcn_mfma_f32_16x16x32_bf16(afrag, bfrag, acc[ct], 0, 0, 0);
    }
    __syncthreads();
  }
  float* dst = pnum + (((long)sp * 8 + b) * 128) * 1024 + n;
#pragma unroll
  for (int ct = 0; ct < 8; ct++)
#pragma unroll
    for (int i = 0; i < 4; i++)
      dst[(long)(ct * 16 + lk * 4 + i) * 1024] = acc[ct][i];
  psum += __shfl_xor(psum, 16);
  psum += __shfl_xor(psum, 32);
  if (lk == 0)
    pden[((long)sp * 8 + b) * 1024 + n] = psum;
}

// ---------------------------------------------------------------------------
// Fused depthwise 3x3 conv + ob reduce + combine into attn (adds to tproj
// output already in attn):  attn += g*y1 + (1-a)*dwconv(y1) + a*obv.
// ---------------------------------------------------------------------------
__global__ __launch_bounds__(256) void dwcombine_kernel(
    const float* __restrict__ y1, float* __restrict__ attn,
    const float* __restrict__ dw_w, const float* __restrict__ dw_b,
    const float* __restrict__ pnum, const float* __restrict__ pden,
    const float* __restrict__ sproj_b, const float* __restrict__ g,
    const float* __restrict__ alpha) {
  const int bc = blockIdx.x;
  const int b = bc >> 7, cx = bc & 127;
  const float* img = y1 + (long)bc * NPIX;
  float* dst = attn + (long)bc * NPIX;
  float w[9];
#pragma unroll
  for (int i = 0; i < 9; i++) w[i] = dw_w[cx * 9 + i];
  const float bias = dw_b[cx];
  const float a = alpha[b];
  const float gg = g[bc];
  const float sb = sproj_b[cx];
  const long ns = 8L * 128 * 1024;
  const long ds = 8L * 1024;
  const long nbase = (long)bc * 1024;
  const long dbase = (long)b * 1024;
  for (int i = threadIdx.x; i < 1024; i += 256) {
    int h = i >> 5, wx = i & 31;
    float s = bias;
#pragma unroll
    for (int ky = 0; ky < 3; ky++) {
      int hh = h + ky - 1;
      if (hh < 0 || hh > 31) continue;
#pragma unroll
      for (int kx = 0; kx < 3; kx++) {
        int ww2 = wx + kx - 1;
        if (ww2 < 0 || ww2 > 31) continue;
        s += img[hh * 32 + ww2] * w[ky * 3 + kx];
      }
    }
    float num = pnum[nbase + i] + pnum[nbase + i + ns] +
                pnum[nbase + i + 2 * ns] + pnum[nbase + i + 3 * ns];
    float den = pden[dbase + i] + pden[dbase + i + ds] +
                pden[dbase + i + 2 * ds] + pden[dbase + i + 3 * ds];
    float obv = num / den + sb;
    dst[i] = dst[i] + gg * img[i] + (1.f - a) * s + a * obv;
  }
}

// ---------------------------------------------------------------------------
extern "C" void kernel_launch(void* const* d_in, const int* in_sizes, int n_in,
                              void* d_out, int out_size, void* d_ws, size_t ws_size,
                              hipStream_t stream) {
  const float* x = (const float*)d_in[0];
  const float* cv1_w = (const float*)d_in[1];
  const float* cv1_b = (const float*)d_in[2];
  const float* fm_w1 = (const float*)d_in[3];
  const float* fm_w2 = (const float*)d_in[4];
  const float* ca_w1 = (const float*)d_in[5];
  const float* ca_w2 = (const float*)d_in[6];
  const float* qkv_w = (const float*)d_in[7];
  const float* tproj_w = (const float*)d_in[8];
  const float* tproj_b = (const float*)d_in[9];
  const float* dw_w = (const float*)d_in[10];
  const float* dw_b = (const float*)d_in[11];
  const float* rt_w = (const float*)d_in[12];
  const float* rt_b = (const float*)d_in[13];
  const float* q_w = (const float*)d_in[14];
  const float* k_w = (const float*)d_in[15];
  const float* v_w = (const float*)d_in[16];
  const float* sproj_w = (const float*)d_in[17];
  const float* sproj_b = (const float*)d_in[18];
  const float* cv2_w = (const float*)d_in[19];
  const float* cv2_b = (const float*)d_in[20];
  float* out = (float*)d_out;

  char* wsp = (char*)d_ws;
  size_t off = 0;
  auto alloc = [&](size_t bytes) {
    void* p = wsp + off;
    off += (bytes + 255) & ~(size_t)255;
    return p;
  };
  float* qkvb = (float*)alloc(8UL * 384 * 1024 * 4);   // pnum head
  float* pn_t = (float*)alloc(8UL * 128 * 1024 * 4);   // pnum tail (16MB total)
  float* y1 = (float*)alloc(8UL * 128 * 1024 * 4);
  float* attn = (float*)alloc(8UL * 128 * 1024 * 4);
  short* ycT = (short*)alloc(8UL * 1024 * 384 * 2);
  short* sqkvT = (short*)alloc(8UL * 1024 * 384 * 2);
  short* xT = (short*)alloc(8UL * 1024 * 256 * 2);
  short* tcT = (short*)alloc(8UL * 1024 * 128 * 2);
  short* pvb = (short*)alloc(8UL * 128 * 1024 * 2);
  short* wb = (short*)alloc(294912UL * 2);
  short* vTb = (short*)alloc(64UL * 16 * 1024 * 2);
  float* pden = (float*)alloc(4UL * 8 * 1024 * 4);
  float* var_k = (float*)alloc(8UL * 8 * 1024 * 4);
  float* var_v = (float*)alloc(8UL * 8 * 1024 * 4);
  float* maxvk = (float*)alloc(64 * 4);
  float* pooled = (float*)alloc(1024 * 4);
  float* m1 = (float*)alloc(1024 * 4);
  float* g = (float*)alloc(1024 * 4);
  float* alpha = (float*)alloc(8 * 4);
  unsigned long long* qbits = (unsigned long long*)alloc(8192UL * 2 * 8);
  unsigned long long* kbits = (unsigned long long*)alloc(8192UL * 2 * 8);
  (void)pn_t;
  float* pnum = qkvb;  // 16.78MB = qkvb+pn_t; qkvb dead after varmax
  // weight arena offsets
  const short* cv1b = wb;
  const short* qsb = wb + 65536;
  const short* tprojb = wb + 163840;
  const short* sprojb = wb + 180224;
  const short* cv2b = wb + 196608;
  if (off > ws_size) return;

  dim3 blk(256);
  // 0. weights -> bf16 arena
  convw_kernel<<<dim3(1152), blk, 0, stream>>>(cv1_w, qkv_w, tproj_w, sproj_w,
                                               cv2_w, q_w, k_w, v_w, wb);
  // 0b. xT = transpose(x) bf16
  tconv_kernel<<<dim3(4, 16, 8), blk, 0, stream>>>(x, 256L * 1024, 256, 0, xT);
  // 1. cv1 (MFMA, MODE2): ycT[n][0..256] bf16 + y1 fp32
  mgemm_kernel<2, true, false><<<dim3(16, 4, 8), blk, 0, stream>>>(
      cv1b, xT, 256, cv1_b, nullptr, ycT, y1, 256, 1024L * 256, 0, 0);
  // 2. FFT pooling + channel means (y1)
  fftpool_kernel<<<dim3(1024), blk, 0, stream>>>(y1, pooled, m1);
  // 3. gates
  gates_kernel<<<dim3(8), dim3(128), 0, stream>>>(pooled, m1, fm_w1, fm_w2,
                                                  ca_w1, ca_w2, rt_w, rt_b, g, alpha);
  // 4. merged qkv + spatial-qkv projection (MODE3, M=768):
  //    rows 0..384 -> qkvb fp32; rows 384..768 -> sqkvT bf16 transposed
  mgemm_kernel<3, false, false><<<dim3(16, 12, 8), blk, 0, stream>>>(
      qsb, ycT + 128, 384, nullptr, nullptr, qkvb, sqkvT, 128, 1024L * 384, 0, 0);
  // 5. variances + per-bh max + bf16 transposed V (vTb)
  varmax_kernel<<<dim3(64), blk, 0, stream>>>(qkvb, var_k, var_v, maxvk, vTb);
  // 6. MFMA stat attention -> tcT (bf16 transposed)
  stat_mfma_kernel<<<dim3(64, 16), blk, 0, stream>>>(vTb, var_k, var_v, maxvk, tcT);
  // 7. tproj (MFMA, MODE0) -> attn
  mgemm_kernel<0, true, false><<<dim3(16, 2, 8), blk, 0, stream>>>(
      tprojb, tcT, 128, tproj_b, nullptr, attn, nullptr, 128, 1024L * 128,
      128L * 1024, 0);
  // 8. sign pack (coalesced reads from sqkvT)
  pack_kernel<<<dim3(2048), blk, 0, stream>>>(sqkvT, qbits, kbits);
  // 8b. pv = sproj_w @ vv (MFMA, MODE1 bf16 out; XT = sqkvT v-region)
  mgemm_kernel<1, false, false><<<dim3(16, 2, 8), blk, 0, stream>>>(
      sprojb, sqkvT + 256, 384, nullptr, nullptr, pvb, nullptr, 128,
      1024L * 384, 128L * 1024, 0);
  // 9. MFMA binary-attention GEMM -> partials
  obgemm_kernel<<<dim3(16, 4, 8), blk, 0, stream>>>(pvb, qbits, kbits, pnum, pden);
  // 10. fused depthwise conv + ob-reduce + combine into attn
  dwcombine_kernel<<<dim3(1024), blk, 0, stream>>>(y1, attn, dw_w, dw_b, pnum,
                                                   pden, sproj_b, g, alpha);
  // 11. transpose attn into ycT[n][256..384]
  tconv_kernel<<<dim3(2, 16, 8), blk, 0, stream>>>(attn, 128L * 1024, 384, 256, ycT);
  // 12. cv2 (MFMA, MODE0) + residual
  mgemm_kernel<0, true, true><<<dim3(16, 4, 8), blk, 0, stream>>>(
      cv2b, ycT, 384, cv2_b, x, out, nullptr, 384, 1024L * 384, 256L * 1024,
      256L * 1024);
}

// Round 17
// 122.969 us; speedup vs baseline: 3.4298x; 1.0236x over previous
//
#include <hip/hip_runtime.h>
#include <math.h>

// Problem constants
#define BATCH 8
#define NPIX 1024   // 32*32

typedef __attribute__((ext_vector_type(8))) short short8v;
typedef __attribute__((ext_vector_type(4))) float f32x4;

__device__ inline unsigned short f2bf(float x) {  // fp32 -> bf16 RNE
  unsigned int u = __float_as_uint(x);
  return (unsigned short)((u + 0x7FFFu + ((u >> 16) & 1u)) >> 16);
}
__device__ inline float bf2f(unsigned short h) {
  return __uint_as_float((unsigned int)h << 16);
}
__device__ inline unsigned long long pack4bf(float a, float b, float c, float d) {
  return (unsigned long long)(unsigned short)f2bf(a) |
         ((unsigned long long)(unsigned short)f2bf(b) << 16) |
         ((unsigned long long)(unsigned short)f2bf(c) << 32) |
         ((unsigned long long)(unsigned short)f2bf(d) << 48);
}

// ---------------------------------------------------------------------------
// Weights -> bf16 arena:
// [0,65536) cv1 | [65536,163840) qkv|q|k|v (768x128) | [163840,180224) tproj
// [180224,196608) sproj | [196608,294912) cv2
// ---------------------------------------------------------------------------
__global__ __launch_bounds__(256) void convw_kernel(
    const float* __restrict__ cv1_w, const float* __restrict__ qkv_w,
    const float* __restrict__ tproj_w, const float* __restrict__ sproj_w,
    const float* __restrict__ cv2_w, const float* __restrict__ q_w,
    const float* __restrict__ k_w, const float* __restrict__ v_w,
    short* __restrict__ wb) {
  int i = blockIdx.x * 256 + threadIdx.x;  // < 294912
  float v;
  if (i < 65536) v = cv1_w[i];
  else if (i < 163840) {
    int j = i - 65536;
    if (j < 49152) v = qkv_w[j];
    else {
      int jj = j - 49152, wsel = jj >> 14, r = jj & 16383;
      v = (wsel == 0) ? q_w[r] : (wsel == 1) ? k_w[r] : v_w[r];
    }
  }
  else if (i < 180224) v = tproj_w[i - 163840];
  else if (i < 196608) v = sproj_w[i - 180224];
  else v = cv2_w[i - 196608];
  wb[i] = (short)f2bf(v);
}

// ---------------------------------------------------------------------------
// MFMA bf16 GEMM.  Output modes:
//  0: fp32 std to Y0
//  1: bf16 std to Y0
//  2: transposed bf16 to Y0 at [n][tOff+m], row stride tStride; if EMIT_HI,
//     also fp32 std rows m>=128 to Y1 (cv1's y1 side output)
//  3: qkv/skv split: m0<384 -> fp32 std Y0; else bf16 transposed Y1 [n][m-384]
// X source: XF32T ? fp32 [K][1024] rows (in-kernel transpose stage)
//                 : bf16 [n][k] rows with stride ldx.
// ---------------------------------------------------------------------------
template<int MODE, bool HAS_BIAS, bool HAS_RES, bool XF32T, bool EMIT_HI>
__global__ __launch_bounds__(256) void mgemm_kernel(
    const short* __restrict__ Wb, const void* __restrict__ Xsrc, int ldx,
    const float* __restrict__ bias, const float* __restrict__ res,
    void* __restrict__ Y0, void* __restrict__ Y1,
    int K, long sXT, long sY, long sR, int tStride, int tOff) {
  __shared__ __align__(16) short As[64][40];
  __shared__ __align__(16) short Bs[64][40];
  const int b = blockIdx.z;
  const int n0 = blockIdx.x * 64, m0 = blockIdx.y * 64;
  const int tid = threadIdx.x;
  const int l = tid & 63, w = tid >> 6;
  const int wm = w >> 1, wn = w & 1;
  const int sr = tid >> 2, sko = (tid & 3) * 8;
  const int xr = tid >> 3, xcg = (tid & 7) * 8;  // XF32T staging map
  const int fr = l & 15, fk = (l >> 4) * 8;
  f32x4 acc[2][2] = {};
  for (int k0 = 0; k0 < K; k0 += 32) {
    *(uint4*)&As[sr][sko] = *(const uint4*)(Wb + (long)(m0 + sr) * K + k0 + sko);
    if (XF32T) {
      const float* Xf = (const float*)Xsrc + (long)b * sXT;
      const float4 xa = *(const float4*)(Xf + (long)(k0 + xr) * 1024 + n0 + xcg);
      const float4 xb = *(const float4*)(Xf + (long)(k0 + xr) * 1024 + n0 + xcg + 4);
      Bs[xcg + 0][xr] = (short)f2bf(xa.x); Bs[xcg + 1][xr] = (short)f2bf(xa.y);
      Bs[xcg + 2][xr] = (short)f2bf(xa.z); Bs[xcg + 3][xr] = (short)f2bf(xa.w);
      Bs[xcg + 4][xr] = (short)f2bf(xb.x); Bs[xcg + 5][xr] = (short)f2bf(xb.y);
      Bs[xcg + 6][xr] = (short)f2bf(xb.z); Bs[xcg + 7][xr] = (short)f2bf(xb.w);
    } else {
      const short* Xb = (const short*)Xsrc + (long)b * sXT;
      *(uint4*)&Bs[sr][sko] = *(const uint4*)(Xb + (long)(n0 + sr) * ldx + k0 + sko);
    }
    __syncthreads();
    short8v a0 = *(short8v*)&As[wm * 32 + fr][fk];
    short8v a1 = *(short8v*)&As[wm * 32 + 16 + fr][fk];
    short8v b0 = *(short8v*)&Bs[wn * 32 + fr][fk];
    short8v b1 = *(short8v*)&Bs[wn * 32 + 16 + fr][fk];
    acc[0][0] = __builtin_amdgcn_mfma_f32_16x16x32_bf16(a0, b0, acc[0][0], 0, 0, 0);
    acc[0][1] = __builtin_amdgcn_mfma_f32_16x16x32_bf16(a0, b1, acc[0][1], 0, 0, 0);
    acc[1][0] = __builtin_amdgcn_mfma_f32_16x16x32_bf16(a1, b0, acc[1][0], 0, 0, 0);
    acc[1][1] = __builtin_amdgcn_mfma_f32_16x16x32_bf16(a1, b1, acc[1][1], 0, 0, 0);
    __syncthreads();
  }
#pragma unroll
  for (int tm = 0; tm < 2; tm++) {
    const int m_base = m0 + wm * 32 + tm * 16 + (l >> 4) * 4;
#pragma unroll
    for (int tn = 0; tn < 2; tn++) {
      const int n = n0 + wn * 32 + tn * 16 + (l & 15);
      float v0 = acc[tm][tn][0], v1 = acc[tm][tn][1];
      float v2 = acc[tm][tn][2], v3 = acc[tm][tn][3];
      if (HAS_BIAS) {
        v0 += bias[m_base]; v1 += bias[m_base + 1];
        v2 += bias[m_base + 2]; v3 += bias[m_base + 3];
      }
      if (HAS_RES) {
        v0 += res[(long)b * sR + (long)(m_base + 0) * 1024 + n];
        v1 += res[(long)b * sR + (long)(m_base + 1) * 1024 + n];
        v2 += res[(long)b * sR + (long)(m_base + 2) * 1024 + n];
        v3 += res[(long)b * sR + (long)(m_base + 3) * 1024 + n];
      }
      if (MODE == 0) {
        float* Y = (float*)Y0 + (long)b * sY + n;
        Y[(long)(m_base + 0) * 1024] = v0; Y[(long)(m_base + 1) * 1024] = v1;
        Y[(long)(m_base + 2) * 1024] = v2; Y[(long)(m_base + 3) * 1024] = v3;
      } else if (MODE == 1) {
        short* Y = (short*)Y0 + (long)b * sY + n;
        Y[(long)(m_base + 0) * 1024] = (short)f2bf(v0);
        Y[(long)(m_base + 1) * 1024] = (short)f2bf(v1);
        Y[(long)(m_base + 2) * 1024] = (short)f2bf(v2);
        Y[(long)(m_base + 3) * 1024] = (short)f2bf(v3);
      } else if (MODE == 2) {
        *(unsigned long long*)((short*)Y0 + ((long)b * 1024 + n) * tStride +
                               tOff + m_base) = pack4bf(v0, v1, v2, v3);
        if (EMIT_HI && m_base >= 128) {
          float* Y = (float*)Y1 + ((long)b * 128 + m_base - 128) * 1024 + n;
          Y[0] = v0; Y[1024] = v1; Y[2048] = v2; Y[3072] = v3;
        }
      } else {  // MODE 3
        if (m0 < 384) {
          float* Y = (float*)Y0 + (long)b * 384 * 1024 + (long)m_base * 1024 + n;
          Y[0] = v0; Y[1024] = v1; Y[2048] = v2; Y[3072] = v3;
        } else {
          *(unsigned long long*)((short*)Y1 + ((long)b * 1024 + n) * 384 +
                                 (m_base - 384)) = pack4bf(v0, v1, v2, v3);
        }
      }
    }
  }
}

// ---------------------------------------------------------------------------
// FFT magnitude pooling + channel means over y1[b][c][n].  Block per (b,c).
// ---------------------------------------------------------------------------
__global__ __launch_bounds__(256) void fftpool_kernel(
    const float* __restrict__ y1, float* __restrict__ pooled, float* __restrict__ m1) {
  const int bc = blockIdx.x;
  const float* img = y1 + (long)bc * NPIX;
  __shared__ float im[1024];
  __shared__ float Gr[32][17], Gi[32][17];
  __shared__ float cs[32], sn[32];
  __shared__ float red[256];
  const int t = threadIdx.x;
  if (t < 32) {
    float ang = -0.19634954084936207f * (float)t;  // -2*pi*t/32
    __sincosf(ang, &sn[t], &cs[t]);
  }
  float lsum = 0.f;
  for (int i = t; i < 1024; i += 256) { float v = img[i]; im[i] = v; lsum += v; }
  red[t] = lsum;
  __syncthreads();
  for (int s = 128; s > 0; s >>= 1) {
    if (t < s) red[t] += red[t + s];
    __syncthreads();
  }
  if (t == 0) m1[bc] = red[0] * (1.f / 1024.f);
  for (int i = t; i < 544; i += 256) {
    int h = i / 17, v = i % 17;
    float ar = 0.f, ai = 0.f;
    for (int w2 = 0; w2 < 32; w2++) {
      int k = (v * w2) & 31;
      float x = im[h * 32 + w2];
      ar += x * cs[k]; ai += x * sn[k];
    }
    Gr[h][v] = ar; Gi[h][v] = ai;
  }
  __syncthreads();
  float asum = 0.f;
  for (int i = t; i < 544; i += 256) {
    int u = i / 17, v = i % 17;
    float xr = 0.f, xi = 0.f;
    for (int h = 0; h < 32; h++) {
      int k = (u * h) & 31;
      float gr = Gr[h][v], gi = Gi[h][v];
      xr += gr * cs[k] - gi * sn[k];
      xi += gr * sn[k] + gi * cs[k];
    }
    asum += sqrtf(xr * xr + xi * xi);
  }
  red[t] = asum;
  __syncthreads();
  for (int s = 128; s > 0; s >>= 1) {
    if (t < s) red[t] += red[t + s];
    __syncthreads();
  }
  if (t == 0) pooled[bc] = red[0] * (1.f / (32.f * 544.f));
}

// ---------------------------------------------------------------------------
// Gates: fw/ca MLPs -> g = fw*ca; p_route -> alpha.  One block per batch.
// ---------------------------------------------------------------------------
__global__ __launch_bounds__(128) void gates_kernel(
    const float* __restrict__ pooled, const float* __restrict__ m1,
    const float* __restrict__ fm_w1, const float* __restrict__ fm_w2,
    const float* __restrict__ ca_w1, const float* __restrict__ ca_w2,
    const float* __restrict__ rt_w, const float* __restrict__ rt_b,
    float* __restrict__ g, float* __restrict__ alpha) {
  const int b = blockIdx.x, t = threadIdx.x;
  __shared__ float h1[8], fwv[128], xsm[128], h2[8];
  const float* pb = pooled + b * 128;
  const float* mb = m1 + b * 128;
  if (t < 8) {
    float s = 0.f;
    for (int c = 0; c < 128; c++) s += pb[c] * fm_w1[t * 128 + c];
    h1[t] = fmaxf(s, 0.f);
  }
  __syncthreads();
  {
    float s = 0.f;
    for (int r = 0; r < 8; r++) s += h1[r] * fm_w2[t * 8 + r];
    float fw = 1.f / (1.f + __expf(-s));
    fwv[t] = fw; xsm[t] = fw * mb[t];
  }
  __syncthreads();
  if (t < 8) {
    float s = 0.f;
    for (int c = 0; c < 128; c++) s += xsm[c] * ca_w1[t * 128 + c];
    h2[t] = fmaxf(s, 0.f);
  }
  __syncthreads();
  {
    float s = 0.f;
    for (int r = 0; r < 8; r++) s += h2[r] * ca_w2[t * 8 + r];
    float ca = 1.f / (1.f + __expf(-s));
    g[b * 128 + t] = fwv[t] * ca;
  }
  if (t == 0) {
    float s = 0.f;
    for (int c = 0; c < 128; c++) s += mb[c] * rt_w[c];
    s += rt_b[0];
    alpha[b] = 1.f / (1.f + __expf(-s));
  }
}

// ---------------------------------------------------------------------------
// Variance of k and v head vectors (ddof=1) + per-bh max(var_k).
// Emits vTb[bh][d][m] (bf16, m-contiguous) via in-LDS transpose.
// ---------------------------------------------------------------------------
__global__ __launch_bounds__(256) void varmax_kernel(
    const float* __restrict__ qkvb, float* __restrict__ var_k,
    float* __restrict__ var_v, float* __restrict__ maxvk,
    short* __restrict__ vTb) {
  const int bh = blockIdx.x;
  const int b = bh >> 3, h = bh & 7;
  __shared__ float red[256];
  __shared__ float trans[16][256];
  const float* kb = qkvb + ((long)b * 384 + 128 + h * 16) * NPIX;
  const float* vb = qkvb + ((long)b * 384 + 256 + h * 16) * NPIX;
  float mx = 0.f;
  for (int j = 0; j < 4; j++) {
    int n = threadIdx.x + j * 256;
    float xk[16], xv[16], sk = 0.f, sv = 0.f;
#pragma unroll
    for (int d = 0; d < 16; d++) {
      xk[d] = kb[(long)d * NPIX + n]; sk += xk[d];
      xv[d] = vb[(long)d * NPIX + n]; sv += xv[d];
    }
    float mk = sk * (1.f / 16.f), mv = sv * (1.f / 16.f);
    float vk_ = 0.f, vv_ = 0.f;
#pragma unroll
    for (int d = 0; d < 16; d++) {
      float a = xk[d] - mk; vk_ += a * a;
      float c = xv[d] - mv; vv_ += c * c;
    }
    vk_ *= (1.f / 15.f); vv_ *= (1.f / 15.f);
    var_k[(long)bh * NPIX + n] = vk_;
    var_v[(long)bh * NPIX + n] = vv_;
    mx = fmaxf(mx, vk_);
#pragma unroll
    for (int d = 0; d < 16; d++) trans[d][threadIdx.x] = xv[d];
    __syncthreads();
    {
      int d = threadIdx.x >> 4, mc = threadIdx.x & 15;
      __align__(16) short tmp[16];
#pragma unroll
      for (int e = 0; e < 16; e++) tmp[e] = (short)f2bf(trans[d][mc * 16 + e]);
      short* dst = vTb + ((long)bh * 16 + d) * 1024 + j * 256 + mc * 16;
      *(uint4*)dst = *(uint4*)tmp;
      *(uint4*)(dst + 8) = *(uint4*)(tmp + 8);
    }
    __syncthreads();
  }
  red[threadIdx.x] = mx;
  __syncthreads();
  for (int s = 128; s > 0; s >>= 1) {
    if (threadIdx.x < s) red[threadIdx.x] = fmaxf(red[threadIdx.x], red[threadIdx.x + s]);
    __syncthreads();
  }
  if (threadIdx.x == 0) maxvk[bh] = red[0];
}

// ---------------------------------------------------------------------------
// MFMA stat attention -> tcT[b][n][h*16+d] bf16 (no partials).
// ---------------------------------------------------------------------------
__global__ __launch_bounds__(256) void stat_mfma_kernel(
    const short* __restrict__ vTb, const float* __restrict__ var_k,
    const float* __restrict__ var_v, const float* __restrict__ maxvk,
    short* __restrict__ tcT) {
  const int bh = blockIdx.x;
  const int b = bh >> 3, h = bh & 7;
  const int n0 = blockIdx.y * 64;
  const int tid = threadIdx.x;
  const int l = tid & 63, w = tid >> 6;
  const int ln = l & 15, lk = l >> 4;
  const int n = n0 + w * 16 + ln;
  __shared__ float vk[1024];
  for (int i = tid; i < 1024; i += 256) vk[i] = var_k[(long)bh * 1024 + i];
  const float cn = var_v[(long)bh * 1024 + n] * 0.25f;
  const float mv = maxvk[bh];
  const short* arow = vTb + ((long)bh * 16 + ln) * 1024 + lk * 8;
  __syncthreads();
  f32x4 acc = {};
  float psum = 0.f;
  for (int m0 = 0; m0 < 1024; m0 += 32) {
    short8v afrag = *(const short8v*)(arow + m0);
    short8v bfrag;
#pragma unroll
    for (int j = 0; j < 8; j++) {
      float wv = __expf(cn * (vk[m0 + lk * 8 + j] - mv));
      psum += wv;
      bfrag[j] = (short)f2bf(wv);
    }
    acc = __builtin_amdgcn_mfma_f32_16x16x32_bf16(afrag, bfrag, acc, 0, 0, 0);
  }
  psum += __shfl_xor(psum, 16);
  psum += __shfl_xor(psum, 32);
  const float inv = 1.f / psum;
  *(unsigned long long*)(tcT + ((long)b * 1024 + n) * 128 + h * 16 + lk * 4) =
      pack4bf(acc[0] * inv, acc[1] * inv, acc[2] * inv, acc[3] * inv);
}

// ---------------------------------------------------------------------------
// Bit-pack signs from sqkvT[b][n][c] (bf16, coalesced).
// ---------------------------------------------------------------------------
__global__ __launch_bounds__(256) void pack_kernel(
    const short* __restrict__ sqkvT,
    unsigned long long* __restrict__ qbits, unsigned long long* __restrict__ kbits) {
  const int wave = threadIdx.x >> 6, lane = threadIdx.x & 63;
  const long p = (long)blockIdx.x * 4 + wave;  // 0..8191 = b*1024+n
  const short* base = sqkvT + p * 384;
  unsigned long long q0 = __ballot(bf2f((unsigned short)base[lane]) > 0.f);
  unsigned long long q1 = __ballot(bf2f((unsigned short)base[64 + lane]) > 0.f);
  unsigned long long k0 = __ballot(bf2f((unsigned short)base[128 + lane]) > 0.f);
  unsigned long long k1 = __ballot(bf2f((unsigned short)base[192 + lane]) > 0.f);
  if (lane == 0) {
    qbits[p * 2] = q0; qbits[p * 2 + 1] = q1;
    kbits[p * 2] = k0; kbits[p * 2 + 1] = k1;
  }
}

// ---------------------------------------------------------------------------
// MFMA binary-attention GEMM with in-register w synthesis (K-split x4).
// Partials written as bf16 (numerator of a weighted mean -> 0.4% rel ok).
// ---------------------------------------------------------------------------
__global__ __launch_bounds__(256) void obgemm_kernel(
    const short* __restrict__ pvb, const unsigned long long* __restrict__ qbits,
    const unsigned long long* __restrict__ kbits, short* __restrict__ pnum,
    float* __restrict__ pden) {
  const int b = blockIdx.z;
  const int sp = blockIdx.y;
  const int n0 = blockIdx.x * 64;
  const int kb0 = sp * 256;
  __shared__ __align__(16) short As[128][40];
  __shared__ __align__(16) unsigned long long kbsh[256][2];
  const int tid = threadIdx.x;
  const int l = tid & 63, w = tid >> 6;
  const int ln = l & 15, lk = l >> 4;
  const int n = n0 + w * 16 + ln;
  const unsigned long long q0 = qbits[((long)b * 1024 + n) * 2];
  const unsigned long long q1 = qbits[((long)b * 1024 + n) * 2 + 1];
  *(uint4*)&kbsh[tid][0] = *(const uint4*)(kbits + ((long)b * 1024 + kb0 + tid) * 2);
  const float fs = 0.08838834764831845f;
  const int sc = tid >> 1, sh = (tid & 1) * 16;
  const short* pvrow = pvb + ((long)b * 128 + sc) * 1024 + kb0;
  f32x4 acc[8] = {};
  float psum = 0.f;
  for (int ks = 0; ks < 8; ks++) {  // 32 m per step
    *(uint4*)&As[sc][sh] = *(const uint4*)(pvrow + ks * 32 + sh);
    *(uint4*)&As[sc][sh + 8] = *(const uint4*)(pvrow + ks * 32 + sh + 8);
    __syncthreads();
    const int mloc = ks * 32 + lk * 8;
    short8v bfrag;
#pragma unroll
    for (int j = 0; j < 8; j++) {
      unsigned long long kw0 = kbsh[mloc + j][0];
      unsigned long long kw1 = kbsh[mloc + j][1];
      int ham = __popcll(kw0 ^ q0) + __popcll(kw1 ^ q1);
      float wv = __expf((float)(128 - 2 * ham) * fs);
      psum += wv;
      bfrag[j] = (short)f2bf(wv);
    }
#pragma unroll
    for (int ct = 0; ct < 8; ct++) {
      short8v afrag = *(short8v*)&As[ct * 16 + ln][lk * 8];
      acc[ct] = __builtin_amdgcn_mfma_f32_16x16x32_bf16(afrag, bfrag, acc[ct], 0, 0, 0);
    }
    __syncthreads();
  }
  short* dst = pnum + (((long)sp * 8 + b) * 128) * 1024 + n;
#pragma unroll
  for (int ct = 0; ct < 8; ct++)
#pragma unroll
    for (int i = 0; i < 4; i++)
      dst[(long)(ct * 16 + lk * 4 + i) * 1024] = (short)f2bf(acc[ct][i]);
  psum += __shfl_xor(psum, 16);
  psum += __shfl_xor(psum, 32);
  if (lk == 0)
    pden[((long)sp * 8 + b) * 1024 + n] = psum;
}

// ---------------------------------------------------------------------------
// Fused depthwise 3x3 conv + ob reduce + combine (WITHOUT tproj part):
// attn = g*y1 + (1-a)*dwconv(y1) + a*obv.  tproj adds itself later (RES).
// ---------------------------------------------------------------------------
__global__ __launch_bounds__(256) void dwcombine_kernel(
    const float* __restrict__ y1, float* __restrict__ attn,
    const float* __restrict__ dw_w, const float* __restrict__ dw_b,
    const short* __restrict__ pnum, const float* __restrict__ pden,
    const float* __restrict__ sproj_b, const float* __restrict__ g,
    const float* __restrict__ alpha) {
  const int bc = blockIdx.x;
  const int b = bc >> 7, cx = bc & 127;
  const float* img = y1 + (long)bc * NPIX;
  float* dst = attn + (long)bc * NPIX;
  float w[9];
#pragma unroll
  for (int i = 0; i < 9; i++) w[i] = dw_w[cx * 9 + i];
  const float bias = dw_b[cx];
  const float a = alpha[b];
  const float gg = g[bc];
  const float sb = sproj_b[cx];
  const long ns = 8L * 128 * 1024;
  const long ds = 8L * 1024;
  const long nbase = (long)bc * 1024;
  const long dbase = (long)b * 1024;
  for (int i = threadIdx.x; i < 1024; i += 256) {
    int h = i >> 5, wx = i & 31;
    float s = bias;
#pragma unroll
    for (int ky = 0; ky < 3; ky++) {
      int hh = h + ky - 1;
      if (hh < 0 || hh > 31) continue;
#pragma unroll
      for (int kx = 0; kx < 3; kx++) {
        int ww2 = wx + kx - 1;
        if (ww2 < 0 || ww2 > 31) continue;
        s += img[hh * 32 + ww2] * w[ky * 3 + kx];
      }
    }
    float num = bf2f((unsigned short)pnum[nbase + i]) +
                bf2f((unsigned short)pnum[nbase + i + ns]) +
                bf2f((unsigned short)pnum[nbase + i + 2 * ns]) +
                bf2f((unsigned short)pnum[nbase + i + 3 * ns]);
    float den = pden[dbase + i] + pden[dbase + i + ds] +
                pden[dbase + i + 2 * ds] + pden[dbase + i + 3 * ds];
    float obv = num / den + sb;
    dst[i] = gg * img[i] + (1.f - a) * s + a * obv;
  }
}

// ---------------------------------------------------------------------------
extern "C" void kernel_launch(void* const* d_in, const int* in_sizes, int n_in,
                              void* d_out, int out_size, void* d_ws, size_t ws_size,
                              hipStream_t stream) {
  const float* x = (const float*)d_in[0];
  const float* cv1_w = (const float*)d_in[1];
  const float* cv1_b = (const float*)d_in[2];
  const float* fm_w1 = (const float*)d_in[3];
  const float* fm_w2 = (const float*)d_in[4];
  const float* ca_w1 = (const float*)d_in[5];
  const float* ca_w2 = (const float*)d_in[6];
  const float* qkv_w = (const float*)d_in[7];
  const float* tproj_w = (const float*)d_in[8];
  const float* tproj_b = (const float*)d_in[9];
  const float* dw_w = (const float*)d_in[10];
  const float* dw_b = (const float*)d_in[11];
  const float* rt_w = (const float*)d_in[12];
  const float* rt_b = (const float*)d_in[13];
  const float* q_w = (const float*)d_in[14];
  const float* k_w = (const float*)d_in[15];
  const float* v_w = (const float*)d_in[16];
  const float* sproj_w = (const float*)d_in[17];
  const float* sproj_b = (const float*)d_in[18];
  const float* cv2_w = (const float*)d_in[19];
  const float* cv2_b = (const float*)d_in[20];
  float* out = (float*)d_out;

  char* wsp = (char*)d_ws;
  size_t off = 0;
  auto alloc = [&](size_t bytes) {
    void* p = wsp + off;
    off += (bytes + 255) & ~(size_t)255;
    return p;
  };
  float* qkvb = (float*)alloc(8UL * 384 * 1024 * 4);  // pnum (bf16) aliases head
  float* y1 = (float*)alloc(8UL * 128 * 1024 * 4);
  float* attn = (float*)alloc(8UL * 128 * 1024 * 4);
  short* ycT = (short*)alloc(8UL * 1024 * 384 * 2);
  short* sqkvT = (short*)alloc(8UL * 1024 * 384 * 2);
  short* tcT = (short*)alloc(8UL * 1024 * 128 * 2);
  short* pvb = (short*)alloc(8UL * 128 * 1024 * 2);
  short* wb = (short*)alloc(294912UL * 2);
  short* vTb = (short*)alloc(64UL * 16 * 1024 * 2);
  float* pden = (float*)alloc(4UL * 8 * 1024 * 4);
  float* var_k = (float*)alloc(8UL * 8 * 1024 * 4);
  float* var_v = (float*)alloc(8UL * 8 * 1024 * 4);
  float* maxvk = (float*)alloc(64 * 4);
  float* pooled = (float*)alloc(1024 * 4);
  float* m1 = (float*)alloc(1024 * 4);
  float* g = (float*)alloc(1024 * 4);
  float* alpha = (float*)alloc(8 * 4);
  unsigned long long* qbits = (unsigned long long*)alloc(8192UL * 2 * 8);
  unsigned long long* kbits = (unsigned long long*)alloc(8192UL * 2 * 8);
  short* pnum = (short*)qkvb;  // 8.4MB bf16 partials inside qkvb (12.6MB),
                               // qkvb dead after varmax
  // weight arena offsets
  const short* cv1b = wb;
  const short* qsb = wb + 65536;
  const short* tprojb = wb + 163840;
  const short* sprojb = wb + 180224;
  const short* cv2b = wb + 196608;
  if (off > ws_size) return;

  dim3 blk(256);
  // 0. weights -> bf16 arena
  convw_kernel<<<dim3(1152), blk, 0, stream>>>(cv1_w, qkv_w, tproj_w, sproj_w,
                                               cv2_w, q_w, k_w, v_w, wb);
  // 1. cv1 (MFMA, MODE2 + XF32T: reads x fp32, in-kernel transpose):
  //    ycT[n][0..256] bf16 + y1 fp32
  mgemm_kernel<2, true, false, true, true><<<dim3(16, 4, 8), blk, 0, stream>>>(
      cv1b, x, 0, cv1_b, nullptr, ycT, y1, 256, 256L * 1024, 0, 0, 384, 0);
  // 2. FFT pooling + channel means (y1)
  fftpool_kernel<<<dim3(1024), blk, 0, stream>>>(y1, pooled, m1);
  // 3. gates
  gates_kernel<<<dim3(8), dim3(128), 0, stream>>>(pooled, m1, fm_w1, fm_w2,
                                                  ca_w1, ca_w2, rt_w, rt_b, g, alpha);
  // 4. merged qkv + spatial-qkv projection (MODE3, M=768)
  mgemm_kernel<3, false, false, false, false><<<dim3(16, 12, 8), blk, 0, stream>>>(
      qsb, ycT + 128, 384, nullptr, nullptr, qkvb, sqkvT, 128, 1024L * 384,
      0, 0, 0, 0);
  // 5. variances + per-bh max + bf16 transposed V (vTb)
  varmax_kernel<<<dim3(64), blk, 0, stream>>>(qkvb, var_k, var_v, maxvk, vTb);
  // 6. MFMA stat attention -> tcT
  stat_mfma_kernel<<<dim3(64, 16), blk, 0, stream>>>(vTb, var_k, var_v, maxvk, tcT);
  // 7. sign pack (coalesced from sqkvT)
  pack_kernel<<<dim3(2048), blk, 0, stream>>>(sqkvT, qbits, kbits);
  // 7b. pv = sproj_w @ vv (MFMA, MODE1 bf16 out)
  mgemm_kernel<1, false, false, false, false><<<dim3(16, 2, 8), blk, 0, stream>>>(
      sprojb, sqkvT + 256, 384, nullptr, nullptr, pvb, nullptr, 128,
      1024L * 384, 128L * 1024, 0, 0, 0);
  // 8. MFMA binary-attention GEMM -> bf16 partials
  obgemm_kernel<<<dim3(16, 4, 8), blk, 0, stream>>>(pvb, qbits, kbits, pnum, pden);
  // 9. dwcombine (freq + spat, WITHOUT tproj) -> attn
  dwcombine_kernel<<<dim3(1024), blk, 0, stream>>>(y1, attn, dw_w, dw_b, pnum,
                                                   pden, sproj_b, g, alpha);
  // 10. tproj (MFMA, MODE2: RES=attn, write transposed into ycT[n][256..384])
  mgemm_kernel<2, true, true, false, false><<<dim3(16, 2, 8), blk, 0, stream>>>(
      tprojb, tcT, 128, tproj_b, attn, ycT, nullptr, 128, 1024L * 128, 0,
      128L * 1024, 384, 256);
  // 11. cv2 (MFMA, MODE0) + residual
  mgemm_kernel<0, true, true, false, false><<<dim3(16, 4, 8), blk, 0, stream>>>(
      cv2b, ycT, 384, cv2_b, x, out, nullptr, 384, 1024L * 384, 256L * 1024,
      256L * 1024, 0, 0);
}